// Round 2
// baseline (2738.310 us; speedup 1.0000x reference)
//
#include <hip/hip_runtime.h>
#include <cstddef>
#include <cstdint>

typedef unsigned int uint;
typedef unsigned short ushort;

// ---------- bf16 helpers (storage type = ushort) ----------
__device__ __forceinline__ float ld1(const float* p) { return *p; }
__device__ __forceinline__ float ld1(const ushort* p) { return __uint_as_float(((uint)*p) << 16); }
__device__ __forceinline__ void st1(float* p, float v) { *p = v; }
__device__ __forceinline__ void st1(ushort* p, float v) {
  uint x = __float_as_uint(v);
  *p = (ushort)((x + 0x7fffu + ((x >> 16) & 1u)) >> 16);  // RNE
}
__device__ __forceinline__ ushort f2b(float v) {
  uint x = __float_as_uint(v);
  return (ushort)((x + 0x7fffu + ((x >> 16) & 1u)) >> 16);
}
struct F4 { float x, y, z, w; };
__device__ __forceinline__ F4 ld4(const float* p) {
  float4 v = *(const float4*)p; return {v.x, v.y, v.z, v.w};
}
__device__ __forceinline__ F4 ld4(const ushort* p) {
  uint2 u = *(const uint2*)p;
  return { __uint_as_float(u.x << 16), __uint_as_float(u.x & 0xffff0000u),
           __uint_as_float(u.y << 16), __uint_as_float(u.y & 0xffff0000u) };
}

__device__ __forceinline__ int lowerb(const int* __restrict__ ids, int M, int v) {
  int lo = 0, hi = M;
  while (lo < hi) { int mid = (lo + hi) >> 1; if (ids[mid] < v) lo = mid + 1; else hi = mid; }
  return lo;
}

__global__ void fillz(float* p, int n) {
  int i = blockIdx.x * 256 + threadIdx.x;
  if (i < n) p[i] = 0.f;
}

// ---------- Y[M,128] = X[M,K] @ W[K,128] + b ----------
// 128 threads (one per output col), ROWS rows per block.
// X rows are uniform-addressed -> scalar (SGPR) loads; W coalesced, L2-resident.
// NOTE: no __restrict__ on X/Y — used in-place for the edge chain.
template<int K, typename TIn, typename TOut, int ROWS>
__global__ __launch_bounds__(128) void lin_tiled(const TIn* X,
                                                 const float* __restrict__ W,
                                                 const float* __restrict__ b,
                                                 TOut* Y, int M) {
  int t = threadIdx.x;
  int row0 = blockIdx.x * ROWS;
  if (row0 >= M) return;
  float bias = b[t];
  float acc[ROWS];
#pragma unroll
  for (int r = 0; r < ROWS; ++r) acc[r] = bias;
  int nr = M - row0; if (nr > ROWS) nr = ROWS;
  if (nr == ROWS) {
    if constexpr ((K & 3) == 0) {
      for (int k = 0; k < K; k += 4) {
        float w0 = W[(k + 0) * 128 + t];
        float w1 = W[(k + 1) * 128 + t];
        float w2 = W[(k + 2) * 128 + t];
        float w3 = W[(k + 3) * 128 + t];
#pragma unroll
        for (int r = 0; r < ROWS; ++r) {
          F4 x = ld4(X + (size_t)(row0 + r) * K + k);
          acc[r] = fmaf(x.x, w0, acc[r]);
          acc[r] = fmaf(x.y, w1, acc[r]);
          acc[r] = fmaf(x.z, w2, acc[r]);
          acc[r] = fmaf(x.w, w3, acc[r]);
        }
      }
    } else {
#pragma unroll
      for (int k = 0; k < K; ++k) {
        float w = W[k * 128 + t];
#pragma unroll
        for (int r = 0; r < ROWS; ++r)
          acc[r] = fmaf(ld1(X + (size_t)(row0 + r) * K + k), w, acc[r]);
      }
    }
  } else {
    for (int k = 0; k < K; ++k) {
      float w = W[k * 128 + t];
      for (int r = 0; r < nr; ++r)
        acc[r] = fmaf(ld1(X + (size_t)(row0 + r) * K + k), w, acc[r]);
    }
  }
#pragma unroll
  for (int r = 0; r < ROWS; ++r)
    if (r < nr) st1(Y + (size_t)(row0 + r) * 128 + t, acc[r]);
}

// ---------- fused edge stage ----------
// e_out (bf16) holds e@Wf+bf on entry; updated in place to
// f_out = leaky_relu(f_ni[src]+f_nj[dst]+e@Wf+bf). Computes per-head logits,
// ex = exp(logit) (softmax is shift-invariant; logits are O(1), no overflow),
// atomically accumulates denom[dst,h]. One wave per edge; lane covers 2 elems.
__global__ void edge_fuse(const float* __restrict__ f_ni, const float* __restrict__ f_nj,
                          ushort* e_out,
                          const int* __restrict__ src, const int* __restrict__ dst,
                          const float* __restrict__ attn,
                          float* __restrict__ ex, float* __restrict__ denom, int E) {
  int e = blockIdx.x * 4 + (threadIdx.x >> 6);
  if (e >= E) return;
  int lane = threadIdx.x & 63;
  int s = src[e], d = dst[e];
  uint* ep = (uint*)(e_out + (size_t)e * 128 + lane * 2);
  uint u = *ep;
  float2 fa = *(const float2*)(f_ni + (size_t)s * 128 + lane * 2);
  float2 fb = *(const float2*)(f_nj + (size_t)d * 128 + lane * 2);
  float v0 = __uint_as_float(u << 16) + fa.x + fb.x;
  float v1 = __uint_as_float(u & 0xffff0000u) + fa.y + fb.y;
  v0 = v0 >= 0.f ? v0 : 0.01f * v0;
  v1 = v1 >= 0.f ? v1 : 0.01f * v1;
  *ep = (uint)f2b(v0) | ((uint)f2b(v1) << 16);
  int h = lane >> 4;                     // head of element 2*lane
  float2 at = *(const float2*)(attn + h * 32 + (lane & 15) * 2);
  float p = v0 * at.x + v1 * at.y;
  p += __shfl_xor(p, 1);
  p += __shfl_xor(p, 2);
  p += __shfl_xor(p, 4);
  p += __shfl_xor(p, 8);
  if ((lane & 15) == 0) {
    float ev = __expf(p);
    ex[(size_t)e * 4 + h] = ev;
    atomicAdd(denom + (size_t)d * 4 + h, ev);
  }
}

// ---------- h_out[dst] += h_node[src] * a ; h_out zeroed beforehand ----------
__global__ void scatter_msg(const float* __restrict__ h_node, const float* __restrict__ ex,
                            const float* __restrict__ denom,
                            const int* __restrict__ src, const int* __restrict__ dst,
                            float* __restrict__ h_out, int E) {
  int e = blockIdx.x * 4 + (threadIdx.x >> 6);
  if (e >= E) return;
  int lane = threadIdx.x & 63;
  int s = src[e], d = dst[e];
  int h = lane >> 4;
  float a = ex[(size_t)e * 4 + h] / denom[(size_t)d * 4 + h];
  float2 m = *(const float2*)(h_node + (size_t)s * 128 + lane * 2);
  atomicAdd(h_out + (size_t)d * 128 + lane * 2, m.x * a);
  atomicAdd(h_out + (size_t)d * 128 + lane * 2 + 1, m.y * a);
}

// ---------- S[g,:] = sum of X rows with (sorted) id == g ----------
template<typename T>
__global__ void segsum(const T* __restrict__ X, const int* __restrict__ ids, int M,
                       float* __restrict__ S, int* __restrict__ cnt) {
  __shared__ int bounds[2];
  int g = blockIdx.x;
  if (threadIdx.x == 0) { bounds[0] = lowerb(ids, M, g); bounds[1] = lowerb(ids, M, g + 1); }
  __syncthreads();
  int lo = bounds[0], hi = bounds[1];
  int t = threadIdx.x;
  float acc = 0.f;
  for (int r = lo; r < hi; ++r) acc += ld1(X + (size_t)r * 128 + t);
  S[(size_t)g * 128 + t] = acc;
  if (t == 0 && cnt) cnt[g] = hi - lo;
}

// ---------- out[g, coloff+t] = (SP[g]-SR[g]) @ W + cnt[g]*b ----------
__global__ void diff_linear(const float* __restrict__ SP, const float* __restrict__ SR,
                            const int* __restrict__ cnt,
                            const float* __restrict__ W, const float* __restrict__ b,
                            float* __restrict__ out, int ldo, int coloff) {
  int g = blockIdx.x;
  int t = threadIdx.x;
  __shared__ float xs[128];
  xs[t] = SP[(size_t)g * 128 + t] - SR[(size_t)g * 128 + t];
  __syncthreads();
  float acc = (float)cnt[g] * b[t];
  for (int k = 0; k < 128; ++k) acc = fmaf(xs[k], W[k * 128 + t], acc);
  out[(size_t)g * ldo + coloff + t] = acc;
}

template<int K, int NC, bool RELU>
__global__ void mlp_linear(const float* __restrict__ X, const float* __restrict__ W,
                           const float* __restrict__ b, float* __restrict__ Y) {
  int g = blockIdx.x;
  int t = threadIdx.x;  // NC threads
  __shared__ float xs[K];
  for (int i = t; i < K; i += NC) xs[i] = X[(size_t)g * K + i];
  __syncthreads();
  float acc = b[t];
  for (int k = 0; k < K; ++k) acc = fmaf(xs[k], W[k * NC + t], acc);
  if (RELU) acc = fmaxf(acc, 0.f);
  Y[(size_t)g * NC + t] = acc;
}

__global__ void mlp_final(const float* __restrict__ X, const float* __restrict__ W,
                          const float* __restrict__ b, float* __restrict__ out, int G) {
  int g = blockIdx.x * blockDim.x + threadIdx.x;
  if (g >= G) return;
  float acc = b[0];
  for (int k = 0; k < 256; ++k) acc = fmaf(X[(size_t)g * 256 + k], W[k], acc);
  out[g] = acc;
}

struct LayerW {
  const float *Wni, *bni, *Wnj, *bnj, *Wf, *bf, *Wnode, *bnode, *attn;
};

// One EGAT layer. Node state nb is updated IN PLACE (read by the 3 node
// linears first, then zeroed, then scatter-accumulated). Edge buffer eb is
// updated in place too. f_node aliases f_ni (dead after edge_fuse).
template<int FNN, int FNE, typename TEin>
static void run_layer(const float* h, const TEin* e, const int* src, const int* dst,
                      const LayerW& w, float* f_ni, float* f_nj,
                      ushort* eb, float* ex, float* denom, float* nb,
                      int N, int E, hipStream_t stream) {
  lin_tiled<FNN, float, float, 16><<<(N + 15) / 16, 128, 0, stream>>>(h, w.Wni, w.bni, f_ni, N);
  lin_tiled<FNN, float, float, 16><<<(N + 15) / 16, 128, 0, stream>>>(h, w.Wnj, w.bnj, f_nj, N);
  lin_tiled<FNE, TEin, ushort, 16><<<(E + 15) / 16, 128, 0, stream>>>(e, w.Wf, w.bf, eb, E);
  fillz<<<(N * 4 + 255) / 256, 256, 0, stream>>>(denom, N * 4);
  edge_fuse<<<(E + 3) / 4, 256, 0, stream>>>(f_ni, f_nj, eb, src, dst, w.attn, ex, denom, E);
  lin_tiled<FNN, float, float, 16><<<(N + 15) / 16, 128, 0, stream>>>(h, w.Wnode, w.bnode, f_ni, N);
  fillz<<<(N * 128 + 255) / 256, 256, 0, stream>>>(nb, N * 128);
  scatter_msg<<<(E + 3) / 4, 256, 0, stream>>>(f_ni, ex, denom, src, dst, nb, E);
}

extern "C" void kernel_launch(void* const* d_in, const int* in_sizes, int n_in,
                              void* d_out, int out_size, void* d_ws, size_t ws_size,
                              hipStream_t stream) {
  const float* hR = (const float*)d_in[0];
  const float* eR = (const float*)d_in[1];
  const float* hP = (const float*)d_in[2];
  const float* eP = (const float*)d_in[3];
  const int* srcR = (const int*)d_in[4];
  const int* dstR = (const int*)d_in[5];
  const int* srcP = (const int*)d_in[6];
  const int* dstP = (const int*)d_in[7];
  const int* nid  = (const int*)d_in[8];
  const int* eid  = (const int*)d_in[9];
  LayerW w1 { (const float*)d_in[10], (const float*)d_in[11], (const float*)d_in[12],
              (const float*)d_in[13], (const float*)d_in[14], (const float*)d_in[15],
              (const float*)d_in[16], (const float*)d_in[17], (const float*)d_in[18] };
  LayerW w2 { (const float*)d_in[19], (const float*)d_in[20], (const float*)d_in[21],
              (const float*)d_in[22], (const float*)d_in[23], (const float*)d_in[24],
              (const float*)d_in[25], (const float*)d_in[26], (const float*)d_in[27] };
  const float* Wa_n = (const float*)d_in[28];
  const float* ba_n = (const float*)d_in[29];
  const float* Wa_e = (const float*)d_in[30];
  const float* ba_e = (const float*)d_in[31];
  const float* Wm1  = (const float*)d_in[32];
  const float* bm1  = (const float*)d_in[33];
  const float* Wm2  = (const float*)d_in[34];
  const float* bm2  = (const float*)d_in[35];
  const float* Wm3  = (const float*)d_in[36];
  const float* bm3  = (const float*)d_in[37];

  const int N = in_sizes[0] / 17;   // 60000
  const int E = in_sizes[4];        // 240000
  const int G = out_size;           // 1024

  // ---- workspace carve-up (bytes), ~165 MB total ----
  char* base = (char*)d_ws;
  size_t off = 0;
  auto alloc = [&](size_t bytes) { char* p = base + off; off += (bytes + 255) & ~(size_t)255; return p; };
  float*  nb    = (float*)alloc((size_t)N * 128 * 4);   // node state (in-place per layer)
  float*  f_ni  = (float*)alloc((size_t)N * 128 * 4);   // also f_node
  float*  f_nj  = (float*)alloc((size_t)N * 128 * 4);
  ushort* eb    = (ushort*)alloc((size_t)E * 128 * 2);  // edge state, bf16, in-place
  float*  ex    = (float*)alloc((size_t)E * 4 * 4);
  float*  denom = (float*)alloc((size_t)N * 4 * 4);
  float*  SnP   = (float*)alloc((size_t)G * 128 * 4);
  float*  SnR   = (float*)alloc((size_t)G * 128 * 4);
  float*  SeP   = (float*)alloc((size_t)G * 128 * 4);
  float*  SeR   = (float*)alloc((size_t)G * 128 * 4);
  float*  Gf    = (float*)alloc((size_t)G * 256 * 4);
  float*  x1    = (float*)alloc((size_t)G * 512 * 4);
  float*  x2    = (float*)alloc((size_t)G * 256 * 4);
  int*    cnt_n = (int*)alloc((size_t)G * 4);
  int*    cnt_e = (int*)alloc((size_t)G * 4);
  if (off > ws_size) return;  // graceful fail (diagnostic: absmax == |ref|max)

  // ---- P branch: one egat1 layer, reduce to G x 128, then reuse buffers ----
  run_layer<17, 15, float>(hP, eP, srcP, dstP, w1, f_ni, f_nj, eb, ex, denom, nb, N, E, stream);
  segsum<float><<<G, 128, 0, stream>>>(nb, nid, N, SnP, cnt_n);
  segsum<ushort><<<G, 128, 0, stream>>>(eb, eid, E, SeP, cnt_e);

  // ---- R branch: egat1, then egat2 x2 (state in place) ----
  run_layer<17, 15, float>(hR, eR, srcR, dstR, w1, f_ni, f_nj, eb, ex, denom, nb, N, E, stream);
  run_layer<128, 128, ushort>(nb, eb, srcR, dstR, w2, f_ni, f_nj, eb, ex, denom, nb, N, E, stream);
  run_layer<128, 128, ushort>(nb, eb, srcR, dstR, w2, f_ni, f_nj, eb, ex, denom, nb, N, E, stream);
  segsum<float><<<G, 128, 0, stream>>>(nb, nid, N, SnR, nullptr);
  segsum<ushort><<<G, 128, 0, stream>>>(eb, eid, E, SeR, nullptr);

  // ---- Diff aggregate + per-graph linears (linear commutes with segment sum) ----
  diff_linear<<<G, 128, 0, stream>>>(SnP, SnR, cnt_n, Wa_n, ba_n, Gf, 256, 0);
  diff_linear<<<G, 128, 0, stream>>>(SeP, SeR, cnt_e, Wa_e, ba_e, Gf, 256, 128);

  // ---- MLP head ----
  mlp_linear<256, 512, true><<<G, 512, 0, stream>>>(Gf, Wm1, bm1, x1);
  mlp_linear<512, 256, true><<<G, 256, 0, stream>>>(x1, Wm2, bm2, x2);
  mlp_final<<<(G + 255) / 256, 256, 0, stream>>>(x2, Wm3, bm3, (float*)d_out, G);
}

// Round 3
// 1596.152 us; speedup vs baseline: 1.7156x; 1.7156x over previous
//
#include <hip/hip_runtime.h>
#include <cstddef>
#include <cstdint>

typedef unsigned int uint;
typedef unsigned short ushort;
typedef __attribute__((ext_vector_type(4))) float f32x4;
typedef __attribute__((ext_vector_type(8))) short short8;

// ---------- bf16 helpers (storage = ushort) ----------
__device__ __forceinline__ ushort f2b(float v) {
  uint x = __float_as_uint(v);
  return (ushort)((x + 0x7fffu + ((x >> 16) & 1u)) >> 16);  // RNE
}
__device__ __forceinline__ float ld1(const float* p) { return *p; }
__device__ __forceinline__ float ld1(const ushort* p) { return __uint_as_float(((uint)*p) << 16); }
__device__ __forceinline__ void st1(float* p, float v) { *p = v; }
__device__ __forceinline__ void st1(ushort* p, float v) { *p = f2b(v); }

// load 8 consecutive elems as packed bf16 (uint4 = 8 x bf16)
__device__ __forceinline__ uint4 ldA8(const float* p) {
  float4 a = *(const float4*)p;
  float4 b = *(const float4*)(p + 4);
  uint4 r;
  r.x = (uint)f2b(a.x) | ((uint)f2b(a.y) << 16);
  r.y = (uint)f2b(a.z) | ((uint)f2b(a.w) << 16);
  r.z = (uint)f2b(b.x) | ((uint)f2b(b.y) << 16);
  r.w = (uint)f2b(b.z) | ((uint)f2b(b.w) << 16);
  return r;
}
__device__ __forceinline__ uint4 ldA8(const ushort* p) { return *(const uint4*)p; }

__device__ __forceinline__ int lowerb(const int* __restrict__ ids, int M, int v) {
  int lo = 0, hi = M;
  while (lo < hi) { int mid = (lo + hi) >> 1; if (ids[mid] < v) lo = mid + 1; else hi = mid; }
  return lo;
}

__global__ void fillz(float* p, int n) {
  int i = blockIdx.x * 256 + threadIdx.x;
  if (i < n) p[i] = 0.f;
}
__global__ void fillz4(float4* p, int n4) {
  int i = blockIdx.x * 256 + threadIdx.x;
  if (i < n4) p[i] = make_float4(0.f, 0.f, 0.f, 0.f);
}

// ---------- prep: W[128][128] fp32 -> transposed, bf16, XOR-swizzled image ----------
// Wt[n*128 + (k ^ ((n&7)<<3))] = bf16(W[k][n])  -> identical to desired LDS image.
__global__ void prep_w(const float* __restrict__ W, ushort* __restrict__ Wt) {
  int t = threadIdx.x;        // 256 threads, 1 block
  int n = t >> 1;
  int k0 = (t & 1) * 64;
  uint sw = (uint)(n & 7) << 3;
  for (int kk = 0; kk < 64; ++kk) {
    int k = k0 + kk;
    Wt[n * 128 + (k ^ sw)] = f2b(W[k * 128 + n]);
  }
}

// ---------- MFMA GEMM: Y[M,128] = X[M,128] @ W[128,128] + b ----------
// BM=128, BN=128(full), 256 threads = 4 waves (2x2 of 64x64).
// As/Bs: bf16, swizzled (ushort index k ^ ((row&7)<<3)) -> 2-way LDS conflicts max.
// In-place safe (Y==X): each block reads only the rows it writes, via LDS.
template<typename TIn, typename TOut>
__global__ __launch_bounds__(256) void gemm_k128(const TIn* X, const ushort* __restrict__ Wt,
                                                 const float* __restrict__ b, TOut* Y, int M) {
  __shared__ ushort As[128 * 128];
  __shared__ ushort Bs[128 * 128];
  int t = threadIdx.x;
  int row0 = blockIdx.x * 128;

  // stage B: linear 128B per thread (pre-swizzled in global)
  {
    const uint4* s4 = (const uint4*)Wt + t * 8;
    uint4* d4 = (uint4*)Bs + t * 8;
#pragma unroll
    for (int c = 0; c < 8; ++c) d4[c] = s4[c];
  }
  // stage A: row r = t>>1, k-half = (t&1)*64 ; convert to bf16, swizzled store
  {
    int r = t >> 1;
    int k0h = (t & 1) * 64;
    int grow = row0 + r;
    uint sw = (uint)(r & 7) << 3;
    if (grow < M) {
      const TIn* xr = X + (size_t)grow * 128;
#pragma unroll
      for (int c = 0; c < 8; ++c) {
        int k0 = k0h + c * 8;
        *(uint4*)(As + r * 128 + (k0 ^ sw)) = ldA8(xr + k0);
      }
    } else {
      uint4 z = make_uint4(0, 0, 0, 0);
#pragma unroll
      for (int c = 0; c < 8; ++c) {
        int k0 = k0h + c * 8;
        *(uint4*)(As + r * 128 + (k0 ^ sw)) = z;
      }
    }
  }
  __syncthreads();

  int lane = t & 63;
  int wid = t >> 6;
  int wr = wid >> 1, wc = wid & 1;
  uint swl = (uint)(lane & 7) << 3;     // row&7 == lane&7 for all fragments

  f32x4 acc[4][4];
#pragma unroll
  for (int n4 = 0; n4 < 4; ++n4) {
    float bv = b[wc * 64 + n4 * 16 + (lane & 15)];
#pragma unroll
    for (int m4 = 0; m4 < 4; ++m4) acc[m4][n4] = (f32x4){bv, bv, bv, bv};
  }

#pragma unroll
  for (int kk = 0; kk < 4; ++kk) {
    int kidx = kk * 32 + 8 * (lane >> 4);      // ushort index of this lane's k-chunk
    short8 af[4], bfr[4];
#pragma unroll
    for (int m4 = 0; m4 < 4; ++m4) {
      int rm = wr * 64 + m4 * 16 + (lane & 15);
      af[m4] = *(const short8*)(As + rm * 128 + (kidx ^ swl));
    }
#pragma unroll
    for (int n4 = 0; n4 < 4; ++n4) {
      int cn = wc * 64 + n4 * 16 + (lane & 15);
      bfr[n4] = *(const short8*)(Bs + cn * 128 + (kidx ^ swl));
    }
#pragma unroll
    for (int m4 = 0; m4 < 4; ++m4)
#pragma unroll
      for (int n4 = 0; n4 < 4; ++n4)
        acc[m4][n4] = __builtin_amdgcn_mfma_f32_16x16x32_bf16(af[m4], bfr[n4], acc[m4][n4], 0, 0, 0);
  }

  // C/D layout: col = lane&15, row = (lane>>4)*4 + i   [m89-verified]
  int coln = wc * 64 + (lane & 15);
#pragma unroll
  for (int m4 = 0; m4 < 4; ++m4) {
    int rb = row0 + wr * 64 + m4 * 16 + ((lane >> 4) << 2);
#pragma unroll
    for (int n4 = 0; n4 < 4; ++n4) {
      int cc = coln + n4 * 16;
#pragma unroll
      for (int i = 0; i < 4; ++i)
        if (rb + i < M) st1(Y + (size_t)(rb + i) * 128 + cc, acc[m4][n4][i]);
    }
  }
}

// ---------- layer-1 fused node linears: 3 outputs from one X pass (K=17) ----------
template<int K>
__global__ __launch_bounds__(128) void lin3_small(const float* __restrict__ X,
    const float* __restrict__ W1, const float* __restrict__ b1,
    const float* __restrict__ W2, const float* __restrict__ b2,
    const float* __restrict__ W3, const float* __restrict__ b3,
    ushort* __restrict__ Y1, ushort* __restrict__ Y2, ushort* __restrict__ Y3, int M) {
  constexpr int ROWS = 16;
  __shared__ float xs[ROWS * K];
  int t = threadIdx.x;
  int row0 = blockIdx.x * ROWS;
  int nr = M - row0; if (nr > ROWS) nr = ROWS;
  for (int i = t; i < nr * K; i += 128) xs[i] = X[(size_t)row0 * K + i];
  __syncthreads();
  float a1[ROWS], a2[ROWS], a3[ROWS];
  float v1 = b1[t], v2 = b2[t], v3 = b3[t];
#pragma unroll
  for (int r = 0; r < ROWS; ++r) { a1[r] = v1; a2[r] = v2; a3[r] = v3; }
#pragma unroll
  for (int k = 0; k < K; ++k) {
    float w1 = W1[k * 128 + t], w2 = W2[k * 128 + t], w3 = W3[k * 128 + t];
#pragma unroll
    for (int r = 0; r < ROWS; ++r) {
      float x = xs[r * K + k];
      a1[r] = fmaf(x, w1, a1[r]);
      a2[r] = fmaf(x, w2, a2[r]);
      a3[r] = fmaf(x, w3, a3[r]);
    }
  }
  for (int r = 0; r < nr; ++r) {
    size_t o = (size_t)(row0 + r) * 128 + t;
    Y1[o] = f2b(a1[r]); Y2[o] = f2b(a2[r]); Y3[o] = f2b(a3[r]);
  }
}

// ---------- layer-1 edge linear (K=15) ----------
template<int K>
__global__ __launch_bounds__(128) void lin1_small(const float* __restrict__ X,
    const float* __restrict__ W, const float* __restrict__ b,
    ushort* __restrict__ Y, int M) {
  constexpr int ROWS = 16;
  __shared__ float xs[ROWS * K];
  int t = threadIdx.x;
  int row0 = blockIdx.x * ROWS;
  int nr = M - row0; if (nr > ROWS) nr = ROWS;
  for (int i = t; i < nr * K; i += 128) xs[i] = X[(size_t)row0 * K + i];
  __syncthreads();
  float acc[ROWS];
  float bias = b[t];
#pragma unroll
  for (int r = 0; r < ROWS; ++r) acc[r] = bias;
#pragma unroll
  for (int k = 0; k < K; ++k) {
    float w = W[k * 128 + t];
#pragma unroll
    for (int r = 0; r < ROWS; ++r) acc[r] = fmaf(xs[r * K + k], w, acc[r]);
  }
  for (int r = 0; r < nr; ++r) Y[(size_t)(row0 + r) * 128 + t] = f2b(acc[r]);
}

// ---------- fused edge stage (all-bf16 gathers) ----------
__global__ void edge_fuse(const ushort* __restrict__ f_ni, const ushort* __restrict__ f_nj,
                          ushort* e_out,
                          const int* __restrict__ src, const int* __restrict__ dst,
                          const float* __restrict__ attn,
                          float* __restrict__ ex, float* __restrict__ denom, int E) {
  int e = blockIdx.x * 4 + (threadIdx.x >> 6);
  if (e >= E) return;
  int lane = threadIdx.x & 63;
  int s = src[e], d = dst[e];
  uint* ep = (uint*)(e_out + (size_t)e * 128) + lane;
  uint u = *ep;
  uint ua = *((const uint*)(f_ni + (size_t)s * 128) + lane);
  uint ub = *((const uint*)(f_nj + (size_t)d * 128) + lane);
  float v0 = __uint_as_float(u << 16) + __uint_as_float(ua << 16) + __uint_as_float(ub << 16);
  float v1 = __uint_as_float(u & 0xffff0000u) + __uint_as_float(ua & 0xffff0000u)
           + __uint_as_float(ub & 0xffff0000u);
  v0 = v0 >= 0.f ? v0 : 0.01f * v0;
  v1 = v1 >= 0.f ? v1 : 0.01f * v1;
  *ep = (uint)f2b(v0) | ((uint)f2b(v1) << 16);
  int h = lane >> 4;                       // head of element 2*lane
  float2 at = *(const float2*)(attn + h * 32 + (lane & 15) * 2);
  float p = v0 * at.x + v1 * at.y;
  p += __shfl_xor(p, 1);
  p += __shfl_xor(p, 2);
  p += __shfl_xor(p, 4);
  p += __shfl_xor(p, 8);
  if ((lane & 15) == 0) {
    float ev = __expf(p);   // softmax shift-invariant; logits O(1), no overflow
    ex[(size_t)e * 4 + h] = ev;
    atomicAdd(denom + (size_t)d * 4 + h, ev);
  }
}

// ---------- h_out[dst] += h_node[src] * a ; h_out zeroed beforehand ----------
__global__ void scatter_msg(const ushort* __restrict__ h_node, const float* __restrict__ ex,
                            const float* __restrict__ denom,
                            const int* __restrict__ src, const int* __restrict__ dst,
                            float* __restrict__ h_out, int E) {
  int e = blockIdx.x * 4 + (threadIdx.x >> 6);
  if (e >= E) return;
  int lane = threadIdx.x & 63;
  int s = src[e], d = dst[e];
  int h = lane >> 4;
  float a = ex[(size_t)e * 4 + h] / denom[(size_t)d * 4 + h];
  uint m = *((const uint*)(h_node + (size_t)s * 128) + lane);
  atomicAdd(h_out + (size_t)d * 128 + lane * 2,     __uint_as_float(m << 16) * a);
  atomicAdd(h_out + (size_t)d * 128 + lane * 2 + 1, __uint_as_float(m & 0xffff0000u) * a);
}

// ---------- S[g,:] = sum of X rows with (sorted) id == g ----------
template<typename T>
__global__ void segsum(const T* __restrict__ X, const int* __restrict__ ids, int M,
                       float* __restrict__ S, int* __restrict__ cnt) {
  __shared__ int bounds[2];
  int g = blockIdx.x;
  if (threadIdx.x == 0) { bounds[0] = lowerb(ids, M, g); bounds[1] = lowerb(ids, M, g + 1); }
  __syncthreads();
  int lo = bounds[0], hi = bounds[1];
  int t = threadIdx.x;
  float acc = 0.f;
  for (int r = lo; r < hi; ++r) acc += ld1(X + (size_t)r * 128 + t);
  S[(size_t)g * 128 + t] = acc;
  if (t == 0 && cnt) cnt[g] = hi - lo;
}

// ---------- out[g, coloff+t] = (SP[g]-SR[g]) @ W + cnt[g]*b ----------
__global__ void diff_linear(const float* __restrict__ SP, const float* __restrict__ SR,
                            const int* __restrict__ cnt,
                            const float* __restrict__ W, const float* __restrict__ b,
                            float* __restrict__ out, int ldo, int coloff) {
  int g = blockIdx.x;
  int t = threadIdx.x;
  __shared__ float xs[128];
  xs[t] = SP[(size_t)g * 128 + t] - SR[(size_t)g * 128 + t];
  __syncthreads();
  float acc = (float)cnt[g] * b[t];
  for (int k = 0; k < 128; ++k) acc = fmaf(xs[k], W[k * 128 + t], acc);
  out[(size_t)g * ldo + coloff + t] = acc;
}

template<int K, int NC, bool RELU>
__global__ void mlp_linear(const float* __restrict__ X, const float* __restrict__ W,
                           const float* __restrict__ b, float* __restrict__ Y) {
  int g = blockIdx.x;
  int t = threadIdx.x;
  __shared__ float xs[K];
  for (int i = t; i < K; i += NC) xs[i] = X[(size_t)g * K + i];
  __syncthreads();
  float acc = b[t];
  for (int k = 0; k < K; ++k) acc = fmaf(xs[k], W[k * NC + t], acc);
  if (RELU) acc = fmaxf(acc, 0.f);
  Y[(size_t)g * NC + t] = acc;
}

__global__ void mlp_final(const float* __restrict__ X, const float* __restrict__ W,
                          const float* __restrict__ b, float* __restrict__ out, int G) {
  int g = blockIdx.x * blockDim.x + threadIdx.x;
  if (g >= G) return;
  float acc = b[0];
  for (int k = 0; k < 256; ++k) acc = fmaf(X[(size_t)g * 256 + k], W[k], acc);
  out[g] = acc;
}

struct LayerW {
  const float *Wni, *bni, *Wnj, *bnj, *Wf, *bf, *Wnode, *bnode, *attn;
};

extern "C" void kernel_launch(void* const* d_in, const int* in_sizes, int n_in,
                              void* d_out, int out_size, void* d_ws, size_t ws_size,
                              hipStream_t stream) {
  const float* hR = (const float*)d_in[0];
  const float* eR = (const float*)d_in[1];
  const float* hP = (const float*)d_in[2];
  const float* eP = (const float*)d_in[3];
  const int* srcR = (const int*)d_in[4];
  const int* dstR = (const int*)d_in[5];
  const int* srcP = (const int*)d_in[6];
  const int* dstP = (const int*)d_in[7];
  const int* nid  = (const int*)d_in[8];
  const int* eid  = (const int*)d_in[9];
  LayerW w1 { (const float*)d_in[10], (const float*)d_in[11], (const float*)d_in[12],
              (const float*)d_in[13], (const float*)d_in[14], (const float*)d_in[15],
              (const float*)d_in[16], (const float*)d_in[17], (const float*)d_in[18] };
  LayerW w2 { (const float*)d_in[19], (const float*)d_in[20], (const float*)d_in[21],
              (const float*)d_in[22], (const float*)d_in[23], (const float*)d_in[24],
              (const float*)d_in[25], (const float*)d_in[26], (const float*)d_in[27] };
  const float* Wa_n = (const float*)d_in[28];
  const float* ba_n = (const float*)d_in[29];
  const float* Wa_e = (const float*)d_in[30];
  const float* ba_e = (const float*)d_in[31];
  const float* Wm1  = (const float*)d_in[32];
  const float* bm1  = (const float*)d_in[33];
  const float* Wm2  = (const float*)d_in[34];
  const float* bm2  = (const float*)d_in[35];
  const float* Wm3  = (const float*)d_in[36];
  const float* bm3  = (const float*)d_in[37];

  const int N = in_sizes[0] / 17;   // 60000
  const int E = in_sizes[4];        // 240000
  const int G = out_size;           // 1024

  // ---- workspace carve-up ----
  char* base = (char*)d_ws;
  size_t off = 0;
  auto alloc = [&](size_t bytes) { char* p = base + off; off += (bytes + 255) & ~(size_t)255; return p; };
  float*  nb     = (float*)alloc((size_t)N * 128 * 4);   // node state fp32 (atomic target)
  ushort* f_ni   = (ushort*)alloc((size_t)N * 128 * 2);
  ushort* f_nj   = (ushort*)alloc((size_t)N * 128 * 2);
  ushort* f_node = (ushort*)alloc((size_t)N * 128 * 2);
  ushort* eb     = (ushort*)alloc((size_t)E * 128 * 2);  // edge state bf16, in-place
  float*  ex     = (float*)alloc((size_t)E * 4 * 4);
  float*  denom  = (float*)alloc((size_t)N * 4 * 4);
  ushort* Wt_ni  = (ushort*)alloc(128 * 128 * 2);
  ushort* Wt_nj  = (ushort*)alloc(128 * 128 * 2);
  ushort* Wt_f   = (ushort*)alloc(128 * 128 * 2);
  ushort* Wt_nd  = (ushort*)alloc(128 * 128 * 2);
  float*  SnP    = (float*)alloc((size_t)G * 128 * 4);
  float*  SnR    = (float*)alloc((size_t)G * 128 * 4);
  float*  SeP    = (float*)alloc((size_t)G * 128 * 4);
  float*  SeR    = (float*)alloc((size_t)G * 128 * 4);
  float*  Gf     = (float*)alloc((size_t)G * 256 * 4);
  float*  x1     = (float*)alloc((size_t)G * 512 * 4);
  float*  x2     = (float*)alloc((size_t)G * 256 * 4);
  int*    cnt_n  = (int*)alloc((size_t)G * 4);
  int*    cnt_e  = (int*)alloc((size_t)G * 4);
  if (off > ws_size) return;  // graceful fail

  // ---- prep egat2 weights (bf16, transposed, swizzled) ----
  prep_w<<<1, 256, 0, stream>>>(w2.Wni,   Wt_ni);
  prep_w<<<1, 256, 0, stream>>>(w2.Wnj,   Wt_nj);
  prep_w<<<1, 256, 0, stream>>>(w2.Wf,    Wt_f);
  prep_w<<<1, 256, 0, stream>>>(w2.Wnode, Wt_nd);

  const int EB4 = (E + 3) / 4;

  auto layer1 = [&](const float* h, const float* e, const int* src, const int* dst) {
    lin3_small<17><<<(N + 15) / 16, 128, 0, stream>>>(h, w1.Wni, w1.bni, w1.Wnj, w1.bnj,
                                                      w1.Wnode, w1.bnode, f_ni, f_nj, f_node, N);
    lin1_small<15><<<(E + 15) / 16, 128, 0, stream>>>(e, w1.Wf, w1.bf, eb, E);
    fillz<<<(N * 4 + 255) / 256, 256, 0, stream>>>(denom, N * 4);
    edge_fuse<<<EB4, 256, 0, stream>>>(f_ni, f_nj, eb, src, dst, w1.attn, ex, denom, E);
    fillz4<<<(N * 32 + 255) / 256, 256, 0, stream>>>((float4*)nb, N * 32);
    scatter_msg<<<EB4, 256, 0, stream>>>(f_node, ex, denom, src, dst, nb, E);
  };
  auto layer2 = [&](const int* src, const int* dst) {
    gemm_k128<float, ushort><<<(N + 127) / 128, 256, 0, stream>>>(nb, Wt_ni, w2.bni, f_ni, N);
    gemm_k128<float, ushort><<<(N + 127) / 128, 256, 0, stream>>>(nb, Wt_nj, w2.bnj, f_nj, N);
    gemm_k128<float, ushort><<<(N + 127) / 128, 256, 0, stream>>>(nb, Wt_nd, w2.bnode, f_node, N);
    gemm_k128<ushort, ushort><<<(E + 127) / 128, 256, 0, stream>>>(eb, Wt_f, w2.bf, eb, E);
    fillz<<<(N * 4 + 255) / 256, 256, 0, stream>>>(denom, N * 4);
    edge_fuse<<<EB4, 256, 0, stream>>>(f_ni, f_nj, eb, src, dst, w2.attn, ex, denom, E);
    fillz4<<<(N * 32 + 255) / 256, 256, 0, stream>>>((float4*)nb, N * 32);
    scatter_msg<<<EB4, 256, 0, stream>>>(f_node, ex, denom, src, dst, nb, E);
  };

  // ---- P branch: one egat1 layer, reduce to G x 128 ----
  layer1(hP, eP, srcP, dstP);
  segsum<float><<<G, 128, 0, stream>>>(nb, nid, N, SnP, cnt_n);
  segsum<ushort><<<G, 128, 0, stream>>>(eb, eid, E, SeP, cnt_e);

  // ---- R branch: egat1 + egat2 x2 ----
  layer1(hR, eR, srcR, dstR);
  layer2(srcR, dstR);
  layer2(srcR, dstR);
  segsum<float><<<G, 128, 0, stream>>>(nb, nid, N, SnR, nullptr);
  segsum<ushort><<<G, 128, 0, stream>>>(eb, eid, E, SeR, nullptr);

  // ---- Diff aggregate + per-graph linears (linear commutes with segment sum) ----
  diff_linear<<<G, 128, 0, stream>>>(SnP, SnR, cnt_n, Wa_n, ba_n, Gf, 256, 0);
  diff_linear<<<G, 128, 0, stream>>>(SeP, SeR, cnt_e, Wa_e, ba_e, Gf, 256, 128);

  // ---- MLP head ----
  mlp_linear<256, 512, true><<<G, 512, 0, stream>>>(Gf, Wm1, bm1, x1);
  mlp_linear<512, 256, true><<<G, 256, 0, stream>>>(x1, Wm2, bm2, x2);
  mlp_final<<<(G + 255) / 256, 256, 0, stream>>>(x2, Wm3, bm3, (float*)d_out, G);
}

// Round 4
// 1128.752 us; speedup vs baseline: 2.4260x; 1.4141x over previous
//
#include <hip/hip_runtime.h>
#include <cstddef>
#include <cstdint>

typedef unsigned int uint;
typedef unsigned short ushort;
typedef __attribute__((ext_vector_type(4))) float f32x4;
typedef __attribute__((ext_vector_type(8))) short short8;

// ---------- bf16 helpers (storage = ushort) ----------
__device__ __forceinline__ ushort f2b(float v) {
  uint x = __float_as_uint(v);
  return (ushort)((x + 0x7fffu + ((x >> 16) & 1u)) >> 16);  // RNE
}
__device__ __forceinline__ float b2f_lo(uint u) { return __uint_as_float(u << 16); }
__device__ __forceinline__ float b2f_hi(uint u) { return __uint_as_float(u & 0xffff0000u); }
__device__ __forceinline__ float ld1(const float* p) { return *p; }
__device__ __forceinline__ float ld1(const ushort* p) { return __uint_as_float(((uint)*p) << 16); }
__device__ __forceinline__ void st1(float* p, float v) { *p = v; }
__device__ __forceinline__ void st1(ushort* p, float v) { *p = f2b(v); }

// load 8 consecutive elems as packed bf16 (uint4 = 8 x bf16)
__device__ __forceinline__ uint4 ldA8(const float* p) {
  float4 a = *(const float4*)p;
  float4 b = *(const float4*)(p + 4);
  uint4 r;
  r.x = (uint)f2b(a.x) | ((uint)f2b(a.y) << 16);
  r.y = (uint)f2b(a.z) | ((uint)f2b(a.w) << 16);
  r.z = (uint)f2b(b.x) | ((uint)f2b(b.y) << 16);
  r.w = (uint)f2b(b.z) | ((uint)f2b(b.w) << 16);
  return r;
}
__device__ __forceinline__ uint4 ldA8(const ushort* p) { return *(const uint4*)p; }

__device__ __forceinline__ int lowerb(const int* __restrict__ ids, int M, int v) {
  int lo = 0, hi = M;
  while (lo < hi) { int mid = (lo + hi) >> 1; if (ids[mid] < v) lo = mid + 1; else hi = mid; }
  return lo;
}

__global__ void fillzi(int* p, int n) {
  int i = blockIdx.x * 256 + threadIdx.x;
  if (i < n) p[i] = 0;
}

// ---------- CSR build: edges sorted by dst ----------
__global__ void hist_dst(const int* __restrict__ dst, int* __restrict__ cnt, int E) {
  int e = blockIdx.x * 256 + threadIdx.x;
  if (e < E) atomicAdd(&cnt[dst[e]], 1);
}

// single block, 1024 threads: exclusive scan of cnt[N] -> rowptr[N+1] (+ cursor copy)
__global__ __launch_bounds__(1024) void exscan(const int* __restrict__ cnt,
                                               int* __restrict__ rowptr,
                                               int* __restrict__ cursor, int N) {
  __shared__ int part[1024];
  int t = threadIdx.x;
  int chunk = (N + 1023) >> 10;
  int s0 = t * chunk, s1 = s0 + chunk; if (s1 > N) s1 = N; if (s0 > N) s0 = N;
  int s = 0;
  for (int i = s0; i < s1; ++i) s += cnt[i];
  part[t] = s;
  __syncthreads();
  for (int ofs = 1; ofs < 1024; ofs <<= 1) {
    int v = (t >= ofs) ? part[t - ofs] : 0;
    __syncthreads();
    part[t] += v;
    __syncthreads();
  }
  int base = (t == 0) ? 0 : part[t - 1];
  for (int i = s0; i < s1; ++i) {
    rowptr[i] = base; cursor[i] = base;
    base += cnt[i];
  }
  if (t == 0) rowptr[N] = part[1023];
}

__global__ void scatter_idx(const int* __restrict__ dst, int* __restrict__ cursor,
                            int* __restrict__ eperm, int E) {
  int e = blockIdx.x * 256 + threadIdx.x;
  if (e < E) {
    int p = atomicAdd(&cursor[dst[e]], 1);
    eperm[p] = e;
  }
}

// ---------- prep: W[128][128] fp32 -> transposed, bf16, XOR-swizzled image ----------
__global__ void prep_w(const float* __restrict__ W, ushort* __restrict__ Wt) {
  int t = threadIdx.x;        // 256 threads, 1 block
  int n = t >> 1;
  int k0 = (t & 1) * 64;
  uint sw = (uint)(n & 7) << 3;
  for (int kk = 0; kk < 64; ++kk) {
    int k = k0 + kk;
    Wt[n * 128 + (k ^ sw)] = f2b(W[k * 128 + n]);
  }
}

// ---------- MFMA GEMM: Y[M,128](ldy) = X[M,128](ldx) @ W[128,128] + b ----------
// In-place safe (Y==X): each block reads only the rows it writes, via LDS.
template<typename TIn, typename TOut>
__global__ __launch_bounds__(256) void gemm_k128(const TIn* X, int ldx,
                                                 const ushort* __restrict__ Wt,
                                                 const float* __restrict__ b,
                                                 TOut* Y, int ldy, int M) {
  __shared__ ushort As[128 * 128];
  __shared__ ushort Bs[128 * 128];
  int t = threadIdx.x;
  int row0 = blockIdx.x * 128;

  { // stage B: linear copy (pre-swizzled in global)
    const uint4* s4 = (const uint4*)Wt + t * 8;
    uint4* d4 = (uint4*)Bs + t * 8;
#pragma unroll
    for (int c = 0; c < 8; ++c) d4[c] = s4[c];
  }
  { // stage A: row r = t>>1, k-half = (t&1)*64; convert to bf16, swizzled store
    int r = t >> 1;
    int k0h = (t & 1) * 64;
    int grow = row0 + r;
    uint sw = (uint)(r & 7) << 3;
    if (grow < M) {
      const TIn* xr = X + (size_t)grow * ldx;
#pragma unroll
      for (int c = 0; c < 8; ++c) {
        int k0 = k0h + c * 8;
        *(uint4*)(As + r * 128 + (k0 ^ sw)) = ldA8(xr + k0);
      }
    } else {
      uint4 z = make_uint4(0, 0, 0, 0);
#pragma unroll
      for (int c = 0; c < 8; ++c) {
        int k0 = k0h + c * 8;
        *(uint4*)(As + r * 128 + (k0 ^ sw)) = z;
      }
    }
  }
  __syncthreads();

  int lane = t & 63;
  int wid = t >> 6;
  int wr = wid >> 1, wc = wid & 1;
  uint swl = (uint)(lane & 7) << 3;

  f32x4 acc[4][4];
#pragma unroll
  for (int n4 = 0; n4 < 4; ++n4) {
    float bv = b[wc * 64 + n4 * 16 + (lane & 15)];
#pragma unroll
    for (int m4 = 0; m4 < 4; ++m4) acc[m4][n4] = (f32x4){bv, bv, bv, bv};
  }

#pragma unroll
  for (int kk = 0; kk < 4; ++kk) {
    int kidx = kk * 32 + 8 * (lane >> 4);
    short8 af[4], bfr[4];
#pragma unroll
    for (int m4 = 0; m4 < 4; ++m4) {
      int rm = wr * 64 + m4 * 16 + (lane & 15);
      af[m4] = *(const short8*)(As + rm * 128 + (kidx ^ swl));
    }
#pragma unroll
    for (int n4 = 0; n4 < 4; ++n4) {
      int cn = wc * 64 + n4 * 16 + (lane & 15);
      bfr[n4] = *(const short8*)(Bs + cn * 128 + (kidx ^ swl));
    }
#pragma unroll
    for (int m4 = 0; m4 < 4; ++m4)
#pragma unroll
      for (int n4 = 0; n4 < 4; ++n4)
        acc[m4][n4] = __builtin_amdgcn_mfma_f32_16x16x32_bf16(af[m4], bfr[n4], acc[m4][n4], 0, 0, 0);
  }

  int coln = wc * 64 + (lane & 15);
#pragma unroll
  for (int m4 = 0; m4 < 4; ++m4) {
    int rb = row0 + wr * 64 + m4 * 16 + ((lane >> 4) << 2);
#pragma unroll
    for (int n4 = 0; n4 < 4; ++n4) {
      int cc = coln + n4 * 16;
#pragma unroll
      for (int i = 0; i < 4; ++i)
        if (rb + i < M) st1(Y + (size_t)(rb + i) * ldy + cc, acc[m4][n4][i]);
    }
  }
}

// ---------- layer-1 fused node linears: ni+node -> f_nin[N][256], nj -> f_nj ----------
template<int K>
__global__ __launch_bounds__(128) void lin3_small(const float* __restrict__ X,
    const float* __restrict__ W1, const float* __restrict__ b1,
    const float* __restrict__ W2, const float* __restrict__ b2,
    const float* __restrict__ W3, const float* __restrict__ b3,
    ushort* __restrict__ Ynin, ushort* __restrict__ Ynj, int M) {
  constexpr int ROWS = 16;
  __shared__ float xs[ROWS * K];
  int t = threadIdx.x;
  int row0 = blockIdx.x * ROWS;
  int nr = M - row0; if (nr > ROWS) nr = ROWS;
  for (int i = t; i < nr * K; i += 128) xs[i] = X[(size_t)row0 * K + i];
  __syncthreads();
  float a1[ROWS], a2[ROWS], a3[ROWS];
  float v1 = b1[t], v2 = b2[t], v3 = b3[t];
#pragma unroll
  for (int r = 0; r < ROWS; ++r) { a1[r] = v1; a2[r] = v2; a3[r] = v3; }
#pragma unroll
  for (int k = 0; k < K; ++k) {
    float w1 = W1[k * 128 + t], w2 = W2[k * 128 + t], w3 = W3[k * 128 + t];
#pragma unroll
    for (int r = 0; r < ROWS; ++r) {
      float x = xs[r * K + k];
      a1[r] = fmaf(x, w1, a1[r]);
      a2[r] = fmaf(x, w2, a2[r]);
      a3[r] = fmaf(x, w3, a3[r]);
    }
  }
  for (int r = 0; r < nr; ++r) {
    size_t n = (size_t)(row0 + r);
    Ynin[n * 256 + t] = f2b(a1[r]);        // f_ni
    Ynin[n * 256 + 128 + t] = f2b(a3[r]);  // f_node
    Ynj[n * 128 + t] = f2b(a2[r]);
  }
}

// ---------- layer-1 edge linear (K=15) ----------
template<int K>
__global__ __launch_bounds__(128) void lin1_small(const float* __restrict__ X,
    const float* __restrict__ W, const float* __restrict__ b,
    ushort* __restrict__ Y, int M) {
  constexpr int ROWS = 16;
  __shared__ float xs[ROWS * K];
  int t = threadIdx.x;
  int row0 = blockIdx.x * ROWS;
  int nr = M - row0; if (nr > ROWS) nr = ROWS;
  for (int i = t; i < nr * K; i += 128) xs[i] = X[(size_t)row0 * K + i];
  __syncthreads();
  float acc[ROWS];
  float bias = b[t];
#pragma unroll
  for (int r = 0; r < ROWS; ++r) acc[r] = bias;
#pragma unroll
  for (int k = 0; k < K; ++k) {
    float w = W[k * 128 + t];
#pragma unroll
    for (int r = 0; r < ROWS; ++r) acc[r] = fmaf(xs[r * K + k], w, acc[r]);
  }
  for (int r = 0; r < nr; ++r) Y[(size_t)(row0 + r) * 128 + t] = f2b(acc[r]);
}

// ---------- fused edge+aggregate stage (CSR over dst) ----------
// One wave per dst node d. For each incoming edge e:
//   f_out = leaky_relu(f_ni[src] + f_nj[d] + eb[e])  (written back to eb[e])
//   logit -> ex = exp(logit) ; exsum += ex ; acc += f_node[src] * ex
// Then nb[d] = acc / exsum (0 if no edges). No atomics anywhere.
__global__ void egat_gather(const ushort* __restrict__ f_nin,   // [N][256] = ni | node
                            const ushort* __restrict__ f_nj,    // [N][128]
                            ushort* eb,                          // [E][128] in/out
                            const int* __restrict__ src,
                            const int* __restrict__ rowptr,
                            const int* __restrict__ eperm,
                            const float* __restrict__ attn,
                            float* __restrict__ nb, int N) {
  int d = blockIdx.x * 4 + (threadIdx.x >> 6);
  if (d >= N) return;
  int lane = threadIdx.x & 63;
  int lo = rowptr[d], hi = rowptr[d + 1];
  int h = lane >> 4;
  float2 at = *(const float2*)(attn + h * 32 + (lane & 15) * 2);
  uint unj = *((const uint*)(f_nj + (size_t)d * 128) + lane);
  float nj0 = b2f_lo(unj), nj1 = b2f_hi(unj);
  float acc0 = 0.f, acc1 = 0.f, exsum = 0.f;
  for (int i = lo; i < hi; ++i) {
    int e = eperm[i];
    int s = src[e];
    const uint* pn = (const uint*)(f_nin + (size_t)s * 256);
    uint uni = pn[lane];        // f_ni[s]
    uint und = pn[64 + lane];   // f_node[s]
    uint* ep = (uint*)(eb + (size_t)e * 128) + lane;
    uint ue = *ep;
    float v0 = b2f_lo(ue) + b2f_lo(uni) + nj0;
    float v1 = b2f_hi(ue) + b2f_hi(uni) + nj1;
    v0 = v0 >= 0.f ? v0 : 0.01f * v0;
    v1 = v1 >= 0.f ? v1 : 0.01f * v1;
    *ep = (uint)f2b(v0) | ((uint)f2b(v1) << 16);
    float p = v0 * at.x + v1 * at.y;
    p += __shfl_xor(p, 1);
    p += __shfl_xor(p, 2);
    p += __shfl_xor(p, 4);
    p += __shfl_xor(p, 8);            // all 16 lanes of head h hold the logit
    float ev = __expf(p);             // softmax shift-invariant; logits O(1)
    exsum += ev;
    acc0 = fmaf(b2f_lo(und), ev, acc0);
    acc1 = fmaf(b2f_hi(und), ev, acc1);
  }
  float inv = exsum > 0.f ? 1.f / exsum : 0.f;
  float2* out = (float2*)(nb + (size_t)d * 128) + lane;
  *out = make_float2(acc0 * inv, acc1 * inv);
}

// ---------- S[g,:] = sum of X rows with (sorted) id == g ----------
template<typename T>
__global__ void segsum(const T* __restrict__ X, const int* __restrict__ ids, int M,
                       float* __restrict__ S, int* __restrict__ cnt) {
  __shared__ int bounds[2];
  int g = blockIdx.x;
  if (threadIdx.x == 0) { bounds[0] = lowerb(ids, M, g); bounds[1] = lowerb(ids, M, g + 1); }
  __syncthreads();
  int lo = bounds[0], hi = bounds[1];
  int t = threadIdx.x;
  float acc = 0.f;
  for (int r = lo; r < hi; ++r) acc += ld1(X + (size_t)r * 128 + t);
  S[(size_t)g * 128 + t] = acc;
  if (t == 0 && cnt) cnt[g] = hi - lo;
}

// ---------- out[g, coloff+t] = (SP[g]-SR[g]) @ W + cnt[g]*b ----------
__global__ void diff_linear(const float* __restrict__ SP, const float* __restrict__ SR,
                            const int* __restrict__ cnt,
                            const float* __restrict__ W, const float* __restrict__ b,
                            float* __restrict__ out, int ldo, int coloff) {
  int g = blockIdx.x;
  int t = threadIdx.x;
  __shared__ float xs[128];
  xs[t] = SP[(size_t)g * 128 + t] - SR[(size_t)g * 128 + t];
  __syncthreads();
  float acc = (float)cnt[g] * b[t];
  for (int k = 0; k < 128; ++k) acc = fmaf(xs[k], W[k * 128 + t], acc);
  out[(size_t)g * ldo + coloff + t] = acc;
}

template<int K, int NC, bool RELU>
__global__ void mlp_linear(const float* __restrict__ X, const float* __restrict__ W,
                           const float* __restrict__ b, float* __restrict__ Y) {
  int g = blockIdx.x;
  int t = threadIdx.x;
  __shared__ float xs[K];
  for (int i = t; i < K; i += NC) xs[i] = X[(size_t)g * K + i];
  __syncthreads();
  float acc = b[t];
  for (int k = 0; k < K; ++k) acc = fmaf(xs[k], W[k * NC + t], acc);
  if (RELU) acc = fmaxf(acc, 0.f);
  Y[(size_t)g * NC + t] = acc;
}

__global__ void mlp_final(const float* __restrict__ X, const float* __restrict__ W,
                          const float* __restrict__ b, float* __restrict__ out, int G) {
  int g = blockIdx.x * blockDim.x + threadIdx.x;
  if (g >= G) return;
  float acc = b[0];
  for (int k = 0; k < 256; ++k) acc = fmaf(X[(size_t)g * 256 + k], W[k], acc);
  out[g] = acc;
}

struct LayerW {
  const float *Wni, *bni, *Wnj, *bnj, *Wf, *bf, *Wnode, *bnode, *attn;
};

extern "C" void kernel_launch(void* const* d_in, const int* in_sizes, int n_in,
                              void* d_out, int out_size, void* d_ws, size_t ws_size,
                              hipStream_t stream) {
  const float* hR = (const float*)d_in[0];
  const float* eR = (const float*)d_in[1];
  const float* hP = (const float*)d_in[2];
  const float* eP = (const float*)d_in[3];
  const int* srcR = (const int*)d_in[4];
  const int* dstR = (const int*)d_in[5];
  const int* srcP = (const int*)d_in[6];
  const int* dstP = (const int*)d_in[7];
  const int* nid  = (const int*)d_in[8];
  const int* eid  = (const int*)d_in[9];
  LayerW w1 { (const float*)d_in[10], (const float*)d_in[11], (const float*)d_in[12],
              (const float*)d_in[13], (const float*)d_in[14], (const float*)d_in[15],
              (const float*)d_in[16], (const float*)d_in[17], (const float*)d_in[18] };
  LayerW w2 { (const float*)d_in[19], (const float*)d_in[20], (const float*)d_in[21],
              (const float*)d_in[22], (const float*)d_in[23], (const float*)d_in[24],
              (const float*)d_in[25], (const float*)d_in[26], (const float*)d_in[27] };
  const float* Wa_n = (const float*)d_in[28];
  const float* ba_n = (const float*)d_in[29];
  const float* Wa_e = (const float*)d_in[30];
  const float* ba_e = (const float*)d_in[31];
  const float* Wm1  = (const float*)d_in[32];
  const float* bm1  = (const float*)d_in[33];
  const float* Wm2  = (const float*)d_in[34];
  const float* bm2  = (const float*)d_in[35];
  const float* Wm3  = (const float*)d_in[36];
  const float* bm3  = (const float*)d_in[37];

  const int N = in_sizes[0] / 17;   // 60000
  const int E = in_sizes[4];        // 240000
  const int G = out_size;           // 1024

  // ---- workspace carve-up ----
  char* base = (char*)d_ws;
  size_t off = 0;
  auto alloc = [&](size_t bytes) { char* p = base + off; off += (bytes + 255) & ~(size_t)255; return p; };
  float*  nb     = (float*)alloc((size_t)N * 128 * 4);    // node state fp32
  ushort* f_nin  = (ushort*)alloc((size_t)N * 256 * 2);   // [ni | node] fused rows
  ushort* f_nj   = (ushort*)alloc((size_t)N * 128 * 2);
  ushort* eb     = (ushort*)alloc((size_t)E * 128 * 2);   // edge state bf16, in-place
  int*    rowptrP = (int*)alloc((size_t)(N + 1) * 4);
  int*    rowptrR = (int*)alloc((size_t)(N + 1) * 4);
  int*    epermP  = (int*)alloc((size_t)E * 4);
  int*    epermR  = (int*)alloc((size_t)E * 4);
  int*    cnt     = (int*)alloc((size_t)N * 4);
  int*    cursor  = (int*)alloc((size_t)N * 4);
  ushort* Wt_ni  = (ushort*)alloc(128 * 128 * 2);
  ushort* Wt_nj  = (ushort*)alloc(128 * 128 * 2);
  ushort* Wt_f   = (ushort*)alloc(128 * 128 * 2);
  ushort* Wt_nd  = (ushort*)alloc(128 * 128 * 2);
  float*  SnP    = (float*)alloc((size_t)G * 128 * 4);
  float*  SnR    = (float*)alloc((size_t)G * 128 * 4);
  float*  SeP    = (float*)alloc((size_t)G * 128 * 4);
  float*  SeR    = (float*)alloc((size_t)G * 128 * 4);
  float*  Gf     = (float*)alloc((size_t)G * 256 * 4);
  float*  x1     = (float*)alloc((size_t)G * 512 * 4);
  float*  x2     = (float*)alloc((size_t)G * 256 * 4);
  int*    cnt_n  = (int*)alloc((size_t)G * 4);
  int*    cnt_e  = (int*)alloc((size_t)G * 4);
  if (off > ws_size) return;  // graceful fail

  const int EB = (E + 255) / 256;
  const int NB = (N + 255) / 256;

  // ---- CSR builds (P, then R; cnt/cursor shared, sequential in-stream) ----
  fillzi<<<NB, 256, 0, stream>>>(cnt, N);
  hist_dst<<<EB, 256, 0, stream>>>(dstP, cnt, E);
  exscan<<<1, 1024, 0, stream>>>(cnt, rowptrP, cursor, N);
  scatter_idx<<<EB, 256, 0, stream>>>(dstP, cursor, epermP, E);
  fillzi<<<NB, 256, 0, stream>>>(cnt, N);
  hist_dst<<<EB, 256, 0, stream>>>(dstR, cnt, E);
  exscan<<<1, 1024, 0, stream>>>(cnt, rowptrR, cursor, N);
  scatter_idx<<<EB, 256, 0, stream>>>(dstR, cursor, epermR, E);

  // ---- prep egat2 weights (bf16, transposed, swizzled) ----
  prep_w<<<1, 256, 0, stream>>>(w2.Wni,   Wt_ni);
  prep_w<<<1, 256, 0, stream>>>(w2.Wnj,   Wt_nj);
  prep_w<<<1, 256, 0, stream>>>(w2.Wf,    Wt_f);
  prep_w<<<1, 256, 0, stream>>>(w2.Wnode, Wt_nd);

  const int GB = (N + 3) / 4;      // egat_gather grid

  auto layer1 = [&](const float* h, const float* e, const int* src,
                    const int* rowptr, const int* eperm) {
    lin3_small<17><<<(N + 15) / 16, 128, 0, stream>>>(h, w1.Wni, w1.bni, w1.Wnj, w1.bnj,
                                                      w1.Wnode, w1.bnode, f_nin, f_nj, N);
    lin1_small<15><<<(E + 15) / 16, 128, 0, stream>>>(e, w1.Wf, w1.bf, eb, E);
    egat_gather<<<GB, 256, 0, stream>>>(f_nin, f_nj, eb, src, rowptr, eperm, w1.attn, nb, N);
  };
  auto layer2 = [&](const int* src, const int* rowptr, const int* eperm) {
    gemm_k128<float, ushort><<<(N + 127) / 128, 256, 0, stream>>>(nb, 128, Wt_ni, w2.bni, f_nin, 256, N);
    gemm_k128<float, ushort><<<(N + 127) / 128, 256, 0, stream>>>(nb, 128, Wt_nd, w2.bnode, f_nin + 128, 256, N);
    gemm_k128<float, ushort><<<(N + 127) / 128, 256, 0, stream>>>(nb, 128, Wt_nj, w2.bnj, f_nj, 128, N);
    gemm_k128<ushort, ushort><<<(E + 127) / 128, 256, 0, stream>>>(eb, 128, Wt_f, w2.bf, eb, 128, E);
    egat_gather<<<GB, 256, 0, stream>>>(f_nin, f_nj, eb, src, rowptr, eperm, w2.attn, nb, N);
  };

  // ---- P branch: one egat1 layer, reduce to G x 128 ----
  layer1(hP, eP, srcP, rowptrP, epermP);
  segsum<float><<<G, 128, 0, stream>>>(nb, nid, N, SnP, cnt_n);
  segsum<ushort><<<G, 128, 0, stream>>>(eb, eid, E, SeP, cnt_e);

  // ---- R branch: egat1 + egat2 x2 ----
  layer1(hR, eR, srcR, rowptrR, epermR);
  layer2(srcR, rowptrR, epermR);
  layer2(srcR, rowptrR, epermR);
  segsum<float><<<G, 128, 0, stream>>>(nb, nid, N, SnR, nullptr);
  segsum<ushort><<<G, 128, 0, stream>>>(eb, eid, E, SeR, nullptr);

  // ---- Diff aggregate + per-graph linears ----
  diff_linear<<<G, 128, 0, stream>>>(SnP, SnR, cnt_n, Wa_n, ba_n, Gf, 256, 0);
  diff_linear<<<G, 128, 0, stream>>>(SeP, SeR, cnt_e, Wa_e, ba_e, Gf, 256, 128);

  // ---- MLP head ----
  mlp_linear<256, 512, true><<<G, 512, 0, stream>>>(Gf, Wm1, bm1, x1);
  mlp_linear<512, 256, true><<<G, 256, 0, stream>>>(x1, Wm2, bm2, x2);
  mlp_final<<<(G + 255) / 256, 256, 0, stream>>>(x2, Wm3, bm3, (float*)d_out, G);
}

// Round 5
// 883.395 us; speedup vs baseline: 3.0998x; 1.2777x over previous
//
#include <hip/hip_runtime.h>
#include <cstddef>
#include <cstdint>

typedef unsigned int uint;
typedef unsigned short ushort;
typedef __attribute__((ext_vector_type(4))) float f32x4;
typedef __attribute__((ext_vector_type(8))) short short8;

// ---------- bf16 helpers (storage = ushort) ----------
__device__ __forceinline__ ushort f2b(float v) {
  uint x = __float_as_uint(v);
  return (ushort)((x + 0x7fffu + ((x >> 16) & 1u)) >> 16);  // RNE
}
__device__ __forceinline__ float b2f_lo(uint u) { return __uint_as_float(u << 16); }
__device__ __forceinline__ float b2f_hi(uint u) { return __uint_as_float(u & 0xffff0000u); }
__device__ __forceinline__ float ld1(const float* p) { return *p; }
__device__ __forceinline__ float ld1(const ushort* p) { return __uint_as_float(((uint)*p) << 16); }
__device__ __forceinline__ void st1(float* p, float v) { *p = v; }
__device__ __forceinline__ void st1(ushort* p, float v) { *p = f2b(v); }

// load 8 consecutive elems as packed bf16 (uint4 = 8 x bf16)
__device__ __forceinline__ uint4 ldA8(const float* p) {
  float4 a = *(const float4*)p;
  float4 b = *(const float4*)(p + 4);
  uint4 r;
  r.x = (uint)f2b(a.x) | ((uint)f2b(a.y) << 16);
  r.y = (uint)f2b(a.z) | ((uint)f2b(a.w) << 16);
  r.z = (uint)f2b(b.x) | ((uint)f2b(b.y) << 16);
  r.w = (uint)f2b(b.z) | ((uint)f2b(b.w) << 16);
  return r;
}
__device__ __forceinline__ uint4 ldA8(const ushort* p) { return *(const uint4*)p; }

__device__ __forceinline__ int lowerb(const int* __restrict__ ids, int M, int v) {
  int lo = 0, hi = M;
  while (lo < hi) { int mid = (lo + hi) >> 1; if (ids[mid] < v) lo = mid + 1; else hi = mid; }
  return lo;
}

__global__ void fillzi(int* p, int n) {
  int i = blockIdx.x * 256 + threadIdx.x;
  if (i < n) p[i] = 0;
}

// ---------- CSR build: edges sorted by dst ----------
__global__ void hist_dst(const int* __restrict__ dst, int* __restrict__ cnt, int E) {
  int e = blockIdx.x * 256 + threadIdx.x;
  if (e < E) atomicAdd(&cnt[dst[e]], 1);
}

// multi-block exclusive scan, phase 1: per-block local exclusive scan + block sums
__global__ void scan_local(const int* __restrict__ cnt, int* __restrict__ rowptr,
                           int* __restrict__ blocksum, int N) {
  __shared__ int tmp[256];
  int t = threadIdx.x;
  int i = blockIdx.x * 256 + t;
  int v = (i < N) ? cnt[i] : 0;
  tmp[t] = v;
  __syncthreads();
  for (int ofs = 1; ofs < 256; ofs <<= 1) {
    int u = (t >= ofs) ? tmp[t - ofs] : 0;
    __syncthreads();
    tmp[t] += u;
    __syncthreads();
  }
  if (i < N) rowptr[i] = tmp[t] - v;          // exclusive
  if (t == 255) blocksum[blockIdx.x] = tmp[255];
}

// phase 2: single tiny block scans the <=256 block sums (exclusive, in place)
__global__ void scan_block(int* __restrict__ bs, int n) {
  __shared__ int tmp[256];
  int t = threadIdx.x;
  int v = (t < n) ? bs[t] : 0;
  tmp[t] = v;
  __syncthreads();
  for (int ofs = 1; ofs < 256; ofs <<= 1) {
    int u = (t >= ofs) ? tmp[t - ofs] : 0;
    __syncthreads();
    tmp[t] += u;
    __syncthreads();
  }
  if (t < n) bs[t] = tmp[t] - v;              // exclusive
}

// phase 3: add block offsets, mirror into cursor, set rowptr[N]=E
__global__ void scan_add(int* __restrict__ rowptr, int* __restrict__ cursor,
                         const int* __restrict__ blocksum, int N, int E) {
  int i = blockIdx.x * 256 + threadIdx.x;
  if (i < N) {
    int v = rowptr[i] + blocksum[blockIdx.x];
    rowptr[i] = v;
    cursor[i] = v;
  }
  if (i == 0) rowptr[N] = E;
}

__global__ void scatter_idx(const int* __restrict__ dst, int* __restrict__ cursor,
                            int* __restrict__ eperm, int E) {
  int e = blockIdx.x * 256 + threadIdx.x;
  if (e < E) {
    int p = atomicAdd(&cursor[dst[e]], 1);
    eperm[p] = e;
  }
}

// ---------- prep: W[128][128] fp32 -> transposed, bf16, XOR-swizzled image ----------
__global__ void prep_w(const float* __restrict__ W, ushort* __restrict__ Wt) {
  int t = threadIdx.x;        // 256 threads, 1 block
  int n = t >> 1;
  int k0 = (t & 1) * 64;
  uint sw = (uint)(n & 7) << 3;
  for (int kk = 0; kk < 64; ++kk) {
    int k = k0 + kk;
    Wt[n * 128 + (k ^ sw)] = f2b(W[k * 128 + n]);
  }
}

// ---------- MFMA GEMM: Y[M,128](ldy) = X[M,128](ldx) @ W[128,128] + b ----------
// In-place safe (Y==X): each block reads only the rows it writes, via LDS.
template<typename TIn, typename TOut>
__global__ __launch_bounds__(256) void gemm_k128(const TIn* X, int ldx,
                                                 const ushort* __restrict__ Wt,
                                                 const float* __restrict__ b,
                                                 TOut* Y, int ldy, int M) {
  __shared__ ushort As[128 * 128];
  __shared__ ushort Bs[128 * 128];
  int t = threadIdx.x;
  int row0 = blockIdx.x * 128;

  { // stage B: linear copy (pre-swizzled in global)
    const uint4* s4 = (const uint4*)Wt + t * 8;
    uint4* d4 = (uint4*)Bs + t * 8;
#pragma unroll
    for (int c = 0; c < 8; ++c) d4[c] = s4[c];
  }
  { // stage A: row r = t>>1, k-half = (t&1)*64; convert to bf16, swizzled store
    int r = t >> 1;
    int k0h = (t & 1) * 64;
    int grow = row0 + r;
    uint sw = (uint)(r & 7) << 3;
    if (grow < M) {
      const TIn* xr = X + (size_t)grow * ldx;
#pragma unroll
      for (int c = 0; c < 8; ++c) {
        int k0 = k0h + c * 8;
        *(uint4*)(As + r * 128 + (k0 ^ sw)) = ldA8(xr + k0);
      }
    } else {
      uint4 z = make_uint4(0, 0, 0, 0);
#pragma unroll
      for (int c = 0; c < 8; ++c) {
        int k0 = k0h + c * 8;
        *(uint4*)(As + r * 128 + (k0 ^ sw)) = z;
      }
    }
  }
  __syncthreads();

  int lane = t & 63;
  int wid = t >> 6;
  int wr = wid >> 1, wc = wid & 1;
  uint swl = (uint)(lane & 7) << 3;

  f32x4 acc[4][4];
#pragma unroll
  for (int n4 = 0; n4 < 4; ++n4) {
    float bv = b[wc * 64 + n4 * 16 + (lane & 15)];
#pragma unroll
    for (int m4 = 0; m4 < 4; ++m4) acc[m4][n4] = (f32x4){bv, bv, bv, bv};
  }

#pragma unroll
  for (int kk = 0; kk < 4; ++kk) {
    int kidx = kk * 32 + 8 * (lane >> 4);
    short8 af[4], bfr[4];
#pragma unroll
    for (int m4 = 0; m4 < 4; ++m4) {
      int rm = wr * 64 + m4 * 16 + (lane & 15);
      af[m4] = *(const short8*)(As + rm * 128 + (kidx ^ swl));
    }
#pragma unroll
    for (int n4 = 0; n4 < 4; ++n4) {
      int cn = wc * 64 + n4 * 16 + (lane & 15);
      bfr[n4] = *(const short8*)(Bs + cn * 128 + (kidx ^ swl));
    }
#pragma unroll
    for (int m4 = 0; m4 < 4; ++m4)
#pragma unroll
      for (int n4 = 0; n4 < 4; ++n4)
        acc[m4][n4] = __builtin_amdgcn_mfma_f32_16x16x32_bf16(af[m4], bfr[n4], acc[m4][n4], 0, 0, 0);
  }

  int coln = wc * 64 + (lane & 15);
#pragma unroll
  for (int m4 = 0; m4 < 4; ++m4) {
    int rb = row0 + wr * 64 + m4 * 16 + ((lane >> 4) << 2);
#pragma unroll
    for (int n4 = 0; n4 < 4; ++n4) {
      int cc = coln + n4 * 16;
#pragma unroll
      for (int i = 0; i < 4; ++i)
        if (rb + i < M) st1(Y + (size_t)(rb + i) * ldy + cc, acc[m4][n4][i]);
    }
  }
}

// ---------- layer-1 fused node linears: ni+node -> f_nin[N][256], nj -> f_nj ----------
template<int K>
__global__ __launch_bounds__(128) void lin3_small(const float* __restrict__ X,
    const float* __restrict__ W1, const float* __restrict__ b1,
    const float* __restrict__ W2, const float* __restrict__ b2,
    const float* __restrict__ W3, const float* __restrict__ b3,
    ushort* __restrict__ Ynin, ushort* __restrict__ Ynj, int M) {
  constexpr int ROWS = 16;
  __shared__ float xs[ROWS * K];
  int t = threadIdx.x;
  int row0 = blockIdx.x * ROWS;
  int nr = M - row0; if (nr > ROWS) nr = ROWS;
  for (int i = t; i < nr * K; i += 128) xs[i] = X[(size_t)row0 * K + i];
  __syncthreads();
  float a1[ROWS], a2[ROWS], a3[ROWS];
  float v1 = b1[t], v2 = b2[t], v3 = b3[t];
#pragma unroll
  for (int r = 0; r < ROWS; ++r) { a1[r] = v1; a2[r] = v2; a3[r] = v3; }
#pragma unroll
  for (int k = 0; k < K; ++k) {
    float w1 = W1[k * 128 + t], w2 = W2[k * 128 + t], w3 = W3[k * 128 + t];
#pragma unroll
    for (int r = 0; r < ROWS; ++r) {
      float x = xs[r * K + k];
      a1[r] = fmaf(x, w1, a1[r]);
      a2[r] = fmaf(x, w2, a2[r]);
      a3[r] = fmaf(x, w3, a3[r]);
    }
  }
  for (int r = 0; r < nr; ++r) {
    size_t n = (size_t)(row0 + r);
    Ynin[n * 256 + t] = f2b(a1[r]);        // f_ni
    Ynin[n * 256 + 128 + t] = f2b(a3[r]);  // f_node
    Ynj[n * 128 + t] = f2b(a2[r]);
  }
}

// ---------- layer-1 edge linear (K=15) ----------
template<int K>
__global__ __launch_bounds__(128) void lin1_small(const float* __restrict__ X,
    const float* __restrict__ W, const float* __restrict__ b,
    ushort* __restrict__ Y, int M) {
  constexpr int ROWS = 16;
  __shared__ float xs[ROWS * K];
  int t = threadIdx.x;
  int row0 = blockIdx.x * ROWS;
  int nr = M - row0; if (nr > ROWS) nr = ROWS;
  for (int i = t; i < nr * K; i += 128) xs[i] = X[(size_t)row0 * K + i];
  __syncthreads();
  float acc[ROWS];
  float bias = b[t];
#pragma unroll
  for (int r = 0; r < ROWS; ++r) acc[r] = bias;
#pragma unroll
  for (int k = 0; k < K; ++k) {
    float w = W[k * 128 + t];
#pragma unroll
    for (int r = 0; r < ROWS; ++r) acc[r] = fmaf(xs[r * K + k], w, acc[r]);
  }
  for (int r = 0; r < nr; ++r) Y[(size_t)(row0 + r) * 128 + t] = f2b(acc[r]);
}

// ---------- fused edge+aggregate stage (CSR over dst) ----------
// One wave per dst node d. For each incoming edge e:
//   f_out = leaky_relu(f_ni[src] + f_nj[d] + eb[e])  (written back to eb[e])
//   logit -> ex = exp(logit) ; exsum += ex ; acc += f_node[src] * ex
// Then nb[d] = acc / exsum (0 if no edges). No atomics anywhere.
__global__ void egat_gather(const ushort* __restrict__ f_nin,   // [N][256] = ni | node
                            const ushort* __restrict__ f_nj,    // [N][128]
                            ushort* eb,                          // [E][128] in/out
                            const int* __restrict__ src,
                            const int* __restrict__ rowptr,
                            const int* __restrict__ eperm,
                            const float* __restrict__ attn,
                            float* __restrict__ nb, int N) {
  int d = blockIdx.x * 4 + (threadIdx.x >> 6);
  if (d >= N) return;
  int lane = threadIdx.x & 63;
  int lo = rowptr[d], hi = rowptr[d + 1];
  int h = lane >> 4;
  float2 at = *(const float2*)(attn + h * 32 + (lane & 15) * 2);
  uint unj = *((const uint*)(f_nj + (size_t)d * 128) + lane);
  float nj0 = b2f_lo(unj), nj1 = b2f_hi(unj);
  float acc0 = 0.f, acc1 = 0.f, exsum = 0.f;
  for (int i = lo; i < hi; ++i) {
    int e = eperm[i];
    int s = src[e];
    const uint* pn = (const uint*)(f_nin + (size_t)s * 256);
    uint uni = pn[lane];        // f_ni[s]
    uint und = pn[64 + lane];   // f_node[s]
    uint* ep = (uint*)(eb + (size_t)e * 128) + lane;
    uint ue = *ep;
    float v0 = b2f_lo(ue) + b2f_lo(uni) + nj0;
    float v1 = b2f_hi(ue) + b2f_hi(uni) + nj1;
    v0 = v0 >= 0.f ? v0 : 0.01f * v0;
    v1 = v1 >= 0.f ? v1 : 0.01f * v1;
    *ep = (uint)f2b(v0) | ((uint)f2b(v1) << 16);
    float p = v0 * at.x + v1 * at.y;
    p += __shfl_xor(p, 1);
    p += __shfl_xor(p, 2);
    p += __shfl_xor(p, 4);
    p += __shfl_xor(p, 8);            // all 16 lanes of head h hold the logit
    float ev = __expf(p);             // softmax shift-invariant; logits O(1)
    exsum += ev;
    acc0 = fmaf(b2f_lo(und), ev, acc0);
    acc1 = fmaf(b2f_hi(und), ev, acc1);
  }
  float inv = exsum > 0.f ? 1.f / exsum : 0.f;
  float2* out = (float2*)(nb + (size_t)d * 128) + lane;
  *out = make_float2(acc0 * inv, acc1 * inv);
}

// ---------- S[g,:] = sum of X rows with (sorted) id == g ----------
template<typename T>
__global__ void segsum(const T* __restrict__ X, const int* __restrict__ ids, int M,
                       float* __restrict__ S, int* __restrict__ cnt) {
  __shared__ int bounds[2];
  int g = blockIdx.x;
  if (threadIdx.x == 0) { bounds[0] = lowerb(ids, M, g); bounds[1] = lowerb(ids, M, g + 1); }
  __syncthreads();
  int lo = bounds[0], hi = bounds[1];
  int t = threadIdx.x;
  float acc = 0.f;
  for (int r = lo; r < hi; ++r) acc += ld1(X + (size_t)r * 128 + t);
  S[(size_t)g * 128 + t] = acc;
  if (t == 0 && cnt) cnt[g] = hi - lo;
}

// ---------- out[g, coloff+t] = (SP[g]-SR[g]) @ W + cnt[g]*b ----------
__global__ void diff_linear(const float* __restrict__ SP, const float* __restrict__ SR,
                            const int* __restrict__ cnt,
                            const float* __restrict__ W, const float* __restrict__ b,
                            float* __restrict__ out, int ldo, int coloff) {
  int g = blockIdx.x;
  int t = threadIdx.x;
  __shared__ float xs[128];
  xs[t] = SP[(size_t)g * 128 + t] - SR[(size_t)g * 128 + t];
  __syncthreads();
  float acc = (float)cnt[g] * b[t];
  for (int k = 0; k < 128; ++k) acc = fmaf(xs[k], W[k * 128 + t], acc);
  out[(size_t)g * ldo + coloff + t] = acc;
}

template<int K, int NC, bool RELU>
__global__ void mlp_linear(const float* __restrict__ X, const float* __restrict__ W,
                           const float* __restrict__ b, float* __restrict__ Y) {
  int g = blockIdx.x;
  int t = threadIdx.x;
  __shared__ float xs[K];
  for (int i = t; i < K; i += NC) xs[i] = X[(size_t)g * K + i];
  __syncthreads();
  float acc = b[t];
  for (int k = 0; k < K; ++k) acc = fmaf(xs[k], W[k * NC + t], acc);
  if (RELU) acc = fmaxf(acc, 0.f);
  Y[(size_t)g * NC + t] = acc;
}

__global__ void mlp_final(const float* __restrict__ X, const float* __restrict__ W,
                          const float* __restrict__ b, float* __restrict__ out, int G) {
  int g = blockIdx.x * blockDim.x + threadIdx.x;
  if (g >= G) return;
  float acc = b[0];
  for (int k = 0; k < 256; ++k) acc = fmaf(X[(size_t)g * 256 + k], W[k], acc);
  out[g] = acc;
}

struct LayerW {
  const float *Wni, *bni, *Wnj, *bnj, *Wf, *bf, *Wnode, *bnode, *attn;
};

extern "C" void kernel_launch(void* const* d_in, const int* in_sizes, int n_in,
                              void* d_out, int out_size, void* d_ws, size_t ws_size,
                              hipStream_t stream) {
  const float* hR = (const float*)d_in[0];
  const float* eR = (const float*)d_in[1];
  const float* hP = (const float*)d_in[2];
  const float* eP = (const float*)d_in[3];
  const int* srcR = (const int*)d_in[4];
  const int* dstR = (const int*)d_in[5];
  const int* srcP = (const int*)d_in[6];
  const int* dstP = (const int*)d_in[7];
  const int* nid  = (const int*)d_in[8];
  const int* eid  = (const int*)d_in[9];
  LayerW w1 { (const float*)d_in[10], (const float*)d_in[11], (const float*)d_in[12],
              (const float*)d_in[13], (const float*)d_in[14], (const float*)d_in[15],
              (const float*)d_in[16], (const float*)d_in[17], (const float*)d_in[18] };
  LayerW w2 { (const float*)d_in[19], (const float*)d_in[20], (const float*)d_in[21],
              (const float*)d_in[22], (const float*)d_in[23], (const float*)d_in[24],
              (const float*)d_in[25], (const float*)d_in[26], (const float*)d_in[27] };
  const float* Wa_n = (const float*)d_in[28];
  const float* ba_n = (const float*)d_in[29];
  const float* Wa_e = (const float*)d_in[30];
  const float* ba_e = (const float*)d_in[31];
  const float* Wm1  = (const float*)d_in[32];
  const float* bm1  = (const float*)d_in[33];
  const float* Wm2  = (const float*)d_in[34];
  const float* bm2  = (const float*)d_in[35];
  const float* Wm3  = (const float*)d_in[36];
  const float* bm3  = (const float*)d_in[37];

  const int N = in_sizes[0] / 17;   // 60000
  const int E = in_sizes[4];        // 240000
  const int G = out_size;           // 1024

  // ---- workspace carve-up ----
  char* base = (char*)d_ws;
  size_t off = 0;
  auto alloc = [&](size_t bytes) { char* p = base + off; off += (bytes + 255) & ~(size_t)255; return p; };
  float*  nb     = (float*)alloc((size_t)N * 128 * 4);    // node state fp32
  ushort* f_nin  = (ushort*)alloc((size_t)N * 256 * 2);   // [ni | node] fused rows
  ushort* f_nj   = (ushort*)alloc((size_t)N * 128 * 2);
  ushort* eb     = (ushort*)alloc((size_t)E * 128 * 2);   // edge state bf16, in-place
  int*    rowptrP = (int*)alloc((size_t)(N + 1) * 4);
  int*    rowptrR = (int*)alloc((size_t)(N + 1) * 4);
  int*    epermP  = (int*)alloc((size_t)E * 4);
  int*    epermR  = (int*)alloc((size_t)E * 4);
  int*    cnt     = (int*)alloc((size_t)N * 4);
  int*    cursor  = (int*)alloc((size_t)N * 4);
  int*    blocksum = (int*)alloc(1024 * 4);
  ushort* Wt_ni  = (ushort*)alloc(128 * 128 * 2);
  ushort* Wt_nj  = (ushort*)alloc(128 * 128 * 2);
  ushort* Wt_f   = (ushort*)alloc(128 * 128 * 2);
  ushort* Wt_nd  = (ushort*)alloc(128 * 128 * 2);
  float*  SnP    = (float*)alloc((size_t)G * 128 * 4);
  float*  SnR    = (float*)alloc((size_t)G * 128 * 4);
  float*  SeP    = (float*)alloc((size_t)G * 128 * 4);
  float*  SeR    = (float*)alloc((size_t)G * 128 * 4);
  float*  Gf     = (float*)alloc((size_t)G * 256 * 4);
  float*  x1     = (float*)alloc((size_t)G * 512 * 4);
  float*  x2     = (float*)alloc((size_t)G * 256 * 4);
  int*    cnt_n  = (int*)alloc((size_t)G * 4);
  int*    cnt_e  = (int*)alloc((size_t)G * 4);
  if (off > ws_size) return;  // graceful fail

  const int EB = (E + 255) / 256;
  const int NB = (N + 255) / 256;   // 235 <= 256, fits scan_block

  // ---- CSR builds (multi-block scan; P then R, cnt/cursor/blocksum shared) ----
  auto build_csr = [&](const int* dst, int* rowptr, int* eperm) {
    fillzi<<<NB, 256, 0, stream>>>(cnt, N);
    hist_dst<<<EB, 256, 0, stream>>>(dst, cnt, E);
    scan_local<<<NB, 256, 0, stream>>>(cnt, rowptr, blocksum, N);
    scan_block<<<1, 256, 0, stream>>>(blocksum, NB);
    scan_add<<<NB, 256, 0, stream>>>(rowptr, cursor, blocksum, N, E);
    scatter_idx<<<EB, 256, 0, stream>>>(dst, cursor, eperm, E);
  };
  build_csr(dstP, rowptrP, epermP);
  build_csr(dstR, rowptrR, epermR);

  // ---- prep egat2 weights (bf16, transposed, swizzled) ----
  prep_w<<<1, 256, 0, stream>>>(w2.Wni,   Wt_ni);
  prep_w<<<1, 256, 0, stream>>>(w2.Wnj,   Wt_nj);
  prep_w<<<1, 256, 0, stream>>>(w2.Wf,    Wt_f);
  prep_w<<<1, 256, 0, stream>>>(w2.Wnode, Wt_nd);

  const int GB = (N + 3) / 4;      // egat_gather grid

  auto layer1 = [&](const float* h, const float* e, const int* src,
                    const int* rowptr, const int* eperm) {
    lin3_small<17><<<(N + 15) / 16, 128, 0, stream>>>(h, w1.Wni, w1.bni, w1.Wnj, w1.bnj,
                                                      w1.Wnode, w1.bnode, f_nin, f_nj, N);
    lin1_small<15><<<(E + 15) / 16, 128, 0, stream>>>(e, w1.Wf, w1.bf, eb, E);
    egat_gather<<<GB, 256, 0, stream>>>(f_nin, f_nj, eb, src, rowptr, eperm, w1.attn, nb, N);
  };
  auto layer2 = [&](const int* src, const int* rowptr, const int* eperm) {
    gemm_k128<float, ushort><<<(N + 127) / 128, 256, 0, stream>>>(nb, 128, Wt_ni, w2.bni, f_nin, 256, N);
    gemm_k128<float, ushort><<<(N + 127) / 128, 256, 0, stream>>>(nb, 128, Wt_nd, w2.bnode, f_nin + 128, 256, N);
    gemm_k128<float, ushort><<<(N + 127) / 128, 256, 0, stream>>>(nb, 128, Wt_nj, w2.bnj, f_nj, 128, N);
    gemm_k128<ushort, ushort><<<(E + 127) / 128, 256, 0, stream>>>(eb, 128, Wt_f, w2.bf, eb, 128, E);
    egat_gather<<<GB, 256, 0, stream>>>(f_nin, f_nj, eb, src, rowptr, eperm, w2.attn, nb, N);
  };

  // ---- P branch: one egat1 layer, reduce to G x 128 ----
  layer1(hP, eP, srcP, rowptrP, epermP);
  segsum<float><<<G, 128, 0, stream>>>(nb, nid, N, SnP, cnt_n);
  segsum<ushort><<<G, 128, 0, stream>>>(eb, eid, E, SeP, cnt_e);

  // ---- R branch: egat1 + egat2 x2 ----
  layer1(hR, eR, srcR, rowptrR, epermR);
  layer2(srcR, rowptrR, epermR);
  layer2(srcR, rowptrR, epermR);
  segsum<float><<<G, 128, 0, stream>>>(nb, nid, N, SnR, nullptr);
  segsum<ushort><<<G, 128, 0, stream>>>(eb, eid, E, SeR, nullptr);

  // ---- Diff aggregate + per-graph linears ----
  diff_linear<<<G, 128, 0, stream>>>(SnP, SnR, cnt_n, Wa_n, ba_n, Gf, 256, 0);
  diff_linear<<<G, 128, 0, stream>>>(SeP, SeR, cnt_e, Wa_e, ba_e, Gf, 256, 128);

  // ---- MLP head ----
  mlp_linear<256, 512, true><<<G, 512, 0, stream>>>(Gf, Wm1, bm1, x1);
  mlp_linear<512, 256, true><<<G, 256, 0, stream>>>(x1, Wm2, bm2, x2);
  mlp_final<<<(G + 255) / 256, 256, 0, stream>>>(x2, Wm3, bm3, (float*)d_out, G);
}

// Round 6
// 799.124 us; speedup vs baseline: 3.4266x; 1.1055x over previous
//
#include <hip/hip_runtime.h>
#include <cstddef>
#include <cstdint>

typedef unsigned int uint;
typedef unsigned short ushort;
typedef __attribute__((ext_vector_type(4))) float f32x4;
typedef __attribute__((ext_vector_type(8))) short short8;

// ---------- bf16 helpers (storage = ushort) ----------
__device__ __forceinline__ ushort f2b(float v) {
  uint x = __float_as_uint(v);
  return (ushort)((x + 0x7fffu + ((x >> 16) & 1u)) >> 16);  // RNE
}
__device__ __forceinline__ float b2f_lo(uint u) { return __uint_as_float(u << 16); }
__device__ __forceinline__ float b2f_hi(uint u) { return __uint_as_float(u & 0xffff0000u); }
__device__ __forceinline__ float ld1(const float* p) { return *p; }
__device__ __forceinline__ float ld1(const ushort* p) { return __uint_as_float(((uint)*p) << 16); }
__device__ __forceinline__ void st1(float* p, float v) { *p = v; }
__device__ __forceinline__ void st1(ushort* p, float v) { *p = f2b(v); }

// load 8 consecutive elems as packed bf16 (uint4 = 8 x bf16)
__device__ __forceinline__ uint4 ldA8(const float* p) {
  float4 a = *(const float4*)p;
  float4 b = *(const float4*)(p + 4);
  uint4 r;
  r.x = (uint)f2b(a.x) | ((uint)f2b(a.y) << 16);
  r.y = (uint)f2b(a.z) | ((uint)f2b(a.w) << 16);
  r.z = (uint)f2b(b.x) | ((uint)f2b(b.y) << 16);
  r.w = (uint)f2b(b.z) | ((uint)f2b(b.w) << 16);
  return r;
}
__device__ __forceinline__ uint4 ldA8(const ushort* p) { return *(const uint4*)p; }

__device__ __forceinline__ int lowerb(const int* __restrict__ ids, int M, int v) {
  int lo = 0, hi = M;
  while (lo < hi) { int mid = (lo + hi) >> 1; if (ids[mid] < v) lo = mid + 1; else hi = mid; }
  return lo;
}

__global__ void fillzi(int* p, int n) {
  int i = blockIdx.x * 256 + threadIdx.x;
  if (i < n) p[i] = 0;
}
__global__ void fillzf(float* p, int n) {
  int i = blockIdx.x * 256 + threadIdx.x;
  if (i < n) p[i] = 0.f;
}

// ---------- CSR build: edges sorted by dst ----------
__global__ void hist_dst(const int* __restrict__ dst, int* __restrict__ cnt, int E) {
  int e = blockIdx.x * 256 + threadIdx.x;
  if (e < E) atomicAdd(&cnt[dst[e]], 1);
}

// multi-block exclusive scan, phase 1: per-block local exclusive scan + block sums
__global__ void scan_local(const int* __restrict__ cnt, int* __restrict__ rowptr,
                           int* __restrict__ blocksum, int N) {
  __shared__ int tmp[256];
  int t = threadIdx.x;
  int i = blockIdx.x * 256 + t;
  int v = (i < N) ? cnt[i] : 0;
  tmp[t] = v;
  __syncthreads();
  for (int ofs = 1; ofs < 256; ofs <<= 1) {
    int u = (t >= ofs) ? tmp[t - ofs] : 0;
    __syncthreads();
    tmp[t] += u;
    __syncthreads();
  }
  if (i < N) rowptr[i] = tmp[t] - v;          // exclusive
  if (t == 255) blocksum[blockIdx.x] = tmp[255];
}

// phase 2: single tiny block scans the <=256 block sums (exclusive, in place)
__global__ void scan_block(int* __restrict__ bs, int n) {
  __shared__ int tmp[256];
  int t = threadIdx.x;
  int v = (t < n) ? bs[t] : 0;
  tmp[t] = v;
  __syncthreads();
  for (int ofs = 1; ofs < 256; ofs <<= 1) {
    int u = (t >= ofs) ? tmp[t - ofs] : 0;
    __syncthreads();
    tmp[t] += u;
    __syncthreads();
  }
  if (t < n) bs[t] = tmp[t] - v;              // exclusive
}

// phase 3: add block offsets, mirror into cursor, set rowptr[N]=E
__global__ void scan_add(int* __restrict__ rowptr, int* __restrict__ cursor,
                         const int* __restrict__ blocksum, int N, int E) {
  int i = blockIdx.x * 256 + threadIdx.x;
  if (i < N) {
    int v = rowptr[i] + blocksum[blockIdx.x];
    rowptr[i] = v;
    cursor[i] = v;
  }
  if (i == 0) rowptr[N] = E;
}

__global__ void scatter_idx(const int* __restrict__ dst, int* __restrict__ cursor,
                            int* __restrict__ eperm, int E) {
  int e = blockIdx.x * 256 + threadIdx.x;
  if (e < E) {
    int p = atomicAdd(&cursor[dst[e]], 1);
    eperm[p] = e;
  }
}

// ---------- prep: W[128][128] fp32 -> transposed, bf16, XOR-swizzled image ----------
__global__ void prep_w(const float* __restrict__ W, ushort* __restrict__ Wt) {
  int t = threadIdx.x;        // 256 threads, 1 block
  int n = t >> 1;
  int k0 = (t & 1) * 64;
  uint sw = (uint)(n & 7) << 3;
  for (int kk = 0; kk < 64; ++kk) {
    int k = k0 + kk;
    Wt[n * 128 + (k ^ sw)] = f2b(W[k * 128 + n]);
  }
}

// ---------- MFMA GEMM: Y[M,128](ldy) = X[M,128](ldx) @ W[128,128] + b ----------
// In-place safe (Y==X): each block reads only the rows it writes, via LDS.
template<typename TIn, typename TOut>
__global__ __launch_bounds__(256) void gemm_k128(const TIn* X, int ldx,
                                                 const ushort* __restrict__ Wt,
                                                 const float* __restrict__ b,
                                                 TOut* Y, int ldy, int M) {
  __shared__ ushort As[128 * 128];
  __shared__ ushort Bs[128 * 128];
  int t = threadIdx.x;
  int row0 = blockIdx.x * 128;

  { // stage B: linear copy (pre-swizzled in global)
    const uint4* s4 = (const uint4*)Wt + t * 8;
    uint4* d4 = (uint4*)Bs + t * 8;
#pragma unroll
    for (int c = 0; c < 8; ++c) d4[c] = s4[c];
  }
  { // stage A: row r = t>>1, k-half = (t&1)*64; convert to bf16, swizzled store
    int r = t >> 1;
    int k0h = (t & 1) * 64;
    int grow = row0 + r;
    uint sw = (uint)(r & 7) << 3;
    if (grow < M) {
      const TIn* xr = X + (size_t)grow * ldx;
#pragma unroll
      for (int c = 0; c < 8; ++c) {
        int k0 = k0h + c * 8;
        *(uint4*)(As + r * 128 + (k0 ^ sw)) = ldA8(xr + k0);
      }
    } else {
      uint4 z = make_uint4(0, 0, 0, 0);
#pragma unroll
      for (int c = 0; c < 8; ++c) {
        int k0 = k0h + c * 8;
        *(uint4*)(As + r * 128 + (k0 ^ sw)) = z;
      }
    }
  }
  __syncthreads();

  int lane = t & 63;
  int wid = t >> 6;
  int wr = wid >> 1, wc = wid & 1;
  uint swl = (uint)(lane & 7) << 3;

  f32x4 acc[4][4];
#pragma unroll
  for (int n4 = 0; n4 < 4; ++n4) {
    float bv = b[wc * 64 + n4 * 16 + (lane & 15)];
#pragma unroll
    for (int m4 = 0; m4 < 4; ++m4) acc[m4][n4] = (f32x4){bv, bv, bv, bv};
  }

#pragma unroll
  for (int kk = 0; kk < 4; ++kk) {
    int kidx = kk * 32 + 8 * (lane >> 4);
    short8 af[4], bfr[4];
#pragma unroll
    for (int m4 = 0; m4 < 4; ++m4) {
      int rm = wr * 64 + m4 * 16 + (lane & 15);
      af[m4] = *(const short8*)(As + rm * 128 + (kidx ^ swl));
    }
#pragma unroll
    for (int n4 = 0; n4 < 4; ++n4) {
      int cn = wc * 64 + n4 * 16 + (lane & 15);
      bfr[n4] = *(const short8*)(Bs + cn * 128 + (kidx ^ swl));
    }
#pragma unroll
    for (int m4 = 0; m4 < 4; ++m4)
#pragma unroll
      for (int n4 = 0; n4 < 4; ++n4)
        acc[m4][n4] = __builtin_amdgcn_mfma_f32_16x16x32_bf16(af[m4], bfr[n4], acc[m4][n4], 0, 0, 0);
  }

  int coln = wc * 64 + (lane & 15);
#pragma unroll
  for (int m4 = 0; m4 < 4; ++m4) {
    int rb = row0 + wr * 64 + m4 * 16 + ((lane >> 4) << 2);
#pragma unroll
    for (int n4 = 0; n4 < 4; ++n4) {
      int cc = coln + n4 * 16;
#pragma unroll
      for (int i = 0; i < 4; ++i)
        if (rb + i < M) st1(Y + (size_t)(rb + i) * ldy + cc, acc[m4][n4][i]);
    }
  }
}

// ---------- layer-1 fused node linears: ni+node -> f_nin[N][256], nj -> f_nj ----------
template<int K>
__global__ __launch_bounds__(128) void lin3_small(const float* __restrict__ X,
    const float* __restrict__ W1, const float* __restrict__ b1,
    const float* __restrict__ W2, const float* __restrict__ b2,
    const float* __restrict__ W3, const float* __restrict__ b3,
    ushort* __restrict__ Ynin, ushort* __restrict__ Ynj, int M) {
  constexpr int ROWS = 16;
  __shared__ float xs[ROWS * K];
  int t = threadIdx.x;
  int row0 = blockIdx.x * ROWS;
  int nr = M - row0; if (nr > ROWS) nr = ROWS;
  for (int i = t; i < nr * K; i += 128) xs[i] = X[(size_t)row0 * K + i];
  __syncthreads();
  float a1[ROWS], a2[ROWS], a3[ROWS];
  float v1 = b1[t], v2 = b2[t], v3 = b3[t];
#pragma unroll
  for (int r = 0; r < ROWS; ++r) { a1[r] = v1; a2[r] = v2; a3[r] = v3; }
#pragma unroll
  for (int k = 0; k < K; ++k) {
    float w1 = W1[k * 128 + t], w2 = W2[k * 128 + t], w3 = W3[k * 128 + t];
#pragma unroll
    for (int r = 0; r < ROWS; ++r) {
      float x = xs[r * K + k];
      a1[r] = fmaf(x, w1, a1[r]);
      a2[r] = fmaf(x, w2, a2[r]);
      a3[r] = fmaf(x, w3, a3[r]);
    }
  }
  for (int r = 0; r < nr; ++r) {
    size_t n = (size_t)(row0 + r);
    Ynin[n * 256 + t] = f2b(a1[r]);        // f_ni
    Ynin[n * 256 + 128 + t] = f2b(a3[r]);  // f_node
    Ynj[n * 128 + t] = f2b(a2[r]);
  }
}

// ---------- layer-1 edge linear (K=15) ----------
template<int K>
__global__ __launch_bounds__(128) void lin1_small(const float* __restrict__ X,
    const float* __restrict__ W, const float* __restrict__ b,
    ushort* __restrict__ Y, int M) {
  constexpr int ROWS = 16;
  __shared__ float xs[ROWS * K];
  int t = threadIdx.x;
  int row0 = blockIdx.x * ROWS;
  int nr = M - row0; if (nr > ROWS) nr = ROWS;
  for (int i = t; i < nr * K; i += 128) xs[i] = X[(size_t)row0 * K + i];
  __syncthreads();
  float acc[ROWS];
  float bias = b[t];
#pragma unroll
  for (int r = 0; r < ROWS; ++r) acc[r] = bias;
#pragma unroll
  for (int k = 0; k < K; ++k) {
    float w = W[k * 128 + t];
#pragma unroll
    for (int r = 0; r < ROWS; ++r) acc[r] = fmaf(xs[r * K + k], w, acc[r]);
  }
  for (int r = 0; r < nr; ++r) Y[(size_t)(row0 + r) * 128 + t] = f2b(acc[r]);
}

// ---------- fused edge+aggregate stage (CSR over dst) ----------
__global__ void egat_gather(const ushort* __restrict__ f_nin,   // [N][256] = ni | node
                            const ushort* __restrict__ f_nj,    // [N][128]
                            ushort* eb,                          // [E][128] in/out
                            const int* __restrict__ src,
                            const int* __restrict__ rowptr,
                            const int* __restrict__ eperm,
                            const float* __restrict__ attn,
                            float* __restrict__ nb, int N) {
  int d = blockIdx.x * 4 + (threadIdx.x >> 6);
  if (d >= N) return;
  int lane = threadIdx.x & 63;
  int lo = rowptr[d], hi = rowptr[d + 1];
  int h = lane >> 4;
  float2 at = *(const float2*)(attn + h * 32 + (lane & 15) * 2);
  uint unj = *((const uint*)(f_nj + (size_t)d * 128) + lane);
  float nj0 = b2f_lo(unj), nj1 = b2f_hi(unj);
  float acc0 = 0.f, acc1 = 0.f, exsum = 0.f;
  for (int i = lo; i < hi; ++i) {
    int e = eperm[i];
    int s = src[e];
    const uint* pn = (const uint*)(f_nin + (size_t)s * 256);
    uint uni = pn[lane];        // f_ni[s]
    uint und = pn[64 + lane];   // f_node[s]
    uint* ep = (uint*)(eb + (size_t)e * 128) + lane;
    uint ue = *ep;
    float v0 = b2f_lo(ue) + b2f_lo(uni) + nj0;
    float v1 = b2f_hi(ue) + b2f_hi(uni) + nj1;
    v0 = v0 >= 0.f ? v0 : 0.01f * v0;
    v1 = v1 >= 0.f ? v1 : 0.01f * v1;
    *ep = (uint)f2b(v0) | ((uint)f2b(v1) << 16);
    float p = v0 * at.x + v1 * at.y;
    p += __shfl_xor(p, 1);
    p += __shfl_xor(p, 2);
    p += __shfl_xor(p, 4);
    p += __shfl_xor(p, 8);            // all 16 lanes of head h hold the logit
    float ev = __expf(p);             // softmax shift-invariant; logits O(1)
    exsum += ev;
    acc0 = fmaf(b2f_lo(und), ev, acc0);
    acc1 = fmaf(b2f_hi(und), ev, acc1);
  }
  float inv = exsum > 0.f ? 1.f / exsum : 0.f;
  float2* out = (float2*)(nb + (size_t)d * 128) + lane;
  *out = make_float2(acc0 * inv, acc1 * inv);
}

// ---------- streaming segment-sum over sorted ids ----------
// One wave per ROWS-row chunk; register accumulate; atomicAdd flush at
// segment boundaries only (~2-3 per block). S must be zeroed beforehand.
template<int ROWS>
__global__ __launch_bounds__(64) void segsum_f32(const float* __restrict__ X,
    const int* __restrict__ ids, int M, float* __restrict__ S) {
  int r0 = blockIdx.x * ROWS;
  if (r0 >= M) return;
  int r1 = r0 + ROWS; if (r1 > M) r1 = M;
  int t = threadIdx.x;
  float a0 = 0.f, a1 = 0.f;
  int cur = ids[r0];
  for (int r = r0; r < r1; ++r) {
    int id = ids[r];
    if (id != cur) {
      atomicAdd(&S[(size_t)cur * 128 + 2 * t], a0);
      atomicAdd(&S[(size_t)cur * 128 + 2 * t + 1], a1);
      a0 = a1 = 0.f; cur = id;
    }
    float2 v = *(const float2*)(X + (size_t)r * 128 + 2 * t);
    a0 += v.x; a1 += v.y;
  }
  atomicAdd(&S[(size_t)cur * 128 + 2 * t], a0);
  atomicAdd(&S[(size_t)cur * 128 + 2 * t + 1], a1);
}

template<int ROWS>
__global__ __launch_bounds__(64) void segsum_bf16(const ushort* __restrict__ X,
    const int* __restrict__ ids, int M, float* __restrict__ S) {
  int r0 = blockIdx.x * ROWS;
  if (r0 >= M) return;
  int r1 = r0 + ROWS; if (r1 > M) r1 = M;
  int t = threadIdx.x;
  float a0 = 0.f, a1 = 0.f;
  int cur = ids[r0];
  for (int r = r0; r < r1; ++r) {
    int id = ids[r];
    if (id != cur) {
      atomicAdd(&S[(size_t)cur * 128 + 2 * t], a0);
      atomicAdd(&S[(size_t)cur * 128 + 2 * t + 1], a1);
      a0 = a1 = 0.f; cur = id;
    }
    uint u = *((const uint*)(X + (size_t)r * 128) + t);
    a0 += b2f_lo(u); a1 += b2f_hi(u);
  }
  atomicAdd(&S[(size_t)cur * 128 + 2 * t], a0);
  atomicAdd(&S[(size_t)cur * 128 + 2 * t + 1], a1);
}

// cnt[g] = number of (sorted) ids equal to g
__global__ void seg_cnt(const int* __restrict__ ids, int M, int* __restrict__ cnt, int G) {
  int g = blockIdx.x * 256 + threadIdx.x;
  if (g < G) cnt[g] = lowerb(ids, M, g + 1) - lowerb(ids, M, g);
}

// ---------- out[g, coloff+t] = (SP[g]-SR[g]) @ W + cnt[g]*b ----------
__global__ void diff_linear(const float* __restrict__ SP, const float* __restrict__ SR,
                            const int* __restrict__ cnt,
                            const float* __restrict__ W, const float* __restrict__ b,
                            float* __restrict__ out, int ldo, int coloff) {
  int g = blockIdx.x;
  int t = threadIdx.x;
  __shared__ float xs[128];
  xs[t] = SP[(size_t)g * 128 + t] - SR[(size_t)g * 128 + t];
  __syncthreads();
  float acc = (float)cnt[g] * b[t];
  for (int k = 0; k < 128; ++k) acc = fmaf(xs[k], W[k * 128 + t], acc);
  out[(size_t)g * ldo + coloff + t] = acc;
}

template<int K, int NC, bool RELU>
__global__ void mlp_linear(const float* __restrict__ X, const float* __restrict__ W,
                           const float* __restrict__ b, float* __restrict__ Y) {
  int g = blockIdx.x;
  int t = threadIdx.x;
  __shared__ float xs[K];
  for (int i = t; i < K; i += NC) xs[i] = X[(size_t)g * K + i];
  __syncthreads();
  float acc = b[t];
  for (int k = 0; k < K; ++k) acc = fmaf(xs[k], W[k * NC + t], acc);
  if (RELU) acc = fmaxf(acc, 0.f);
  Y[(size_t)g * NC + t] = acc;
}

__global__ void mlp_final(const float* __restrict__ X, const float* __restrict__ W,
                          const float* __restrict__ b, float* __restrict__ out, int G) {
  int g = blockIdx.x * blockDim.x + threadIdx.x;
  if (g >= G) return;
  float acc = b[0];
  for (int k = 0; k < 256; ++k) acc = fmaf(X[(size_t)g * 256 + k], W[k], acc);
  out[g] = acc;
}

struct LayerW {
  const float *Wni, *bni, *Wnj, *bnj, *Wf, *bf, *Wnode, *bnode, *attn;
};

extern "C" void kernel_launch(void* const* d_in, const int* in_sizes, int n_in,
                              void* d_out, int out_size, void* d_ws, size_t ws_size,
                              hipStream_t stream) {
  const float* hR = (const float*)d_in[0];
  const float* eR = (const float*)d_in[1];
  const float* hP = (const float*)d_in[2];
  const float* eP = (const float*)d_in[3];
  const int* srcR = (const int*)d_in[4];
  const int* dstR = (const int*)d_in[5];
  const int* srcP = (const int*)d_in[6];
  const int* dstP = (const int*)d_in[7];
  const int* nid  = (const int*)d_in[8];
  const int* eid  = (const int*)d_in[9];
  LayerW w1 { (const float*)d_in[10], (const float*)d_in[11], (const float*)d_in[12],
              (const float*)d_in[13], (const float*)d_in[14], (const float*)d_in[15],
              (const float*)d_in[16], (const float*)d_in[17], (const float*)d_in[18] };
  LayerW w2 { (const float*)d_in[19], (const float*)d_in[20], (const float*)d_in[21],
              (const float*)d_in[22], (const float*)d_in[23], (const float*)d_in[24],
              (const float*)d_in[25], (const float*)d_in[26], (const float*)d_in[27] };
  const float* Wa_n = (const float*)d_in[28];
  const float* ba_n = (const float*)d_in[29];
  const float* Wa_e = (const float*)d_in[30];
  const float* ba_e = (const float*)d_in[31];
  const float* Wm1  = (const float*)d_in[32];
  const float* bm1  = (const float*)d_in[33];
  const float* Wm2  = (const float*)d_in[34];
  const float* bm2  = (const float*)d_in[35];
  const float* Wm3  = (const float*)d_in[36];
  const float* bm3  = (const float*)d_in[37];

  const int N = in_sizes[0] / 17;   // 60000
  const int E = in_sizes[4];        // 240000
  const int G = out_size;           // 1024

  // ---- workspace carve-up ----
  char* base = (char*)d_ws;
  size_t off = 0;
  auto alloc = [&](size_t bytes) { char* p = base + off; off += (bytes + 255) & ~(size_t)255; return p; };
  float*  nb     = (float*)alloc((size_t)N * 128 * 4);    // node state fp32
  ushort* f_nin  = (ushort*)alloc((size_t)N * 256 * 2);   // [ni | node] fused rows
  ushort* f_nj   = (ushort*)alloc((size_t)N * 128 * 2);
  ushort* eb     = (ushort*)alloc((size_t)E * 128 * 2);   // edge state bf16, in-place
  int*    rowptrP = (int*)alloc((size_t)(N + 1) * 4);
  int*    rowptrR = (int*)alloc((size_t)(N + 1) * 4);
  int*    epermP  = (int*)alloc((size_t)E * 4);
  int*    epermR  = (int*)alloc((size_t)E * 4);
  int*    cnt     = (int*)alloc((size_t)N * 4);
  int*    cursor  = (int*)alloc((size_t)N * 4);
  int*    blocksum = (int*)alloc(1024 * 4);
  ushort* Wt_ni  = (ushort*)alloc(128 * 128 * 2);
  ushort* Wt_nj  = (ushort*)alloc(128 * 128 * 2);
  ushort* Wt_f   = (ushort*)alloc(128 * 128 * 2);
  ushort* Wt_nd  = (ushort*)alloc(128 * 128 * 2);
  float*  SnP    = (float*)alloc((size_t)G * 128 * 4);
  float*  SnR    = (float*)alloc((size_t)G * 128 * 4);
  float*  SeP    = (float*)alloc((size_t)G * 128 * 4);
  float*  SeR    = (float*)alloc((size_t)G * 128 * 4);
  float*  Gf     = (float*)alloc((size_t)G * 256 * 4);
  float*  x1     = (float*)alloc((size_t)G * 512 * 4);
  float*  x2     = (float*)alloc((size_t)G * 256 * 4);
  int*    cnt_n  = (int*)alloc((size_t)G * 4);
  int*    cnt_e  = (int*)alloc((size_t)G * 4);
  if (off > ws_size) return;  // graceful fail

  const int EB = (E + 255) / 256;
  const int NB = (N + 255) / 256;   // 235 <= 256, fits scan_block

  // ---- zero the 4 contiguous S accumulators (SnP..SeR) once ----
  fillzf<<<(G * 512 + 255) / 256, 256, 0, stream>>>(SnP, G * 512);

  // ---- CSR builds (multi-block scan; P then R, cnt/cursor/blocksum shared) ----
  auto build_csr = [&](const int* dst, int* rowptr, int* eperm) {
    fillzi<<<NB, 256, 0, stream>>>(cnt, N);
    hist_dst<<<EB, 256, 0, stream>>>(dst, cnt, E);
    scan_local<<<NB, 256, 0, stream>>>(cnt, rowptr, blocksum, N);
    scan_block<<<1, 256, 0, stream>>>(blocksum, NB);
    scan_add<<<NB, 256, 0, stream>>>(rowptr, cursor, blocksum, N, E);
    scatter_idx<<<EB, 256, 0, stream>>>(dst, cursor, eperm, E);
  };
  build_csr(dstP, rowptrP, epermP);
  build_csr(dstR, rowptrR, epermR);

  // ---- prep egat2 weights (bf16, transposed, swizzled) ----
  prep_w<<<1, 256, 0, stream>>>(w2.Wni,   Wt_ni);
  prep_w<<<1, 256, 0, stream>>>(w2.Wnj,   Wt_nj);
  prep_w<<<1, 256, 0, stream>>>(w2.Wf,    Wt_f);
  prep_w<<<1, 256, 0, stream>>>(w2.Wnode, Wt_nd);

  // ---- per-graph counts ----
  seg_cnt<<<(G + 255) / 256, 256, 0, stream>>>(nid, N, cnt_n, G);
  seg_cnt<<<(G + 255) / 256, 256, 0, stream>>>(eid, E, cnt_e, G);

  const int GB = (N + 3) / 4;      // egat_gather grid

  auto layer1 = [&](const float* h, const float* e, const int* src,
                    const int* rowptr, const int* eperm) {
    lin3_small<17><<<(N + 15) / 16, 128, 0, stream>>>(h, w1.Wni, w1.bni, w1.Wnj, w1.bnj,
                                                      w1.Wnode, w1.bnode, f_nin, f_nj, N);
    lin1_small<15><<<(E + 15) / 16, 128, 0, stream>>>(e, w1.Wf, w1.bf, eb, E);
    egat_gather<<<GB, 256, 0, stream>>>(f_nin, f_nj, eb, src, rowptr, eperm, w1.attn, nb, N);
  };
  auto layer2 = [&](const int* src, const int* rowptr, const int* eperm) {
    gemm_k128<float, ushort><<<(N + 127) / 128, 256, 0, stream>>>(nb, 128, Wt_ni, w2.bni, f_nin, 256, N);
    gemm_k128<float, ushort><<<(N + 127) / 128, 256, 0, stream>>>(nb, 128, Wt_nd, w2.bnode, f_nin + 128, 256, N);
    gemm_k128<float, ushort><<<(N + 127) / 128, 256, 0, stream>>>(nb, 128, Wt_nj, w2.bnj, f_nj, 128, N);
    gemm_k128<ushort, ushort><<<(E + 127) / 128, 256, 0, stream>>>(eb, 128, Wt_f, w2.bf, eb, 128, E);
    egat_gather<<<GB, 256, 0, stream>>>(f_nin, f_nj, eb, src, rowptr, eperm, w2.attn, nb, N);
  };

  // ---- P branch: one egat1 layer, reduce to G x 128 ----
  layer1(hP, eP, srcP, rowptrP, epermP);
  segsum_f32<64><<<(N + 63) / 64, 64, 0, stream>>>(nb, nid, N, SnP);
  segsum_bf16<128><<<(E + 127) / 128, 64, 0, stream>>>(eb, eid, E, SeP);

  // ---- R branch: egat1 + egat2 x2 ----
  layer1(hR, eR, srcR, rowptrR, epermR);
  layer2(srcR, rowptrR, epermR);
  layer2(srcR, rowptrR, epermR);
  segsum_f32<64><<<(N + 63) / 64, 64, 0, stream>>>(nb, nid, N, SnR);
  segsum_bf16<128><<<(E + 127) / 128, 64, 0, stream>>>(eb, eid, E, SeR);

  // ---- Diff aggregate + per-graph linears ----
  diff_linear<<<G, 128, 0, stream>>>(SnP, SnR, cnt_n, Wa_n, ba_n, Gf, 256, 0);
  diff_linear<<<G, 128, 0, stream>>>(SeP, SeR, cnt_e, Wa_e, ba_e, Gf, 256, 128);

  // ---- MLP head ----
  mlp_linear<256, 512, true><<<G, 512, 0, stream>>>(Gf, Wm1, bm1, x1);
  mlp_linear<512, 256, true><<<G, 256, 0, stream>>>(x1, Wm2, bm2, x2);
  mlp_final<<<(G + 255) / 256, 256, 0, stream>>>(x2, Wm3, bm3, (float*)d_out, G);
}

// Round 7
// 794.503 us; speedup vs baseline: 3.4466x; 1.0058x over previous
//
#include <hip/hip_runtime.h>
#include <cstddef>
#include <cstdint>

typedef unsigned int uint;
typedef unsigned short ushort;
typedef __attribute__((ext_vector_type(4))) float f32x4;
typedef __attribute__((ext_vector_type(8))) short short8;

// ---------- bf16 helpers (storage = ushort) ----------
__device__ __forceinline__ ushort f2b(float v) {
  uint x = __float_as_uint(v);
  return (ushort)((x + 0x7fffu + ((x >> 16) & 1u)) >> 16);  // RNE
}
__device__ __forceinline__ float b2f_lo(uint u) { return __uint_as_float(u << 16); }
__device__ __forceinline__ float b2f_hi(uint u) { return __uint_as_float(u & 0xffff0000u); }
__device__ __forceinline__ float ld1(const float* p) { return *p; }
__device__ __forceinline__ float ld1(const ushort* p) { return __uint_as_float(((uint)*p) << 16); }
__device__ __forceinline__ void st1(float* p, float v) { *p = v; }
__device__ __forceinline__ void st1(ushort* p, float v) { *p = f2b(v); }

// load 8 consecutive elems as packed bf16 (uint4 = 8 x bf16)
__device__ __forceinline__ uint4 ldA8(const float* p) {
  float4 a = *(const float4*)p;
  float4 b = *(const float4*)(p + 4);
  uint4 r;
  r.x = (uint)f2b(a.x) | ((uint)f2b(a.y) << 16);
  r.y = (uint)f2b(a.z) | ((uint)f2b(a.w) << 16);
  r.z = (uint)f2b(b.x) | ((uint)f2b(b.y) << 16);
  r.w = (uint)f2b(b.z) | ((uint)f2b(b.w) << 16);
  return r;
}
__device__ __forceinline__ uint4 ldA8(const ushort* p) { return *(const uint4*)p; }

__device__ __forceinline__ int lowerb(const int* __restrict__ ids, int M, int v) {
  int lo = 0, hi = M;
  while (lo < hi) { int mid = (lo + hi) >> 1; if (ids[mid] < v) lo = mid + 1; else hi = mid; }
  return lo;
}

__global__ void fillzi(int* p, int n) {
  int i = blockIdx.x * 256 + threadIdx.x;
  if (i < n) p[i] = 0;
}
__global__ void fillzf(float* p, int n) {
  int i = blockIdx.x * 256 + threadIdx.x;
  if (i < n) p[i] = 0.f;
}

// ---------- CSR build: edges sorted by dst ----------
__global__ void hist_dst(const int* __restrict__ dst, int* __restrict__ cnt, int E) {
  int e = blockIdx.x * 256 + threadIdx.x;
  if (e < E) atomicAdd(&cnt[dst[e]], 1);
}

// multi-block exclusive scan, phase 1: per-block local exclusive scan + block sums
__global__ void scan_local(const int* __restrict__ cnt, int* __restrict__ rowptr,
                           int* __restrict__ blocksum, int N) {
  __shared__ int tmp[256];
  int t = threadIdx.x;
  int i = blockIdx.x * 256 + t;
  int v = (i < N) ? cnt[i] : 0;
  tmp[t] = v;
  __syncthreads();
  for (int ofs = 1; ofs < 256; ofs <<= 1) {
    int u = (t >= ofs) ? tmp[t - ofs] : 0;
    __syncthreads();
    tmp[t] += u;
    __syncthreads();
  }
  if (i < N) rowptr[i] = tmp[t] - v;          // exclusive
  if (t == 255) blocksum[blockIdx.x] = tmp[255];
}

// phase 2: single tiny block scans the <=256 block sums (exclusive, in place)
__global__ void scan_block(int* __restrict__ bs, int n) {
  __shared__ int tmp[256];
  int t = threadIdx.x;
  int v = (t < n) ? bs[t] : 0;
  tmp[t] = v;
  __syncthreads();
  for (int ofs = 1; ofs < 256; ofs <<= 1) {
    int u = (t >= ofs) ? tmp[t - ofs] : 0;
    __syncthreads();
    tmp[t] += u;
    __syncthreads();
  }
  if (t < n) bs[t] = tmp[t] - v;              // exclusive
}

// phase 3: add block offsets, mirror into cursor, set rowptr[N]=E
__global__ void scan_add(int* __restrict__ rowptr, int* __restrict__ cursor,
                         const int* __restrict__ blocksum, int N, int E) {
  int i = blockIdx.x * 256 + threadIdx.x;
  if (i < N) {
    int v = rowptr[i] + blocksum[blockIdx.x];
    rowptr[i] = v;
    cursor[i] = v;
  }
  if (i == 0) rowptr[N] = E;
}

// also emits invperm (orig->perm position) and src_perm (src in perm order)
__global__ void scatter_idx(const int* __restrict__ dst, const int* __restrict__ src,
                            int* __restrict__ cursor,
                            int* __restrict__ eperm, int* __restrict__ invperm,
                            int* __restrict__ src_perm, int E) {
  int e = blockIdx.x * 256 + threadIdx.x;
  if (e < E) {
    int p = atomicAdd(&cursor[dst[e]], 1);
    eperm[p] = e;
    invperm[e] = p;
    src_perm[p] = src[e];
  }
}

// ---------- prep: W[128][128] fp32 -> transposed, bf16, XOR-swizzled image ----------
__global__ void prep_w(const float* __restrict__ W, ushort* __restrict__ Wt) {
  int t = threadIdx.x;        // 256 threads, 1 block
  int n = t >> 1;
  int k0 = (t & 1) * 64;
  uint sw = (uint)(n & 7) << 3;
  for (int kk = 0; kk < 64; ++kk) {
    int k = k0 + kk;
    Wt[n * 128 + (k ^ sw)] = f2b(W[k * 128 + n]);
  }
}

// ---------- MFMA GEMM: Y[M,128](ldy) = X[M,128](ldx) @ W[128,128] + b ----------
// In-place safe (Y==X): each block reads only the rows it writes, via LDS.
template<typename TIn, typename TOut>
__global__ __launch_bounds__(256) void gemm_k128(const TIn* X, int ldx,
                                                 const ushort* __restrict__ Wt,
                                                 const float* __restrict__ b,
                                                 TOut* Y, int ldy, int M) {
  __shared__ ushort As[128 * 128];
  __shared__ ushort Bs[128 * 128];
  int t = threadIdx.x;
  int row0 = blockIdx.x * 128;

  { // stage B: linear copy (pre-swizzled in global)
    const uint4* s4 = (const uint4*)Wt + t * 8;
    uint4* d4 = (uint4*)Bs + t * 8;
#pragma unroll
    for (int c = 0; c < 8; ++c) d4[c] = s4[c];
  }
  { // stage A: row r = t>>1, k-half = (t&1)*64; convert to bf16, swizzled store
    int r = t >> 1;
    int k0h = (t & 1) * 64;
    int grow = row0 + r;
    uint sw = (uint)(r & 7) << 3;
    if (grow < M) {
      const TIn* xr = X + (size_t)grow * ldx;
#pragma unroll
      for (int c = 0; c < 8; ++c) {
        int k0 = k0h + c * 8;
        *(uint4*)(As + r * 128 + (k0 ^ sw)) = ldA8(xr + k0);
      }
    } else {
      uint4 z = make_uint4(0, 0, 0, 0);
#pragma unroll
      for (int c = 0; c < 8; ++c) {
        int k0 = k0h + c * 8;
        *(uint4*)(As + r * 128 + (k0 ^ sw)) = z;
      }
    }
  }
  __syncthreads();

  int lane = t & 63;
  int wid = t >> 6;
  int wr = wid >> 1, wc = wid & 1;
  uint swl = (uint)(lane & 7) << 3;

  f32x4 acc[4][4];
#pragma unroll
  for (int n4 = 0; n4 < 4; ++n4) {
    float bv = b[wc * 64 + n4 * 16 + (lane & 15)];
#pragma unroll
    for (int m4 = 0; m4 < 4; ++m4) acc[m4][n4] = (f32x4){bv, bv, bv, bv};
  }

#pragma unroll
  for (int kk = 0; kk < 4; ++kk) {
    int kidx = kk * 32 + 8 * (lane >> 4);
    short8 af[4], bfr[4];
#pragma unroll
    for (int m4 = 0; m4 < 4; ++m4) {
      int rm = wr * 64 + m4 * 16 + (lane & 15);
      af[m4] = *(const short8*)(As + rm * 128 + (kidx ^ swl));
    }
#pragma unroll
    for (int n4 = 0; n4 < 4; ++n4) {
      int cn = wc * 64 + n4 * 16 + (lane & 15);
      bfr[n4] = *(const short8*)(Bs + cn * 128 + (kidx ^ swl));
    }
#pragma unroll
    for (int m4 = 0; m4 < 4; ++m4)
#pragma unroll
      for (int n4 = 0; n4 < 4; ++n4)
        acc[m4][n4] = __builtin_amdgcn_mfma_f32_16x16x32_bf16(af[m4], bfr[n4], acc[m4][n4], 0, 0, 0);
  }

  int coln = wc * 64 + (lane & 15);
#pragma unroll
  for (int m4 = 0; m4 < 4; ++m4) {
    int rb = row0 + wr * 64 + m4 * 16 + ((lane >> 4) << 2);
#pragma unroll
    for (int n4 = 0; n4 < 4; ++n4) {
      int cc = coln + n4 * 16;
#pragma unroll
      for (int i = 0; i < 4; ++i)
        if (rb + i < M) st1(Y + (size_t)(rb + i) * ldy + cc, acc[m4][n4][i]);
    }
  }
}

// ---------- layer-1 fused node linears: ni+node -> f_nin[N][256], nj -> f_nj ----------
template<int K>
__global__ __launch_bounds__(128) void lin3_small(const float* __restrict__ X,
    const float* __restrict__ W1, const float* __restrict__ b1,
    const float* __restrict__ W2, const float* __restrict__ b2,
    const float* __restrict__ W3, const float* __restrict__ b3,
    ushort* __restrict__ Ynin, ushort* __restrict__ Ynj, int M) {
  constexpr int ROWS = 16;
  __shared__ float xs[ROWS * K];
  int t = threadIdx.x;
  int row0 = blockIdx.x * ROWS;
  int nr = M - row0; if (nr > ROWS) nr = ROWS;
  for (int i = t; i < nr * K; i += 128) xs[i] = X[(size_t)row0 * K + i];
  __syncthreads();
  float a1[ROWS], a2[ROWS], a3[ROWS];
  float v1 = b1[t], v2 = b2[t], v3 = b3[t];
#pragma unroll
  for (int r = 0; r < ROWS; ++r) { a1[r] = v1; a2[r] = v2; a3[r] = v3; }
#pragma unroll
  for (int k = 0; k < K; ++k) {
    float w1 = W1[k * 128 + t], w2 = W2[k * 128 + t], w3 = W3[k * 128 + t];
#pragma unroll
    for (int r = 0; r < ROWS; ++r) {
      float x = xs[r * K + k];
      a1[r] = fmaf(x, w1, a1[r]);
      a2[r] = fmaf(x, w2, a2[r]);
      a3[r] = fmaf(x, w3, a3[r]);
    }
  }
  for (int r = 0; r < nr; ++r) {
    size_t n = (size_t)(row0 + r);
    Ynin[n * 256 + t] = f2b(a1[r]);        // f_ni
    Ynin[n * 256 + 128 + t] = f2b(a3[r]);  // f_node
    Ynj[n * 128 + t] = f2b(a2[r]);
  }
}

// ---------- layer-1 edge linear (K=15), emits rows in dst-CSR (permuted) order ----------
template<int K>
__global__ __launch_bounds__(128) void lin1_perm(const float* __restrict__ X,
    const float* __restrict__ W, const float* __restrict__ b,
    const int* __restrict__ eperm, ushort* __restrict__ Y, int M) {
  constexpr int ROWS = 16;
  __shared__ float xs[ROWS * K];
  __shared__ int es[ROWS];
  int t = threadIdx.x;
  int row0 = blockIdx.x * ROWS;
  int nr = M - row0; if (nr > ROWS) nr = ROWS;
  if (t < nr) es[t] = eperm[row0 + t];
  __syncthreads();
  for (int i = t; i < nr * K; i += 128) {
    int r = i / K, c = i - r * K;
    xs[i] = X[(size_t)es[r] * K + c];
  }
  __syncthreads();
  float acc[ROWS];
  float bias = b[t];
#pragma unroll
  for (int r = 0; r < ROWS; ++r) acc[r] = bias;
#pragma unroll
  for (int k = 0; k < K; ++k) {
    float w = W[k * 128 + t];
#pragma unroll
    for (int r = 0; r < ROWS; ++r) acc[r] = fmaf(xs[r * K + k], w, acc[r]);
  }
  for (int r = 0; r < nr; ++r) Y[(size_t)(row0 + r) * 128 + t] = f2b(acc[r]);
}

// ---------- fused edge+aggregate stage, edge state in dst-CSR order ----------
// One wave per dst node d; its edges are the CONTIGUOUS rows [lo,hi) of ebp.
// Only remaining random access: the f_nin[src] gather (L2/L3-resident).
__global__ void egat_gather(const ushort* __restrict__ f_nin,   // [N][256] = ni | node
                            const ushort* __restrict__ f_nj,    // [N][128]
                            ushort* ebp,                         // [E][128] perm order, in/out
                            const int* __restrict__ src_perm,
                            const int* __restrict__ rowptr,
                            const float* __restrict__ attn,
                            float* __restrict__ nb, int N) {
  int d = blockIdx.x * 4 + (threadIdx.x >> 6);
  if (d >= N) return;
  int lane = threadIdx.x & 63;
  int lo = rowptr[d], hi = rowptr[d + 1];
  int h = lane >> 4;
  float2 at = *(const float2*)(attn + h * 32 + (lane & 15) * 2);
  uint unj = *((const uint*)(f_nj + (size_t)d * 128) + lane);
  float nj0 = b2f_lo(unj), nj1 = b2f_hi(unj);
  float acc0 = 0.f, acc1 = 0.f, exsum = 0.f;
  for (int i = lo; i < hi; ++i) {
    int s = src_perm[i];
    const uint* pn = (const uint*)(f_nin + (size_t)s * 256);
    uint uni = pn[lane];        // f_ni[s]
    uint und = pn[64 + lane];   // f_node[s]
    uint* ep = (uint*)(ebp + (size_t)i * 128) + lane;
    uint ue = *ep;
    float v0 = b2f_lo(ue) + b2f_lo(uni) + nj0;
    float v1 = b2f_hi(ue) + b2f_hi(uni) + nj1;
    v0 = v0 >= 0.f ? v0 : 0.01f * v0;
    v1 = v1 >= 0.f ? v1 : 0.01f * v1;
    *ep = (uint)f2b(v0) | ((uint)f2b(v1) << 16);
    float p = v0 * at.x + v1 * at.y;
    p += __shfl_xor(p, 1);
    p += __shfl_xor(p, 2);
    p += __shfl_xor(p, 4);
    p += __shfl_xor(p, 8);            // all 16 lanes of head h hold the logit
    float ev = __expf(p);             // softmax shift-invariant; logits O(1)
    exsum += ev;
    acc0 = fmaf(b2f_lo(und), ev, acc0);
    acc1 = fmaf(b2f_hi(und), ev, acc1);
  }
  float inv = exsum > 0.f ? 1.f / exsum : 0.f;
  float2* out = (float2*)(nb + (size_t)d * 128) + lane;
  *out = make_float2(acc0 * inv, acc1 * inv);
}

// ---------- streaming segment-sum over sorted ids ----------
template<int ROWS>
__global__ __launch_bounds__(64) void segsum_f32(const float* __restrict__ X,
    const int* __restrict__ ids, int M, float* __restrict__ S) {
  int r0 = blockIdx.x * ROWS;
  if (r0 >= M) return;
  int r1 = r0 + ROWS; if (r1 > M) r1 = M;
  int t = threadIdx.x;
  float a0 = 0.f, a1 = 0.f;
  int cur = ids[r0];
  for (int r = r0; r < r1; ++r) {
    int id = ids[r];
    if (id != cur) {
      atomicAdd(&S[(size_t)cur * 128 + 2 * t], a0);
      atomicAdd(&S[(size_t)cur * 128 + 2 * t + 1], a1);
      a0 = a1 = 0.f; cur = id;
    }
    float2 v = *(const float2*)(X + (size_t)r * 128 + 2 * t);
    a0 += v.x; a1 += v.y;
  }
  atomicAdd(&S[(size_t)cur * 128 + 2 * t], a0);
  atomicAdd(&S[(size_t)cur * 128 + 2 * t + 1], a1);
}

// bf16 variant with row indirection (X rows live at invperm[r])
template<int ROWS>
__global__ __launch_bounds__(64) void segsum_bf16g(const ushort* __restrict__ X,
    const int* __restrict__ invperm,
    const int* __restrict__ ids, int M, float* __restrict__ S) {
  int r0 = blockIdx.x * ROWS;
  if (r0 >= M) return;
  int r1 = r0 + ROWS; if (r1 > M) r1 = M;
  int t = threadIdx.x;
  float a0 = 0.f, a1 = 0.f;
  int cur = ids[r0];
  for (int r = r0; r < r1; ++r) {
    int id = ids[r];
    if (id != cur) {
      atomicAdd(&S[(size_t)cur * 128 + 2 * t], a0);
      atomicAdd(&S[(size_t)cur * 128 + 2 * t + 1], a1);
      a0 = a1 = 0.f; cur = id;
    }
    uint u = *((const uint*)(X + (size_t)invperm[r] * 128) + t);
    a0 += b2f_lo(u); a1 += b2f_hi(u);
  }
  atomicAdd(&S[(size_t)cur * 128 + 2 * t], a0);
  atomicAdd(&S[(size_t)cur * 128 + 2 * t + 1], a1);
}

// cnt[g] = number of (sorted) ids equal to g
__global__ void seg_cnt(const int* __restrict__ ids, int M, int* __restrict__ cnt, int G) {
  int g = blockIdx.x * 256 + threadIdx.x;
  if (g < G) cnt[g] = lowerb(ids, M, g + 1) - lowerb(ids, M, g);
}

// ---------- out[g, coloff+t] = (SP[g]-SR[g]) @ W + cnt[g]*b ----------
__global__ void diff_linear(const float* __restrict__ SP, const float* __restrict__ SR,
                            const int* __restrict__ cnt,
                            const float* __restrict__ W, const float* __restrict__ b,
                            float* __restrict__ out, int ldo, int coloff) {
  int g = blockIdx.x;
  int t = threadIdx.x;
  __shared__ float xs[128];
  xs[t] = SP[(size_t)g * 128 + t] - SR[(size_t)g * 128 + t];
  __syncthreads();
  float acc = (float)cnt[g] * b[t];
  for (int k = 0; k < 128; ++k) acc = fmaf(xs[k], W[k * 128 + t], acc);
  out[(size_t)g * ldo + coloff + t] = acc;
}

template<int K, int NC, bool RELU>
__global__ void mlp_linear(const float* __restrict__ X, const float* __restrict__ W,
                           const float* __restrict__ b, float* __restrict__ Y) {
  int g = blockIdx.x;
  int t = threadIdx.x;
  __shared__ float xs[K];
  for (int i = t; i < K; i += NC) xs[i] = X[(size_t)g * K + i];
  __syncthreads();
  float acc = b[t];
  for (int k = 0; k < K; ++k) acc = fmaf(xs[k], W[k * NC + t], acc);
  if (RELU) acc = fmaxf(acc, 0.f);
  Y[(size_t)g * NC + t] = acc;
}

__global__ void mlp_final(const float* __restrict__ X, const float* __restrict__ W,
                          const float* __restrict__ b, float* __restrict__ out, int G) {
  int g = blockIdx.x * blockDim.x + threadIdx.x;
  if (g >= G) return;
  float acc = b[0];
  for (int k = 0; k < 256; ++k) acc = fmaf(X[(size_t)g * 256 + k], W[k], acc);
  out[g] = acc;
}

struct LayerW {
  const float *Wni, *bni, *Wnj, *bnj, *Wf, *bf, *Wnode, *bnode, *attn;
};

extern "C" void kernel_launch(void* const* d_in, const int* in_sizes, int n_in,
                              void* d_out, int out_size, void* d_ws, size_t ws_size,
                              hipStream_t stream) {
  const float* hR = (const float*)d_in[0];
  const float* eR = (const float*)d_in[1];
  const float* hP = (const float*)d_in[2];
  const float* eP = (const float*)d_in[3];
  const int* srcR = (const int*)d_in[4];
  const int* dstR = (const int*)d_in[5];
  const int* srcP = (const int*)d_in[6];
  const int* dstP = (const int*)d_in[7];
  const int* nid  = (const int*)d_in[8];
  const int* eid  = (const int*)d_in[9];
  LayerW w1 { (const float*)d_in[10], (const float*)d_in[11], (const float*)d_in[12],
              (const float*)d_in[13], (const float*)d_in[14], (const float*)d_in[15],
              (const float*)d_in[16], (const float*)d_in[17], (const float*)d_in[18] };
  LayerW w2 { (const float*)d_in[19], (const float*)d_in[20], (const float*)d_in[21],
              (const float*)d_in[22], (const float*)d_in[23], (const float*)d_in[24],
              (const float*)d_in[25], (const float*)d_in[26], (const float*)d_in[27] };
  const float* Wa_n = (const float*)d_in[28];
  const float* ba_n = (const float*)d_in[29];
  const float* Wa_e = (const float*)d_in[30];
  const float* ba_e = (const float*)d_in[31];
  const float* Wm1  = (const float*)d_in[32];
  const float* bm1  = (const float*)d_in[33];
  const float* Wm2  = (const float*)d_in[34];
  const float* bm2  = (const float*)d_in[35];
  const float* Wm3  = (const float*)d_in[36];
  const float* bm3  = (const float*)d_in[37];

  const int N = in_sizes[0] / 17;   // 60000
  const int E = in_sizes[4];        // 240000
  const int G = out_size;           // 1024

  // ---- workspace carve-up ----
  char* base = (char*)d_ws;
  size_t off = 0;
  auto alloc = [&](size_t bytes) { char* p = base + off; off += (bytes + 255) & ~(size_t)255; return p; };
  float*  nb     = (float*)alloc((size_t)N * 128 * 4);    // node state fp32
  ushort* f_nin  = (ushort*)alloc((size_t)N * 256 * 2);   // [ni | node] fused rows
  ushort* f_nj   = (ushort*)alloc((size_t)N * 128 * 2);
  ushort* ebp    = (ushort*)alloc((size_t)E * 128 * 2);   // edge state bf16, dst-CSR order
  int*    rowptrP = (int*)alloc((size_t)(N + 1) * 4);
  int*    rowptrR = (int*)alloc((size_t)(N + 1) * 4);
  int*    epermP  = (int*)alloc((size_t)E * 4);
  int*    epermR  = (int*)alloc((size_t)E * 4);
  int*    invpermP = (int*)alloc((size_t)E * 4);
  int*    invpermR = (int*)alloc((size_t)E * 4);
  int*    srcpermP = (int*)alloc((size_t)E * 4);
  int*    srcpermR = (int*)alloc((size_t)E * 4);
  int*    cnt     = (int*)alloc((size_t)N * 4);
  int*    cursor  = (int*)alloc((size_t)N * 4);
  int*    blocksum = (int*)alloc(1024 * 4);
  ushort* Wt_ni  = (ushort*)alloc(128 * 128 * 2);
  ushort* Wt_nj  = (ushort*)alloc(128 * 128 * 2);
  ushort* Wt_f   = (ushort*)alloc(128 * 128 * 2);
  ushort* Wt_nd  = (ushort*)alloc(128 * 128 * 2);
  float*  SnP    = (float*)alloc((size_t)G * 128 * 4);
  float*  SnR    = (float*)alloc((size_t)G * 128 * 4);
  float*  SeP    = (float*)alloc((size_t)G * 128 * 4);
  float*  SeR    = (float*)alloc((size_t)G * 128 * 4);
  float*  Gf     = (float*)alloc((size_t)G * 256 * 4);
  float*  x1     = (float*)alloc((size_t)G * 512 * 4);
  float*  x2     = (float*)alloc((size_t)G * 256 * 4);
  int*    cnt_n  = (int*)alloc((size_t)G * 4);
  int*    cnt_e  = (int*)alloc((size_t)G * 4);
  if (off > ws_size) return;  // graceful fail

  const int EB = (E + 255) / 256;
  const int NB = (N + 255) / 256;   // 235 <= 256, fits scan_block

  // ---- zero the 4 contiguous S accumulators (SnP..SeR) once ----
  fillzf<<<(G * 512 + 255) / 256, 256, 0, stream>>>(SnP, G * 512);

  // ---- CSR builds (multi-block scan; P then R, cnt/cursor/blocksum shared) ----
  auto build_csr = [&](const int* dst, const int* src, int* rowptr,
                       int* eperm, int* invperm, int* src_perm) {
    fillzi<<<NB, 256, 0, stream>>>(cnt, N);
    hist_dst<<<EB, 256, 0, stream>>>(dst, cnt, E);
    scan_local<<<NB, 256, 0, stream>>>(cnt, rowptr, blocksum, N);
    scan_block<<<1, 256, 0, stream>>>(blocksum, NB);
    scan_add<<<NB, 256, 0, stream>>>(rowptr, cursor, blocksum, N, E);
    scatter_idx<<<EB, 256, 0, stream>>>(dst, src, cursor, eperm, invperm, src_perm, E);
  };
  build_csr(dstP, srcP, rowptrP, epermP, invpermP, srcpermP);
  build_csr(dstR, srcR, rowptrR, epermR, invpermR, srcpermR);

  // ---- prep egat2 weights (bf16, transposed, swizzled) ----
  prep_w<<<1, 256, 0, stream>>>(w2.Wni,   Wt_ni);
  prep_w<<<1, 256, 0, stream>>>(w2.Wnj,   Wt_nj);
  prep_w<<<1, 256, 0, stream>>>(w2.Wf,    Wt_f);
  prep_w<<<1, 256, 0, stream>>>(w2.Wnode, Wt_nd);

  // ---- per-graph counts ----
  seg_cnt<<<(G + 255) / 256, 256, 0, stream>>>(nid, N, cnt_n, G);
  seg_cnt<<<(G + 255) / 256, 256, 0, stream>>>(eid, E, cnt_e, G);

  const int GB = (N + 3) / 4;      // egat_gather grid

  auto layer1 = [&](const float* h, const float* e, const int* eperm,
                    const int* src_perm, const int* rowptr) {
    lin3_small<17><<<(N + 15) / 16, 128, 0, stream>>>(h, w1.Wni, w1.bni, w1.Wnj, w1.bnj,
                                                      w1.Wnode, w1.bnode, f_nin, f_nj, N);
    lin1_perm<15><<<(E + 15) / 16, 128, 0, stream>>>(e, w1.Wf, w1.bf, eperm, ebp, E);
    egat_gather<<<GB, 256, 0, stream>>>(f_nin, f_nj, ebp, src_perm, rowptr, w1.attn, nb, N);
  };
  auto layer2 = [&](const int* src_perm, const int* rowptr) {
    gemm_k128<float, ushort><<<(N + 127) / 128, 256, 0, stream>>>(nb, 128, Wt_ni, w2.bni, f_nin, 256, N);
    gemm_k128<float, ushort><<<(N + 127) / 128, 256, 0, stream>>>(nb, 128, Wt_nd, w2.bnode, f_nin + 128, 256, N);
    gemm_k128<float, ushort><<<(N + 127) / 128, 256, 0, stream>>>(nb, 128, Wt_nj, w2.bnj, f_nj, 128, N);
    gemm_k128<ushort, ushort><<<(E + 127) / 128, 256, 0, stream>>>(ebp, 128, Wt_f, w2.bf, ebp, 128, E);
    egat_gather<<<GB, 256, 0, stream>>>(f_nin, f_nj, ebp, src_perm, rowptr, w2.attn, nb, N);
  };

  // ---- P branch: one egat1 layer, reduce to G x 128 ----
  layer1(hP, eP, epermP, srcpermP, rowptrP);
  segsum_f32<64><<<(N + 63) / 64, 64, 0, stream>>>(nb, nid, N, SnP);
  segsum_bf16g<128><<<(E + 127) / 128, 64, 0, stream>>>(ebp, invpermP, eid, E, SeP);

  // ---- R branch: egat1 + egat2 x2 ----
  layer1(hR, eR, epermR, srcpermR, rowptrR);
  layer2(srcpermR, rowptrR);
  layer2(srcpermR, rowptrR);
  segsum_f32<64><<<(N + 63) / 64, 64, 0, stream>>>(nb, nid, N, SnR);
  segsum_bf16g<128><<<(E + 127) / 128, 64, 0, stream>>>(ebp, invpermR, eid, E, SeR);

  // ---- Diff aggregate + per-graph linears ----
  diff_linear<<<G, 128, 0, stream>>>(SnP, SnR, cnt_n, Wa_n, ba_n, Gf, 256, 0);
  diff_linear<<<G, 128, 0, stream>>>(SeP, SeR, cnt_e, Wa_e, ba_e, Gf, 256, 128);

  // ---- MLP head ----
  mlp_linear<256, 512, true><<<G, 512, 0, stream>>>(Gf, Wm1, bm1, x1);
  mlp_linear<512, 256, true><<<G, 256, 0, stream>>>(x1, Wm2, bm2, x2);
  mlp_final<<<(G + 255) / 256, 256, 0, stream>>>(x2, Wm3, bm3, (float*)d_out, G);
}

// Round 8
// 740.413 us; speedup vs baseline: 3.6984x; 1.0731x over previous
//
#include <hip/hip_runtime.h>
#include <cstddef>
#include <cstdint>

typedef unsigned int uint;
typedef unsigned short ushort;
typedef __attribute__((ext_vector_type(4))) float f32x4;
typedef __attribute__((ext_vector_type(8))) short short8;

// ---------- bf16 helpers (storage = ushort) ----------
__device__ __forceinline__ ushort f2b(float v) {
  uint x = __float_as_uint(v);
  return (ushort)((x + 0x7fffu + ((x >> 16) & 1u)) >> 16);  // RNE
}
__device__ __forceinline__ float b2f_lo(uint u) { return __uint_as_float(u << 16); }
__device__ __forceinline__ float b2f_hi(uint u) { return __uint_as_float(u & 0xffff0000u); }
__device__ __forceinline__ float ld1(const float* p) { return *p; }
__device__ __forceinline__ float ld1(const ushort* p) { return __uint_as_float(((uint)*p) << 16); }
__device__ __forceinline__ void st1(float* p, float v) { *p = v; }
__device__ __forceinline__ void st1(ushort* p, float v) { *p = f2b(v); }

// load 8 consecutive elems as packed bf16 (uint4 = 8 x bf16)
__device__ __forceinline__ uint4 ldA8(const float* p) {
  float4 a = *(const float4*)p;
  float4 b = *(const float4*)(p + 4);
  uint4 r;
  r.x = (uint)f2b(a.x) | ((uint)f2b(a.y) << 16);
  r.y = (uint)f2b(a.z) | ((uint)f2b(a.w) << 16);
  r.z = (uint)f2b(b.x) | ((uint)f2b(b.y) << 16);
  r.w = (uint)f2b(b.z) | ((uint)f2b(b.w) << 16);
  return r;
}
__device__ __forceinline__ uint4 ldA8(const ushort* p) { return *(const uint4*)p; }

__device__ __forceinline__ int lowerb(const int* __restrict__ ids, int M, int v) {
  int lo = 0, hi = M;
  while (lo < hi) { int mid = (lo + hi) >> 1; if (ids[mid] < v) lo = mid + 1; else hi = mid; }
  return lo;
}

__global__ void fillzi(int* p, int n) {
  int i = blockIdx.x * 256 + threadIdx.x;
  if (i < n) p[i] = 0;
}
__global__ void fillzf(float* p, int n) {
  int i = blockIdx.x * 256 + threadIdx.x;
  if (i < n) p[i] = 0.f;
}

// ---------- CSR build: edges sorted by dst ----------
__global__ void hist_dst(const int* __restrict__ dst, int* __restrict__ cnt, int E) {
  int e = blockIdx.x * 256 + threadIdx.x;
  if (e < E) atomicAdd(&cnt[dst[e]], 1);
}

// multi-block exclusive scan, phase 1: per-block local exclusive scan + block sums
__global__ void scan_local(const int* __restrict__ cnt, int* __restrict__ rowptr,
                           int* __restrict__ blocksum, int N) {
  __shared__ int tmp[256];
  int t = threadIdx.x;
  int i = blockIdx.x * 256 + t;
  int v = (i < N) ? cnt[i] : 0;
  tmp[t] = v;
  __syncthreads();
  for (int ofs = 1; ofs < 256; ofs <<= 1) {
    int u = (t >= ofs) ? tmp[t - ofs] : 0;
    __syncthreads();
    tmp[t] += u;
    __syncthreads();
  }
  if (i < N) rowptr[i] = tmp[t] - v;          // exclusive
  if (t == 255) blocksum[blockIdx.x] = tmp[255];
}

// phase 2: single tiny block scans the <=256 block sums (exclusive, in place)
__global__ void scan_block(int* __restrict__ bs, int n) {
  __shared__ int tmp[256];
  int t = threadIdx.x;
  int v = (t < n) ? bs[t] : 0;
  tmp[t] = v;
  __syncthreads();
  for (int ofs = 1; ofs < 256; ofs <<= 1) {
    int u = (t >= ofs) ? tmp[t - ofs] : 0;
    __syncthreads();
    tmp[t] += u;
    __syncthreads();
  }
  if (t < n) bs[t] = tmp[t] - v;              // exclusive
}

// phase 3: add block offsets, mirror into cursor, set rowptr[N]=E
__global__ void scan_add(int* __restrict__ rowptr, int* __restrict__ cursor,
                         const int* __restrict__ blocksum, int N, int E) {
  int i = blockIdx.x * 256 + threadIdx.x;
  if (i < N) {
    int v = rowptr[i] + blocksum[blockIdx.x];
    rowptr[i] = v;
    cursor[i] = v;
  }
  if (i == 0) rowptr[N] = E;
}

// also emits invperm (orig->perm position) and src_perm (src in perm order)
__global__ void scatter_idx(const int* __restrict__ dst, const int* __restrict__ src,
                            int* __restrict__ cursor,
                            int* __restrict__ eperm, int* __restrict__ invperm,
                            int* __restrict__ src_perm, int E) {
  int e = blockIdx.x * 256 + threadIdx.x;
  if (e < E) {
    int p = atomicAdd(&cursor[dst[e]], 1);
    eperm[p] = e;
    invperm[e] = p;
    src_perm[p] = src[e];
  }
}

// ---------- prep: W[128][128] fp32 -> transposed, bf16, XOR-swizzled image ----------
__global__ void prep_w(const float* __restrict__ W, ushort* __restrict__ Wt) {
  int t = threadIdx.x;        // 256 threads, 1 block
  int n = t >> 1;
  int k0 = (t & 1) * 64;
  uint sw = (uint)(n & 7) << 3;
  for (int kk = 0; kk < 64; ++kk) {
    int k = k0 + kk;
    Wt[n * 128 + (k ^ sw)] = f2b(W[k * 128 + n]);
  }
}

// ---------- MFMA GEMM: Y[M,128](ldy) = X[M,128](ldx) @ W[128,128] + b ----------
// In-place safe (Y==X): each block reads only the rows it writes, via LDS.
template<typename TIn, typename TOut>
__global__ __launch_bounds__(256) void gemm_k128(const TIn* X, int ldx,
                                                 const ushort* __restrict__ Wt,
                                                 const float* __restrict__ b,
                                                 TOut* Y, int ldy, int M) {
  __shared__ ushort As[128 * 128];
  __shared__ ushort Bs[128 * 128];
  int t = threadIdx.x;
  int row0 = blockIdx.x * 128;

  { // stage B: linear copy (pre-swizzled in global)
    const uint4* s4 = (const uint4*)Wt + t * 8;
    uint4* d4 = (uint4*)Bs + t * 8;
#pragma unroll
    for (int c = 0; c < 8; ++c) d4[c] = s4[c];
  }
  { // stage A: row r = t>>1, k-half = (t&1)*64; convert to bf16, swizzled store
    int r = t >> 1;
    int k0h = (t & 1) * 64;
    int grow = row0 + r;
    uint sw = (uint)(r & 7) << 3;
    if (grow < M) {
      const TIn* xr = X + (size_t)grow * ldx;
#pragma unroll
      for (int c = 0; c < 8; ++c) {
        int k0 = k0h + c * 8;
        *(uint4*)(As + r * 128 + (k0 ^ sw)) = ldA8(xr + k0);
      }
    } else {
      uint4 z = make_uint4(0, 0, 0, 0);
#pragma unroll
      for (int c = 0; c < 8; ++c) {
        int k0 = k0h + c * 8;
        *(uint4*)(As + r * 128 + (k0 ^ sw)) = z;
      }
    }
  }
  __syncthreads();

  int lane = t & 63;
  int wid = t >> 6;
  int wr = wid >> 1, wc = wid & 1;
  uint swl = (uint)(lane & 7) << 3;

  f32x4 acc[4][4];
#pragma unroll
  for (int n4 = 0; n4 < 4; ++n4) {
    float bv = b[wc * 64 + n4 * 16 + (lane & 15)];
#pragma unroll
    for (int m4 = 0; m4 < 4; ++m4) acc[m4][n4] = (f32x4){bv, bv, bv, bv};
  }

#pragma unroll
  for (int kk = 0; kk < 4; ++kk) {
    int kidx = kk * 32 + 8 * (lane >> 4);
    short8 af[4], bfr[4];
#pragma unroll
    for (int m4 = 0; m4 < 4; ++m4) {
      int rm = wr * 64 + m4 * 16 + (lane & 15);
      af[m4] = *(const short8*)(As + rm * 128 + (kidx ^ swl));
    }
#pragma unroll
    for (int n4 = 0; n4 < 4; ++n4) {
      int cn = wc * 64 + n4 * 16 + (lane & 15);
      bfr[n4] = *(const short8*)(Bs + cn * 128 + (kidx ^ swl));
    }
#pragma unroll
    for (int m4 = 0; m4 < 4; ++m4)
#pragma unroll
      for (int n4 = 0; n4 < 4; ++n4)
        acc[m4][n4] = __builtin_amdgcn_mfma_f32_16x16x32_bf16(af[m4], bfr[n4], acc[m4][n4], 0, 0, 0);
  }

  int coln = wc * 64 + (lane & 15);
#pragma unroll
  for (int m4 = 0; m4 < 4; ++m4) {
    int rb = row0 + wr * 64 + m4 * 16 + ((lane >> 4) << 2);
#pragma unroll
    for (int n4 = 0; n4 < 4; ++n4) {
      int cc = coln + n4 * 16;
#pragma unroll
      for (int i = 0; i < 4; ++i)
        if (rb + i < M) st1(Y + (size_t)(rb + i) * ldy + cc, acc[m4][n4][i]);
    }
  }
}

// ---------- layer-1 fused node linears: ni+node -> f_nin[N][256], nj -> f_nj ----------
template<int K>
__global__ __launch_bounds__(128) void lin3_small(const float* __restrict__ X,
    const float* __restrict__ W1, const float* __restrict__ b1,
    const float* __restrict__ W2, const float* __restrict__ b2,
    const float* __restrict__ W3, const float* __restrict__ b3,
    ushort* __restrict__ Ynin, ushort* __restrict__ Ynj, int M) {
  constexpr int ROWS = 16;
  __shared__ float xs[ROWS * K];
  int t = threadIdx.x;
  int row0 = blockIdx.x * ROWS;
  int nr = M - row0; if (nr > ROWS) nr = ROWS;
  for (int i = t; i < nr * K; i += 128) xs[i] = X[(size_t)row0 * K + i];
  __syncthreads();
  float a1[ROWS], a2[ROWS], a3[ROWS];
  float v1 = b1[t], v2 = b2[t], v3 = b3[t];
#pragma unroll
  for (int r = 0; r < ROWS; ++r) { a1[r] = v1; a2[r] = v2; a3[r] = v3; }
#pragma unroll
  for (int k = 0; k < K; ++k) {
    float w1 = W1[k * 128 + t], w2 = W2[k * 128 + t], w3 = W3[k * 128 + t];
#pragma unroll
    for (int r = 0; r < ROWS; ++r) {
      float x = xs[r * K + k];
      a1[r] = fmaf(x, w1, a1[r]);
      a2[r] = fmaf(x, w2, a2[r]);
      a3[r] = fmaf(x, w3, a3[r]);
    }
  }
  for (int r = 0; r < nr; ++r) {
    size_t n = (size_t)(row0 + r);
    Ynin[n * 256 + t] = f2b(a1[r]);        // f_ni
    Ynin[n * 256 + 128 + t] = f2b(a3[r]);  // f_node
    Ynj[n * 128 + t] = f2b(a2[r]);
  }
}

// ---------- layer-1 edge linear (K=15), emits rows in dst-CSR (permuted) order ----------
template<int K>
__global__ __launch_bounds__(128) void lin1_perm(const float* __restrict__ X,
    const float* __restrict__ W, const float* __restrict__ b,
    const int* __restrict__ eperm, ushort* __restrict__ Y, int M) {
  constexpr int ROWS = 16;
  __shared__ float xs[ROWS * K];
  __shared__ int es[ROWS];
  int t = threadIdx.x;
  int row0 = blockIdx.x * ROWS;
  int nr = M - row0; if (nr > ROWS) nr = ROWS;
  if (t < nr) es[t] = eperm[row0 + t];
  __syncthreads();
  for (int i = t; i < nr * K; i += 128) {
    int r = i / K, c = i - r * K;
    xs[i] = X[(size_t)es[r] * K + c];
  }
  __syncthreads();
  float acc[ROWS];
  float bias = b[t];
#pragma unroll
  for (int r = 0; r < ROWS; ++r) acc[r] = bias;
#pragma unroll
  for (int k = 0; k < K; ++k) {
    float w = W[k * 128 + t];
#pragma unroll
    for (int r = 0; r < ROWS; ++r) acc[r] = fmaf(xs[r * K + k], w, acc[r]);
  }
  for (int r = 0; r < nr; ++r) Y[(size_t)(row0 + r) * 128 + t] = f2b(acc[r]);
}

// ---------- fused edge+aggregate stage, edge state in dst-CSR order ----------
// One wave per dst node d; its edges are the CONTIGUOUS rows [lo,hi) of ebp.
// Only remaining random access: the f_nin[src] gather (L2/L3-resident).
__global__ void egat_gather(const ushort* __restrict__ f_nin,   // [N][256] = ni | node
                            const ushort* __restrict__ f_nj,    // [N][128]
                            ushort* ebp,                         // [E][128] perm order, in/out
                            const int* __restrict__ src_perm,
                            const int* __restrict__ rowptr,
                            const float* __restrict__ attn,
                            float* __restrict__ nb, int N) {
  int d = blockIdx.x * 4 + (threadIdx.x >> 6);
  if (d >= N) return;
  int lane = threadIdx.x & 63;
  int lo = rowptr[d], hi = rowptr[d + 1];
  int h = lane >> 4;
  float2 at = *(const float2*)(attn + h * 32 + (lane & 15) * 2);
  uint unj = *((const uint*)(f_nj + (size_t)d * 128) + lane);
  float nj0 = b2f_lo(unj), nj1 = b2f_hi(unj);
  float acc0 = 0.f, acc1 = 0.f, exsum = 0.f;
  for (int i = lo; i < hi; ++i) {
    int s = src_perm[i];
    const uint* pn = (const uint*)(f_nin + (size_t)s * 256);
    uint uni = pn[lane];        // f_ni[s]
    uint und = pn[64 + lane];   // f_node[s]
    uint* ep = (uint*)(ebp + (size_t)i * 128) + lane;
    uint ue = *ep;
    float v0 = b2f_lo(ue) + b2f_lo(uni) + nj0;
    float v1 = b2f_hi(ue) + b2f_hi(uni) + nj1;
    v0 = v0 >= 0.f ? v0 : 0.01f * v0;
    v1 = v1 >= 0.f ? v1 : 0.01f * v1;
    *ep = (uint)f2b(v0) | ((uint)f2b(v1) << 16);
    float p = v0 * at.x + v1 * at.y;
    p += __shfl_xor(p, 1);
    p += __shfl_xor(p, 2);
    p += __shfl_xor(p, 4);
    p += __shfl_xor(p, 8);            // all 16 lanes of head h hold the logit
    float ev = __expf(p);             // softmax shift-invariant; logits O(1)
    exsum += ev;
    acc0 = fmaf(b2f_lo(und), ev, acc0);
    acc1 = fmaf(b2f_hi(und), ev, acc1);
  }
  float inv = exsum > 0.f ? 1.f / exsum : 0.f;
  float2* out = (float2*)(nb + (size_t)d * 128) + lane;
  *out = make_float2(acc0 * inv, acc1 * inv);
}

// ---------- streaming segment-sum over sorted ids ----------
// 4 waves per block, ROWS rows per wave; register accumulate; atomicAdd flush
// at segment boundaries only. S must be zeroed beforehand.
template<int ROWS>
__global__ __launch_bounds__(256) void segsum_f32(const float* __restrict__ X,
    const int* __restrict__ ids, int M, float* __restrict__ S) {
  int r0 = (blockIdx.x * 4 + (threadIdx.x >> 6)) * ROWS;
  if (r0 >= M) return;
  int r1 = r0 + ROWS; if (r1 > M) r1 = M;
  int t = threadIdx.x & 63;
  float a0 = 0.f, a1 = 0.f;
  int cur = ids[r0];
  for (int r = r0; r < r1; ++r) {
    int id = ids[r];
    if (id != cur) {
      atomicAdd(&S[(size_t)cur * 128 + 2 * t], a0);
      atomicAdd(&S[(size_t)cur * 128 + 2 * t + 1], a1);
      a0 = a1 = 0.f; cur = id;
    }
    float2 v = *(const float2*)(X + (size_t)r * 128 + 2 * t);
    a0 += v.x; a1 += v.y;
  }
  atomicAdd(&S[(size_t)cur * 128 + 2 * t], a0);
  atomicAdd(&S[(size_t)cur * 128 + 2 * t + 1], a1);
}

// bf16 variant with row indirection (X rows live at invperm[r])
template<int ROWS>
__global__ __launch_bounds__(256) void segsum_bf16g(const ushort* __restrict__ X,
    const int* __restrict__ invperm,
    const int* __restrict__ ids, int M, float* __restrict__ S) {
  int r0 = (blockIdx.x * 4 + (threadIdx.x >> 6)) * ROWS;
  if (r0 >= M) return;
  int r1 = r0 + ROWS; if (r1 > M) r1 = M;
  int t = threadIdx.x & 63;
  float a0 = 0.f, a1 = 0.f;
  int cur = ids[r0];
  for (int r = r0; r < r1; ++r) {
    int id = ids[r];
    if (id != cur) {
      atomicAdd(&S[(size_t)cur * 128 + 2 * t], a0);
      atomicAdd(&S[(size_t)cur * 128 + 2 * t + 1], a1);
      a0 = a1 = 0.f; cur = id;
    }
    uint u = *((const uint*)(X + (size_t)invperm[r] * 128) + t);
    a0 += b2f_lo(u); a1 += b2f_hi(u);
  }
  atomicAdd(&S[(size_t)cur * 128 + 2 * t], a0);
  atomicAdd(&S[(size_t)cur * 128 + 2 * t + 1], a1);
}

// cnt[g] = number of (sorted) ids equal to g
__global__ void seg_cnt(const int* __restrict__ ids, int M, int* __restrict__ cnt, int G) {
  int g = blockIdx.x * 256 + threadIdx.x;
  if (g < G) cnt[g] = lowerb(ids, M, g + 1) - lowerb(ids, M, g);
}

// ---------- out[g, coloff+t] = (SP[g]-SR[g]) @ W + cnt[g]*b ----------
__global__ void diff_linear(const float* __restrict__ SP, const float* __restrict__ SR,
                            const int* __restrict__ cnt,
                            const float* __restrict__ W, const float* __restrict__ b,
                            float* __restrict__ out, int ldo, int coloff) {
  int g = blockIdx.x;
  int t = threadIdx.x;
  __shared__ float xs[128];
  xs[t] = SP[(size_t)g * 128 + t] - SR[(size_t)g * 128 + t];
  __syncthreads();
  float acc = (float)cnt[g] * b[t];
  for (int k = 0; k < 128; ++k) acc = fmaf(xs[k], W[k * 128 + t], acc);
  out[(size_t)g * ldo + coloff + t] = acc;
}

template<int K, int NC, bool RELU>
__global__ void mlp_linear(const float* __restrict__ X, const float* __restrict__ W,
                           const float* __restrict__ b, float* __restrict__ Y) {
  int g = blockIdx.x;
  int t = threadIdx.x;
  __shared__ float xs[K];
  for (int i = t; i < K; i += NC) xs[i] = X[(size_t)g * K + i];
  __syncthreads();
  float acc = b[t];
  for (int k = 0; k < K; ++k) acc = fmaf(xs[k], W[k * NC + t], acc);
  if (RELU) acc = fmaxf(acc, 0.f);
  Y[(size_t)g * NC + t] = acc;
}

__global__ void mlp_final(const float* __restrict__ X, const float* __restrict__ W,
                          const float* __restrict__ b, float* __restrict__ out, int G) {
  int g = blockIdx.x * blockDim.x + threadIdx.x;
  if (g >= G) return;
  float acc = b[0];
  for (int k = 0; k < 256; ++k) acc = fmaf(X[(size_t)g * 256 + k], W[k], acc);
  out[g] = acc;
}

struct LayerW {
  const float *Wni, *bni, *Wnj, *bnj, *Wf, *bf, *Wnode, *bnode, *attn;
};

extern "C" void kernel_launch(void* const* d_in, const int* in_sizes, int n_in,
                              void* d_out, int out_size, void* d_ws, size_t ws_size,
                              hipStream_t stream) {
  const float* hR = (const float*)d_in[0];
  const float* eR = (const float*)d_in[1];
  const float* hP = (const float*)d_in[2];
  const float* eP = (const float*)d_in[3];
  const int* srcR = (const int*)d_in[4];
  const int* dstR = (const int*)d_in[5];
  const int* srcP = (const int*)d_in[6];
  const int* dstP = (const int*)d_in[7];
  const int* nid  = (const int*)d_in[8];
  const int* eid  = (const int*)d_in[9];
  LayerW w1 { (const float*)d_in[10], (const float*)d_in[11], (const float*)d_in[12],
              (const float*)d_in[13], (const float*)d_in[14], (const float*)d_in[15],
              (const float*)d_in[16], (const float*)d_in[17], (const float*)d_in[18] };
  LayerW w2 { (const float*)d_in[19], (const float*)d_in[20], (const float*)d_in[21],
              (const float*)d_in[22], (const float*)d_in[23], (const float*)d_in[24],
              (const float*)d_in[25], (const float*)d_in[26], (const float*)d_in[27] };
  const float* Wa_n = (const float*)d_in[28];
  const float* ba_n = (const float*)d_in[29];
  const float* Wa_e = (const float*)d_in[30];
  const float* ba_e = (const float*)d_in[31];
  const float* Wm1  = (const float*)d_in[32];
  const float* bm1  = (const float*)d_in[33];
  const float* Wm2  = (const float*)d_in[34];
  const float* bm2  = (const float*)d_in[35];
  const float* Wm3  = (const float*)d_in[36];
  const float* bm3  = (const float*)d_in[37];

  const int N = in_sizes[0] / 17;   // 60000
  const int E = in_sizes[4];        // 240000
  const int G = out_size;           // 1024

  // ---- workspace carve-up ----
  char* base = (char*)d_ws;
  size_t off = 0;
  auto alloc = [&](size_t bytes) { char* p = base + off; off += (bytes + 255) & ~(size_t)255; return p; };
  float*  nb     = (float*)alloc((size_t)N * 128 * 4);    // node state fp32
  ushort* f_nin  = (ushort*)alloc((size_t)N * 256 * 2);   // [ni | node] fused rows
  ushort* f_nj   = (ushort*)alloc((size_t)N * 128 * 2);
  ushort* ebp    = (ushort*)alloc((size_t)E * 128 * 2);   // edge state bf16, dst-CSR order
  int*    rowptrP = (int*)alloc((size_t)(N + 1) * 4);
  int*    rowptrR = (int*)alloc((size_t)(N + 1) * 4);
  int*    epermP  = (int*)alloc((size_t)E * 4);
  int*    epermR  = (int*)alloc((size_t)E * 4);
  int*    invpermP = (int*)alloc((size_t)E * 4);
  int*    invpermR = (int*)alloc((size_t)E * 4);
  int*    srcpermP = (int*)alloc((size_t)E * 4);
  int*    srcpermR = (int*)alloc((size_t)E * 4);
  int*    cnt     = (int*)alloc((size_t)N * 4);
  int*    cursor  = (int*)alloc((size_t)N * 4);
  int*    blocksum = (int*)alloc(1024 * 4);
  ushort* Wt_ni  = (ushort*)alloc(128 * 128 * 2);
  ushort* Wt_nj  = (ushort*)alloc(128 * 128 * 2);
  ushort* Wt_f   = (ushort*)alloc(128 * 128 * 2);
  ushort* Wt_nd  = (ushort*)alloc(128 * 128 * 2);
  float*  SnP    = (float*)alloc((size_t)G * 128 * 4);
  float*  SnR    = (float*)alloc((size_t)G * 128 * 4);
  float*  SeP    = (float*)alloc((size_t)G * 128 * 4);
  float*  SeR    = (float*)alloc((size_t)G * 128 * 4);
  float*  Gf     = (float*)alloc((size_t)G * 256 * 4);
  float*  x1     = (float*)alloc((size_t)G * 512 * 4);
  float*  x2     = (float*)alloc((size_t)G * 256 * 4);
  int*    cnt_n  = (int*)alloc((size_t)G * 4);
  int*    cnt_e  = (int*)alloc((size_t)G * 4);
  if (off > ws_size) return;  // graceful fail

  const int EB = (E + 255) / 256;
  const int NB = (N + 255) / 256;   // 235 <= 256, fits scan_block

  // ---- zero the 4 contiguous S accumulators (SnP..SeR) once ----
  fillzf<<<(G * 512 + 255) / 256, 256, 0, stream>>>(SnP, G * 512);

  // ---- CSR builds (multi-block scan; P then R, cnt/cursor/blocksum shared) ----
  auto build_csr = [&](const int* dst, const int* src, int* rowptr,
                       int* eperm, int* invperm, int* src_perm) {
    fillzi<<<NB, 256, 0, stream>>>(cnt, N);
    hist_dst<<<EB, 256, 0, stream>>>(dst, cnt, E);
    scan_local<<<NB, 256, 0, stream>>>(cnt, rowptr, blocksum, N);
    scan_block<<<1, 256, 0, stream>>>(blocksum, NB);
    scan_add<<<NB, 256, 0, stream>>>(rowptr, cursor, blocksum, N, E);
    scatter_idx<<<EB, 256, 0, stream>>>(dst, src, cursor, eperm, invperm, src_perm, E);
  };
  build_csr(dstP, srcP, rowptrP, epermP, invpermP, srcpermP);
  build_csr(dstR, srcR, rowptrR, epermR, invpermR, srcpermR);

  // ---- prep egat2 weights (bf16, transposed, swizzled) ----
  prep_w<<<1, 256, 0, stream>>>(w2.Wni,   Wt_ni);
  prep_w<<<1, 256, 0, stream>>>(w2.Wnj,   Wt_nj);
  prep_w<<<1, 256, 0, stream>>>(w2.Wf,    Wt_f);
  prep_w<<<1, 256, 0, stream>>>(w2.Wnode, Wt_nd);

  // ---- per-graph counts ----
  seg_cnt<<<(G + 255) / 256, 256, 0, stream>>>(nid, N, cnt_n, G);
  seg_cnt<<<(G + 255) / 256, 256, 0, stream>>>(eid, E, cnt_e, G);

  const int GB = (N + 3) / 4;      // egat_gather grid

  auto layer1 = [&](const float* h, const float* e, const int* eperm,
                    const int* src_perm, const int* rowptr) {
    lin3_small<17><<<(N + 15) / 16, 128, 0, stream>>>(h, w1.Wni, w1.bni, w1.Wnj, w1.bnj,
                                                      w1.Wnode, w1.bnode, f_nin, f_nj, N);
    lin1_perm<15><<<(E + 15) / 16, 128, 0, stream>>>(e, w1.Wf, w1.bf, eperm, ebp, E);
    egat_gather<<<GB, 256, 0, stream>>>(f_nin, f_nj, ebp, src_perm, rowptr, w1.attn, nb, N);
  };
  auto layer2 = [&](const int* src_perm, const int* rowptr) {
    gemm_k128<float, ushort><<<(N + 127) / 128, 256, 0, stream>>>(nb, 128, Wt_ni, w2.bni, f_nin, 256, N);
    gemm_k128<float, ushort><<<(N + 127) / 128, 256, 0, stream>>>(nb, 128, Wt_nd, w2.bnode, f_nin + 128, 256, N);
    gemm_k128<float, ushort><<<(N + 127) / 128, 256, 0, stream>>>(nb, 128, Wt_nj, w2.bnj, f_nj, 128, N);
    gemm_k128<ushort, ushort><<<(E + 127) / 128, 256, 0, stream>>>(ebp, 128, Wt_f, w2.bf, ebp, 128, E);
    egat_gather<<<GB, 256, 0, stream>>>(f_nin, f_nj, ebp, src_perm, rowptr, w2.attn, nb, N);
  };

  // ---- P branch: one egat1 layer, reduce to G x 128 ----
  layer1(hP, eP, epermP, srcpermP, rowptrP);
  segsum_f32<32><<<(N + 127) / 128, 256, 0, stream>>>(nb, nid, N, SnP);
  segsum_bf16g<16><<<(E + 63) / 64, 256, 0, stream>>>(ebp, invpermP, eid, E, SeP);

  // ---- R branch: egat1 + egat2 x2 ----
  layer1(hR, eR, epermR, srcpermR, rowptrR);
  layer2(srcpermR, rowptrR);
  layer2(srcpermR, rowptrR);
  segsum_f32<32><<<(N + 127) / 128, 256, 0, stream>>>(nb, nid, N, SnR);
  segsum_bf16g<16><<<(E + 63) / 64, 256, 0, stream>>>(ebp, invpermR, eid, E, SeR);

  // ---- Diff aggregate + per-graph linears ----
  diff_linear<<<G, 128, 0, stream>>>(SnP, SnR, cnt_n, Wa_n, ba_n, Gf, 256, 0);
  diff_linear<<<G, 128, 0, stream>>>(SeP, SeR, cnt_e, Wa_e, ba_e, Gf, 256, 128);

  // ---- MLP head ----
  mlp_linear<256, 512, true><<<G, 512, 0, stream>>>(Gf, Wm1, bm1, x1);
  mlp_linear<512, 256, true><<<G, 256, 0, stream>>>(x1, Wm2, bm2, x2);
  mlp_final<<<(G + 255) / 256, 256, 0, stream>>>(x2, Wm3, bm3, (float*)d_out, G);
}

// Round 9
// 713.322 us; speedup vs baseline: 3.8388x; 1.0380x over previous
//
#include <hip/hip_runtime.h>
#include <cstddef>
#include <cstdint>

typedef unsigned int uint;
typedef unsigned short ushort;
typedef __attribute__((ext_vector_type(4))) float f32x4;
typedef __attribute__((ext_vector_type(8))) short short8;

// ---------- bf16 helpers (storage = ushort) ----------
__device__ __forceinline__ ushort f2b(float v) {
  uint x = __float_as_uint(v);
  return (ushort)((x + 0x7fffu + ((x >> 16) & 1u)) >> 16);  // RNE
}
__device__ __forceinline__ float b2f_lo(uint u) { return __uint_as_float(u << 16); }
__device__ __forceinline__ float b2f_hi(uint u) { return __uint_as_float(u & 0xffff0000u); }
__device__ __forceinline__ float ld1(const float* p) { return *p; }
__device__ __forceinline__ float ld1(const ushort* p) { return __uint_as_float(((uint)*p) << 16); }
__device__ __forceinline__ void st1(float* p, float v) { *p = v; }
__device__ __forceinline__ void st1(ushort* p, float v) { *p = f2b(v); }

// load 8 consecutive elems as packed bf16 (uint4 = 8 x bf16)
__device__ __forceinline__ uint4 ldA8(const float* p) {
  float4 a = *(const float4*)p;
  float4 b = *(const float4*)(p + 4);
  uint4 r;
  r.x = (uint)f2b(a.x) | ((uint)f2b(a.y) << 16);
  r.y = (uint)f2b(a.z) | ((uint)f2b(a.w) << 16);
  r.z = (uint)f2b(b.x) | ((uint)f2b(b.y) << 16);
  r.w = (uint)f2b(b.z) | ((uint)f2b(b.w) << 16);
  return r;
}
__device__ __forceinline__ uint4 ldA8(const ushort* p) { return *(const uint4*)p; }

__device__ __forceinline__ int lowerb(const int* __restrict__ ids, int M, int v) {
  int lo = 0, hi = M;
  while (lo < hi) { int mid = (lo + hi) >> 1; if (ids[mid] < v) lo = mid + 1; else hi = mid; }
  return lo;
}

__global__ void fillzi(int* p, int n) {
  int i = blockIdx.x * 256 + threadIdx.x;
  if (i < n) p[i] = 0;
}
__global__ void fillzf(float* p, int n) {
  int i = blockIdx.x * 256 + threadIdx.x;
  if (i < n) p[i] = 0.f;
}

// ---------- CSR build: edges sorted by dst ----------
__global__ void hist_dst(const int* __restrict__ dst, int* __restrict__ cnt, int E) {
  int e = blockIdx.x * 256 + threadIdx.x;
  if (e < E) atomicAdd(&cnt[dst[e]], 1);
}

__global__ void scan_local(const int* __restrict__ cnt, int* __restrict__ rowptr,
                           int* __restrict__ blocksum, int N) {
  __shared__ int tmp[256];
  int t = threadIdx.x;
  int i = blockIdx.x * 256 + t;
  int v = (i < N) ? cnt[i] : 0;
  tmp[t] = v;
  __syncthreads();
  for (int ofs = 1; ofs < 256; ofs <<= 1) {
    int u = (t >= ofs) ? tmp[t - ofs] : 0;
    __syncthreads();
    tmp[t] += u;
    __syncthreads();
  }
  if (i < N) rowptr[i] = tmp[t] - v;          // exclusive
  if (t == 255) blocksum[blockIdx.x] = tmp[255];
}

__global__ void scan_block(int* __restrict__ bs, int n) {
  __shared__ int tmp[256];
  int t = threadIdx.x;
  int v = (t < n) ? bs[t] : 0;
  tmp[t] = v;
  __syncthreads();
  for (int ofs = 1; ofs < 256; ofs <<= 1) {
    int u = (t >= ofs) ? tmp[t - ofs] : 0;
    __syncthreads();
    tmp[t] += u;
    __syncthreads();
  }
  if (t < n) bs[t] = tmp[t] - v;              // exclusive
}

__global__ void scan_add(int* __restrict__ rowptr, int* __restrict__ cursor,
                         const int* __restrict__ blocksum, int N, int E) {
  int i = blockIdx.x * 256 + threadIdx.x;
  if (i < N) {
    int v = rowptr[i] + blocksum[blockIdx.x];
    rowptr[i] = v;
    cursor[i] = v;
  }
  if (i == 0) rowptr[N] = E;
}

// also emits invperm (orig->perm position) and src_perm (src in perm order)
__global__ void scatter_idx(const int* __restrict__ dst, const int* __restrict__ src,
                            int* __restrict__ cursor,
                            int* __restrict__ eperm, int* __restrict__ invperm,
                            int* __restrict__ src_perm, int E) {
  int e = blockIdx.x * 256 + threadIdx.x;
  if (e < E) {
    int p = atomicAdd(&cursor[dst[e]], 1);
    eperm[p] = e;
    invperm[e] = p;
    src_perm[p] = src[e];
  }
}

// ---------- prep: W[128][128] fp32 -> transposed, bf16, XOR-swizzled image ----------
__global__ void prep_w(const float* __restrict__ W, ushort* __restrict__ Wt) {
  int t = threadIdx.x;        // 256 threads, 1 block
  int n = t >> 1;
  int k0 = (t & 1) * 64;
  uint sw = (uint)(n & 7) << 3;
  for (int kk = 0; kk < 64; ++kk) {
    int k = k0 + kk;
    Wt[n * 128 + (k ^ sw)] = f2b(W[k * 128 + n]);
  }
}

// ---------- MFMA GEMM: Y[M,128](ldy) = X[M,128](ldx) @ W[128,128] + b ----------
// In-place safe (Y==X): each block reads only the rows it writes, via LDS.
template<typename TIn, typename TOut>
__global__ __launch_bounds__(256) void gemm_k128(const TIn* X, int ldx,
                                                 const ushort* __restrict__ Wt,
                                                 const float* __restrict__ b,
                                                 TOut* Y, int ldy, int M) {
  __shared__ ushort As[128 * 128];
  __shared__ ushort Bs[128 * 128];
  int t = threadIdx.x;
  int row0 = blockIdx.x * 128;

  { // stage B: linear copy (pre-swizzled in global)
    const uint4* s4 = (const uint4*)Wt + t * 8;
    uint4* d4 = (uint4*)Bs + t * 8;
#pragma unroll
    for (int c = 0; c < 8; ++c) d4[c] = s4[c];
  }
  { // stage A
    int r = t >> 1;
    int k0h = (t & 1) * 64;
    int grow = row0 + r;
    uint sw = (uint)(r & 7) << 3;
    if (grow < M) {
      const TIn* xr = X + (size_t)grow * ldx;
#pragma unroll
      for (int c = 0; c < 8; ++c) {
        int k0 = k0h + c * 8;
        *(uint4*)(As + r * 128 + (k0 ^ sw)) = ldA8(xr + k0);
      }
    } else {
      uint4 z = make_uint4(0, 0, 0, 0);
#pragma unroll
      for (int c = 0; c < 8; ++c) {
        int k0 = k0h + c * 8;
        *(uint4*)(As + r * 128 + (k0 ^ sw)) = z;
      }
    }
  }
  __syncthreads();

  int lane = t & 63;
  int wid = t >> 6;
  int wr = wid >> 1, wc = wid & 1;
  uint swl = (uint)(lane & 7) << 3;

  f32x4 acc[4][4];
#pragma unroll
  for (int n4 = 0; n4 < 4; ++n4) {
    float bv = b[wc * 64 + n4 * 16 + (lane & 15)];
#pragma unroll
    for (int m4 = 0; m4 < 4; ++m4) acc[m4][n4] = (f32x4){bv, bv, bv, bv};
  }

#pragma unroll
  for (int kk = 0; kk < 4; ++kk) {
    int kidx = kk * 32 + 8 * (lane >> 4);
    short8 af[4], bfr[4];
#pragma unroll
    for (int m4 = 0; m4 < 4; ++m4) {
      int rm = wr * 64 + m4 * 16 + (lane & 15);
      af[m4] = *(const short8*)(As + rm * 128 + (kidx ^ swl));
    }
#pragma unroll
    for (int n4 = 0; n4 < 4; ++n4) {
      int cn = wc * 64 + n4 * 16 + (lane & 15);
      bfr[n4] = *(const short8*)(Bs + cn * 128 + (kidx ^ swl));
    }
#pragma unroll
    for (int m4 = 0; m4 < 4; ++m4)
#pragma unroll
      for (int n4 = 0; n4 < 4; ++n4)
        acc[m4][n4] = __builtin_amdgcn_mfma_f32_16x16x32_bf16(af[m4], bfr[n4], acc[m4][n4], 0, 0, 0);
  }

  int coln = wc * 64 + (lane & 15);
#pragma unroll
  for (int m4 = 0; m4 < 4; ++m4) {
    int rb = row0 + wr * 64 + m4 * 16 + ((lane >> 4) << 2);
#pragma unroll
    for (int n4 = 0; n4 < 4; ++n4) {
      int cc = coln + n4 * 16;
#pragma unroll
      for (int i = 0; i < 4; ++i)
        if (rb + i < M) st1(Y + (size_t)(rb + i) * ldy + cc, acc[m4][n4][i]);
    }
  }
}

// ---------- fused triple GEMM: stage A once, apply 3 weight matrices ----------
// X is bf16 [M][128]; outputs Yw (bf16) with per-output ld. A-tile staged once.
__global__ __launch_bounds__(256) void gemm3_k128(
    const ushort* __restrict__ X,
    const ushort* __restrict__ Wt0, const float* __restrict__ b0, ushort* __restrict__ Y0, int ldy0,
    const ushort* __restrict__ Wt1, const float* __restrict__ b1, ushort* __restrict__ Y1, int ldy1,
    const ushort* __restrict__ Wt2, const float* __restrict__ b2, ushort* __restrict__ Y2, int ldy2,
    int M) {
  __shared__ ushort As[128 * 128];
  __shared__ ushort Bs[128 * 128];
  int t = threadIdx.x;
  int row0 = blockIdx.x * 128;

  { // stage A: pure linear bf16 copy, swizzled store
    int r = t >> 1;
    int k0h = (t & 1) * 64;
    int grow = row0 + r;
    uint sw = (uint)(r & 7) << 3;
    if (grow < M) {
      const ushort* xr = X + (size_t)grow * 128;
#pragma unroll
      for (int c = 0; c < 8; ++c) {
        int k0 = k0h + c * 8;
        *(uint4*)(As + r * 128 + (k0 ^ sw)) = *(const uint4*)(xr + k0);
      }
    } else {
      uint4 z = make_uint4(0, 0, 0, 0);
#pragma unroll
      for (int c = 0; c < 8; ++c) {
        int k0 = k0h + c * 8;
        *(uint4*)(As + r * 128 + (k0 ^ sw)) = z;
      }
    }
  }

  int lane = t & 63;
  int wid = t >> 6;
  int wr = wid >> 1, wc = wid & 1;
  uint swl = (uint)(lane & 7) << 3;

#pragma unroll
  for (int w = 0; w < 3; ++w) {
    const ushort* Wt = (w == 0) ? Wt0 : (w == 1) ? Wt1 : Wt2;
    const float* bb  = (w == 0) ? b0  : (w == 1) ? b1  : b2;
    ushort* Y        = (w == 0) ? Y0  : (w == 1) ? Y1  : Y2;
    int ldy          = (w == 0) ? ldy0 : (w == 1) ? ldy1 : ldy2;

    if (w > 0) __syncthreads();           // prior Bs reads complete
    { // stage B (linear, pre-swizzled)
      const uint4* s4 = (const uint4*)Wt + t * 8;
      uint4* d4 = (uint4*)Bs + t * 8;
#pragma unroll
      for (int c = 0; c < 8; ++c) d4[c] = s4[c];
    }
    __syncthreads();                      // Bs (and As on w==0) visible

    f32x4 acc[4][4];
#pragma unroll
    for (int n4 = 0; n4 < 4; ++n4) {
      float bv = bb[wc * 64 + n4 * 16 + (lane & 15)];
#pragma unroll
      for (int m4 = 0; m4 < 4; ++m4) acc[m4][n4] = (f32x4){bv, bv, bv, bv};
    }
#pragma unroll
    for (int kk = 0; kk < 4; ++kk) {
      int kidx = kk * 32 + 8 * (lane >> 4);
      short8 af[4], bfr[4];
#pragma unroll
      for (int m4 = 0; m4 < 4; ++m4) {
        int rm = wr * 64 + m4 * 16 + (lane & 15);
        af[m4] = *(const short8*)(As + rm * 128 + (kidx ^ swl));
      }
#pragma unroll
      for (int n4 = 0; n4 < 4; ++n4) {
        int cn = wc * 64 + n4 * 16 + (lane & 15);
        bfr[n4] = *(const short8*)(Bs + cn * 128 + (kidx ^ swl));
      }
#pragma unroll
      for (int m4 = 0; m4 < 4; ++m4)
#pragma unroll
        for (int n4 = 0; n4 < 4; ++n4)
          acc[m4][n4] = __builtin_amdgcn_mfma_f32_16x16x32_bf16(af[m4], bfr[n4], acc[m4][n4], 0, 0, 0);
    }
    int coln = wc * 64 + (lane & 15);
#pragma unroll
    for (int m4 = 0; m4 < 4; ++m4) {
      int rb = row0 + wr * 64 + m4 * 16 + ((lane >> 4) << 2);
#pragma unroll
      for (int n4 = 0; n4 < 4; ++n4) {
        int cc = coln + n4 * 16;
#pragma unroll
        for (int i = 0; i < 4; ++i)
          if (rb + i < M) Y[(size_t)(rb + i) * ldy + cc] = f2b(acc[m4][n4][i]);
      }
    }
  }
}

// ---------- layer-1 fused node linears: ni+node -> f_nin[N][256], nj -> f_nj ----------
template<int K>
__global__ __launch_bounds__(128) void lin3_small(const float* __restrict__ X,
    const float* __restrict__ W1, const float* __restrict__ b1,
    const float* __restrict__ W2, const float* __restrict__ b2,
    const float* __restrict__ W3, const float* __restrict__ b3,
    ushort* __restrict__ Ynin, ushort* __restrict__ Ynj, int M) {
  constexpr int ROWS = 16;
  __shared__ float xs[ROWS * K];
  int t = threadIdx.x;
  int row0 = blockIdx.x * ROWS;
  int nr = M - row0; if (nr > ROWS) nr = ROWS;
  for (int i = t; i < nr * K; i += 128) xs[i] = X[(size_t)row0 * K + i];
  __syncthreads();
  float a1[ROWS], a2[ROWS], a3[ROWS];
  float v1 = b1[t], v2 = b2[t], v3 = b3[t];
#pragma unroll
  for (int r = 0; r < ROWS; ++r) { a1[r] = v1; a2[r] = v2; a3[r] = v3; }
#pragma unroll
  for (int k = 0; k < K; ++k) {
    float w1 = W1[k * 128 + t], w2 = W2[k * 128 + t], w3 = W3[k * 128 + t];
#pragma unroll
    for (int r = 0; r < ROWS; ++r) {
      float x = xs[r * K + k];
      a1[r] = fmaf(x, w1, a1[r]);
      a2[r] = fmaf(x, w2, a2[r]);
      a3[r] = fmaf(x, w3, a3[r]);
    }
  }
  for (int r = 0; r < nr; ++r) {
    size_t n = (size_t)(row0 + r);
    Ynin[n * 256 + t] = f2b(a1[r]);        // f_ni
    Ynin[n * 256 + 128 + t] = f2b(a3[r]);  // f_node
    Ynj[n * 128 + t] = f2b(a2[r]);
  }
}

// ---------- layer-1 edge linear (K=15), emits rows in dst-CSR (permuted) order ----------
template<int K>
__global__ __launch_bounds__(128) void lin1_perm(const float* __restrict__ X,
    const float* __restrict__ W, const float* __restrict__ b,
    const int* __restrict__ eperm, ushort* __restrict__ Y, int M) {
  constexpr int ROWS = 16;
  __shared__ float xs[ROWS * K];
  __shared__ int es[ROWS];
  int t = threadIdx.x;
  int row0 = blockIdx.x * ROWS;
  int nr = M - row0; if (nr > ROWS) nr = ROWS;
  if (t < nr) es[t] = eperm[row0 + t];
  __syncthreads();
  for (int i = t; i < nr * K; i += 128) {
    int r = i / K, c = i - r * K;
    xs[i] = X[(size_t)es[r] * K + c];
  }
  __syncthreads();
  float acc[ROWS];
  float bias = b[t];
#pragma unroll
  for (int r = 0; r < ROWS; ++r) acc[r] = bias;
#pragma unroll
  for (int k = 0; k < K; ++k) {
    float w = W[k * 128 + t];
#pragma unroll
    for (int r = 0; r < ROWS; ++r) acc[r] = fmaf(xs[r * K + k], w, acc[r]);
  }
  for (int r = 0; r < nr; ++r) Y[(size_t)(row0 + r) * 128 + t] = f2b(acc[r]);
}

// ---------- fused edge+aggregate stage, edge state in dst-CSR order ----------
// One wave per dst node d; its edges are the CONTIGUOUS rows [lo,hi) of ebp.
// nb output is bf16 (identical to the bf16 the GEMM would stage anyway).
__global__ void egat_gather(const ushort* __restrict__ f_nin,   // [N][256] = ni | node
                            const ushort* __restrict__ f_nj,    // [N][128]
                            ushort* ebp,                         // [E][128] perm order, in/out
                            const int* __restrict__ src_perm,
                            const int* __restrict__ rowptr,
                            const float* __restrict__ attn,
                            ushort* __restrict__ nb, int N) {
  int d = blockIdx.x * 4 + (threadIdx.x >> 6);
  if (d >= N) return;
  int lane = threadIdx.x & 63;
  int lo = rowptr[d], hi = rowptr[d + 1];
  int h = lane >> 4;
  float2 at = *(const float2*)(attn + h * 32 + (lane & 15) * 2);
  uint unj = *((const uint*)(f_nj + (size_t)d * 128) + lane);
  float nj0 = b2f_lo(unj), nj1 = b2f_hi(unj);
  float acc0 = 0.f, acc1 = 0.f, exsum = 0.f;
  for (int i = lo; i < hi; ++i) {
    int s = src_perm[i];
    const uint* pn = (const uint*)(f_nin + (size_t)s * 256);
    uint uni = pn[lane];        // f_ni[s]
    uint und = pn[64 + lane];   // f_node[s]
    uint* ep = (uint*)(ebp + (size_t)i * 128) + lane;
    uint ue = *ep;
    float v0 = b2f_lo(ue) + b2f_lo(uni) + nj0;
    float v1 = b2f_hi(ue) + b2f_hi(uni) + nj1;
    v0 = v0 >= 0.f ? v0 : 0.01f * v0;
    v1 = v1 >= 0.f ? v1 : 0.01f * v1;
    *ep = (uint)f2b(v0) | ((uint)f2b(v1) << 16);
    float p = v0 * at.x + v1 * at.y;
    p += __shfl_xor(p, 1);
    p += __shfl_xor(p, 2);
    p += __shfl_xor(p, 4);
    p += __shfl_xor(p, 8);            // all 16 lanes of head h hold the logit
    float ev = __expf(p);             // softmax shift-invariant; logits O(1)
    exsum += ev;
    acc0 = fmaf(b2f_lo(und), ev, acc0);
    acc1 = fmaf(b2f_hi(und), ev, acc1);
  }
  float inv = exsum > 0.f ? 1.f / exsum : 0.f;
  ((uint*)(nb + (size_t)d * 128))[lane] =
      (uint)f2b(acc0 * inv) | ((uint)f2b(acc1 * inv) << 16);
}

// ---------- streaming segment-sum over sorted ids (4 waves/block) ----------
template<int ROWS>
__global__ __launch_bounds__(256) void segsum_bf16(const ushort* __restrict__ X,
    const int* __restrict__ ids, int M, float* __restrict__ S) {
  int r0 = (blockIdx.x * 4 + (threadIdx.x >> 6)) * ROWS;
  if (r0 >= M) return;
  int r1 = r0 + ROWS; if (r1 > M) r1 = M;
  int t = threadIdx.x & 63;
  float a0 = 0.f, a1 = 0.f;
  int cur = ids[r0];
  for (int r = r0; r < r1; ++r) {
    int id = ids[r];
    if (id != cur) {
      atomicAdd(&S[(size_t)cur * 128 + 2 * t], a0);
      atomicAdd(&S[(size_t)cur * 128 + 2 * t + 1], a1);
      a0 = a1 = 0.f; cur = id;
    }
    uint u = *((const uint*)(X + (size_t)r * 128) + t);
    a0 += b2f_lo(u); a1 += b2f_hi(u);
  }
  atomicAdd(&S[(size_t)cur * 128 + 2 * t], a0);
  atomicAdd(&S[(size_t)cur * 128 + 2 * t + 1], a1);
}

// bf16 variant with row indirection (X rows live at invperm[r])
template<int ROWS>
__global__ __launch_bounds__(256) void segsum_bf16g(const ushort* __restrict__ X,
    const int* __restrict__ invperm,
    const int* __restrict__ ids, int M, float* __restrict__ S) {
  int r0 = (blockIdx.x * 4 + (threadIdx.x >> 6)) * ROWS;
  if (r0 >= M) return;
  int r1 = r0 + ROWS; if (r1 > M) r1 = M;
  int t = threadIdx.x & 63;
  float a0 = 0.f, a1 = 0.f;
  int cur = ids[r0];
  for (int r = r0; r < r1; ++r) {
    int id = ids[r];
    if (id != cur) {
      atomicAdd(&S[(size_t)cur * 128 + 2 * t], a0);
      atomicAdd(&S[(size_t)cur * 128 + 2 * t + 1], a1);
      a0 = a1 = 0.f; cur = id;
    }
    uint u = *((const uint*)(X + (size_t)invperm[r] * 128) + t);
    a0 += b2f_lo(u); a1 += b2f_hi(u);
  }
  atomicAdd(&S[(size_t)cur * 128 + 2 * t], a0);
  atomicAdd(&S[(size_t)cur * 128 + 2 * t + 1], a1);
}

// cnt[g] = number of (sorted) ids equal to g
__global__ void seg_cnt(const int* __restrict__ ids, int M, int* __restrict__ cnt, int G) {
  int g = blockIdx.x * 256 + threadIdx.x;
  if (g < G) cnt[g] = lowerb(ids, M, g + 1) - lowerb(ids, M, g);
}

// ---------- out[g, coloff+t] = (SP[g]-SR[g]) @ W + cnt[g]*b ----------
__global__ void diff_linear(const float* __restrict__ SP, const float* __restrict__ SR,
                            const int* __restrict__ cnt,
                            const float* __restrict__ W, const float* __restrict__ b,
                            float* __restrict__ out, int ldo, int coloff) {
  int g = blockIdx.x;
  int t = threadIdx.x;
  __shared__ float xs[128];
  xs[t] = SP[(size_t)g * 128 + t] - SR[(size_t)g * 128 + t];
  __syncthreads();
  float acc = (float)cnt[g] * b[t];
  for (int k = 0; k < 128; ++k) acc = fmaf(xs[k], W[k * 128 + t], acc);
  out[(size_t)g * ldo + coloff + t] = acc;
}

template<int K, int NC, bool RELU>
__global__ void mlp_linear(const float* __restrict__ X, const float* __restrict__ W,
                           const float* __restrict__ b, float* __restrict__ Y) {
  int g = blockIdx.x;
  int t = threadIdx.x;
  __shared__ float xs[K];
  for (int i = t; i < K; i += NC) xs[i] = X[(size_t)g * K + i];
  __syncthreads();
  float acc = b[t];
  for (int k = 0; k < K; ++k) acc = fmaf(xs[k], W[k * NC + t], acc);
  if (RELU) acc = fmaxf(acc, 0.f);
  Y[(size_t)g * NC + t] = acc;
}

__global__ void mlp_final(const float* __restrict__ X, const float* __restrict__ W,
                          const float* __restrict__ b, float* __restrict__ out, int G) {
  int g = blockIdx.x * blockDim.x + threadIdx.x;
  if (g >= G) return;
  float acc = b[0];
  for (int k = 0; k < 256; ++k) acc = fmaf(X[(size_t)g * 256 + k], W[k], acc);
  out[g] = acc;
}

struct LayerW {
  const float *Wni, *bni, *Wnj, *bnj, *Wf, *bf, *Wnode, *bnode, *attn;
};

extern "C" void kernel_launch(void* const* d_in, const int* in_sizes, int n_in,
                              void* d_out, int out_size, void* d_ws, size_t ws_size,
                              hipStream_t stream) {
  const float* hR = (const float*)d_in[0];
  const float* eR = (const float*)d_in[1];
  const float* hP = (const float*)d_in[2];
  const float* eP = (const float*)d_in[3];
  const int* srcR = (const int*)d_in[4];
  const int* dstR = (const int*)d_in[5];
  const int* srcP = (const int*)d_in[6];
  const int* dstP = (const int*)d_in[7];
  const int* nid  = (const int*)d_in[8];
  const int* eid  = (const int*)d_in[9];
  LayerW w1 { (const float*)d_in[10], (const float*)d_in[11], (const float*)d_in[12],
              (const float*)d_in[13], (const float*)d_in[14], (const float*)d_in[15],
              (const float*)d_in[16], (const float*)d_in[17], (const float*)d_in[18] };
  LayerW w2 { (const float*)d_in[19], (const float*)d_in[20], (const float*)d_in[21],
              (const float*)d_in[22], (const float*)d_in[23], (const float*)d_in[24],
              (const float*)d_in[25], (const float*)d_in[26], (const float*)d_in[27] };
  const float* Wa_n = (const float*)d_in[28];
  const float* ba_n = (const float*)d_in[29];
  const float* Wa_e = (const float*)d_in[30];
  const float* ba_e = (const float*)d_in[31];
  const float* Wm1  = (const float*)d_in[32];
  const float* bm1  = (const float*)d_in[33];
  const float* Wm2  = (const float*)d_in[34];
  const float* bm2  = (const float*)d_in[35];
  const float* Wm3  = (const float*)d_in[36];
  const float* bm3  = (const float*)d_in[37];

  const int N = in_sizes[0] / 17;   // 60000
  const int E = in_sizes[4];        // 240000
  const int G = out_size;           // 1024

  // ---- workspace carve-up ----
  char* base = (char*)d_ws;
  size_t off = 0;
  auto alloc = [&](size_t bytes) { char* p = base + off; off += (bytes + 255) & ~(size_t)255; return p; };
  ushort* nb     = (ushort*)alloc((size_t)N * 128 * 2);   // node state bf16
  ushort* f_nin  = (ushort*)alloc((size_t)N * 256 * 2);   // [ni | node] fused rows
  ushort* f_nj   = (ushort*)alloc((size_t)N * 128 * 2);
  ushort* ebp    = (ushort*)alloc((size_t)E * 128 * 2);   // edge state bf16, dst-CSR order
  int*    rowptrP = (int*)alloc((size_t)(N + 1) * 4);
  int*    rowptrR = (int*)alloc((size_t)(N + 1) * 4);
  int*    epermP  = (int*)alloc((size_t)E * 4);
  int*    epermR  = (int*)alloc((size_t)E * 4);
  int*    invpermP = (int*)alloc((size_t)E * 4);
  int*    invpermR = (int*)alloc((size_t)E * 4);
  int*    srcpermP = (int*)alloc((size_t)E * 4);
  int*    srcpermR = (int*)alloc((size_t)E * 4);
  int*    cnt     = (int*)alloc((size_t)N * 4);
  int*    cursor  = (int*)alloc((size_t)N * 4);
  int*    blocksum = (int*)alloc(1024 * 4);
  ushort* Wt_ni  = (ushort*)alloc(128 * 128 * 2);
  ushort* Wt_nj  = (ushort*)alloc(128 * 128 * 2);
  ushort* Wt_f   = (ushort*)alloc(128 * 128 * 2);
  ushort* Wt_nd  = (ushort*)alloc(128 * 128 * 2);
  float*  SnP    = (float*)alloc((size_t)G * 128 * 4);
  float*  SnR    = (float*)alloc((size_t)G * 128 * 4);
  float*  SeP    = (float*)alloc((size_t)G * 128 * 4);
  float*  SeR    = (float*)alloc((size_t)G * 128 * 4);
  float*  Gf     = (float*)alloc((size_t)G * 256 * 4);
  float*  x1     = (float*)alloc((size_t)G * 512 * 4);
  float*  x2     = (float*)alloc((size_t)G * 256 * 4);
  int*    cnt_n  = (int*)alloc((size_t)G * 4);
  int*    cnt_e  = (int*)alloc((size_t)G * 4);
  if (off > ws_size) return;  // graceful fail

  const int EB = (E + 255) / 256;
  const int NB = (N + 255) / 256;   // 235 <= 256, fits scan_block

  // ---- zero the 4 contiguous S accumulators (SnP..SeR) once ----
  fillzf<<<(G * 512 + 255) / 256, 256, 0, stream>>>(SnP, G * 512);

  // ---- CSR builds ----
  auto build_csr = [&](const int* dst, const int* src, int* rowptr,
                       int* eperm, int* invperm, int* src_perm) {
    fillzi<<<NB, 256, 0, stream>>>(cnt, N);
    hist_dst<<<EB, 256, 0, stream>>>(dst, cnt, E);
    scan_local<<<NB, 256, 0, stream>>>(cnt, rowptr, blocksum, N);
    scan_block<<<1, 256, 0, stream>>>(blocksum, NB);
    scan_add<<<NB, 256, 0, stream>>>(rowptr, cursor, blocksum, N, E);
    scatter_idx<<<EB, 256, 0, stream>>>(dst, src, cursor, eperm, invperm, src_perm, E);
  };
  build_csr(dstP, srcP, rowptrP, epermP, invpermP, srcpermP);
  build_csr(dstR, srcR, rowptrR, epermR, invpermR, srcpermR);

  // ---- prep egat2 weights (bf16, transposed, swizzled) ----
  prep_w<<<1, 256, 0, stream>>>(w2.Wni,   Wt_ni);
  prep_w<<<1, 256, 0, stream>>>(w2.Wnj,   Wt_nj);
  prep_w<<<1, 256, 0, stream>>>(w2.Wf,    Wt_f);
  prep_w<<<1, 256, 0, stream>>>(w2.Wnode, Wt_nd);

  // ---- per-graph counts ----
  seg_cnt<<<(G + 255) / 256, 256, 0, stream>>>(nid, N, cnt_n, G);
  seg_cnt<<<(G + 255) / 256, 256, 0, stream>>>(eid, E, cnt_e, G);

  const int GB = (N + 3) / 4;      // egat_gather grid

  auto layer1 = [&](const float* h, const float* e, const int* eperm,
                    const int* src_perm, const int* rowptr) {
    lin3_small<17><<<(N + 15) / 16, 128, 0, stream>>>(h, w1.Wni, w1.bni, w1.Wnj, w1.bnj,
                                                      w1.Wnode, w1.bnode, f_nin, f_nj, N);
    lin1_perm<15><<<(E + 15) / 16, 128, 0, stream>>>(e, w1.Wf, w1.bf, eperm, ebp, E);
    egat_gather<<<GB, 256, 0, stream>>>(f_nin, f_nj, ebp, src_perm, rowptr, w1.attn, nb, N);
  };
  auto layer2 = [&](const int* src_perm, const int* rowptr) {
    gemm3_k128<<<(N + 127) / 128, 256, 0, stream>>>(nb,
        Wt_ni, w2.bni,   f_nin,       256,
        Wt_nd, w2.bnode, f_nin + 128, 256,
        Wt_nj, w2.bnj,   f_nj,        128, N);
    gemm_k128<ushort, ushort><<<(E + 127) / 128, 256, 0, stream>>>(ebp, 128, Wt_f, w2.bf, ebp, 128, E);
    egat_gather<<<GB, 256, 0, stream>>>(f_nin, f_nj, ebp, src_perm, rowptr, w2.attn, nb, N);
  };

  // ---- P branch: one egat1 layer, reduce to G x 128 ----
  layer1(hP, eP, epermP, srcpermP, rowptrP);
  segsum_bf16<32><<<(N + 127) / 128, 256, 0, stream>>>(nb, nid, N, SnP);
  segsum_bf16g<16><<<(E + 63) / 64, 256, 0, stream>>>(ebp, invpermP, eid, E, SeP);

  // ---- R branch: egat1 + egat2 x2 ----
  layer1(hR, eR, epermR, srcpermR, rowptrR);
  layer2(srcpermR, rowptrR);
  layer2(srcpermR, rowptrR);
  segsum_bf16<32><<<(N + 127) / 128, 256, 0, stream>>>(nb, nid, N, SnR);
  segsum_bf16g<16><<<(E + 63) / 64, 256, 0, stream>>>(ebp, invpermR, eid, E, SeR);

  // ---- Diff aggregate + per-graph linears ----
  diff_linear<<<G, 128, 0, stream>>>(SnP, SnR, cnt_n, Wa_n, ba_n, Gf, 256, 0);
  diff_linear<<<G, 128, 0, stream>>>(SeP, SeR, cnt_e, Wa_e, ba_e, Gf, 256, 128);

  // ---- MLP head ----
  mlp_linear<256, 512, true><<<G, 512, 0, stream>>>(Gf, Wm1, bm1, x1);
  mlp_linear<512, 256, true><<<G, 256, 0, stream>>>(x1, Wm2, bm2, x2);
  mlp_final<<<(G + 255) / 256, 256, 0, stream>>>(x2, Wm3, bm3, (float*)d_out, G);
}